// Round 5
// baseline (1490.483 us; speedup 1.0000x reference)
//
#include <hip/hip_runtime.h>
#include <hip/hip_bf16.h>

// Problem constants (match reference setup_inputs)
static constexpr int cNV = 4096, cEV = 16384, cB = 128, cNC = 32, cNS = 128;
static constexpr int cNSITE = 16384, cES = 131072;
static constexpr int cH = 128, cK8 = 8, cHI = 64;

__device__ __forceinline__ float leakyf(float x){ return x > 0.f ? x : 0.1f * x; }
__device__ __forceinline__ float sigm(float x){ return 1.f / (1.f + __expf(-x)); }

// ---------------- elementwise helpers ----------------
__global__ void zero_k(float* __restrict__ p, long n){
  long i = (long)blockIdx.x * 256 + threadIdx.x;
  if (i < n) p[i] = 0.f;
}

__global__ void add_k(const float* __restrict__ a, const float* __restrict__ b,
                      float* __restrict__ c, int n){
  int i = blockIdx.x * 256 + threadIdx.x;
  if (i < n) c[i] = a[i] + b[i];
}

// ---------------- generic segmented-A GEMM ----------------
// C[M,N] = act( concat_K(A0..A3) @ W + bias ), all fp32.
// W addressing: addr(r,c) = r*ldw + (c>>cshift)*cs + (c & ((1<<cshift)-1))
//   standard row-major:  cshift=30, cs=0
//   head-blocked [Kh,128,128]: cshift=7, cs=16384 ; [7,128,64]: cshift=6, cs=8192
__global__ __launch_bounds__(256) void gemm_seg(
    const float* __restrict__ A0, const float* __restrict__ A1,
    const float* __restrict__ A2, const float* __restrict__ A3,
    int k1, int k2, int k3, int K, int M,
    const float* __restrict__ W, int ldw, int cshift, int cs,
    const float* __restrict__ bias,
    float* __restrict__ C, int N, int act)
{
  __shared__ float As[16][64];
  __shared__ float Bs[16][64];
  const int t = threadIdx.x;
  const int tx = t & 15, ty = t >> 4;
  const int m0 = blockIdx.y * 64, n0 = blockIdx.x * 64;
  const unsigned cmask = (1u << cshift) - 1u;
  const long wbase = (long)(n0 >> cshift) * cs + (long)(n0 & cmask);
  const int w1 = k2 - k1, w2 = k3 - k2, w3 = K - k3;
  float acc[16];
  #pragma unroll
  for (int i = 0; i < 16; i++) acc[i] = 0.f;
  const int mm = t >> 2, kb = (t & 3) * 4;
  const int nn = t & 63, kwb = (t >> 6) * 4;
  for (int kt = 0; kt < K; kt += 16) {
    int mg = m0 + mm;
    #pragma unroll
    for (int i = 0; i < 4; i++) {
      int kg = kt + kb + i;
      float v = 0.f;
      if (mg < M && kg < K) {
        if (kg < k1)      v = A0[(long)mg * k1 + kg];
        else if (kg < k2) v = A1[(long)mg * w1 + (kg - k1)];
        else if (kg < k3) v = A2[(long)mg * w2 + (kg - k2)];
        else              v = A3[(long)mg * w3 + (kg - k3)];
      }
      As[kb + i][mm] = v;
    }
    #pragma unroll
    for (int i = 0; i < 4; i++) {
      int kg = kt + kwb + i;
      float v = 0.f;
      if (kg < K) v = W[(long)kg * ldw + wbase + nn];
      Bs[kwb + i][nn] = v;
    }
    __syncthreads();
    #pragma unroll
    for (int kk = 0; kk < 16; kk++) {
      float a[4], b[4];
      #pragma unroll
      for (int i = 0; i < 4; i++) a[i] = As[kk][ty * 4 + i];
      #pragma unroll
      for (int j = 0; j < 4; j++) b[j] = Bs[kk][tx * 4 + j];
      #pragma unroll
      for (int i = 0; i < 4; i++)
        #pragma unroll
        for (int j = 0; j < 4; j++)
          acc[i * 4 + j] += a[i] * b[j];
    }
    __syncthreads();
  }
  #pragma unroll
  for (int j = 0; j < 4; j++) {
    int c = n0 + tx * 4 + j;
    float bv = (bias != nullptr && c < N) ? bias[c] : 0.f;
    #pragma unroll
    for (int i = 0; i < 4; i++) {
      int m = m0 + ty * 4 + i;
      if (m < M && c < N) {
        float v = acc[i * 4 + j] + bv;
        if (act == 1) v = leakyf(v);
        else if (act == 2) v = tanhf(v);
        else if (act == 3) v = sigm(v);
        C[(long)m * N + c] = v;
      }
    }
  }
}

// ---------------- compound-graph kernels ----------------
__global__ void supe_init_k(const float* __restrict__ vert, float* __restrict__ supe){
  int b = blockIdx.x, c = threadIdx.x;
  float s = 0.f;
  for (int i = 0; i < cNC; i++) s += vert[(b * cNC + i) * cH + c];
  supe[b * cH + c] = s;
}

__global__ void scatter_vert_k(const float* __restrict__ vert, const int* __restrict__ src,
                               const int* __restrict__ dst, float* __restrict__ nei){
  int idx = blockIdx.x * 256 + threadIdx.x;
  if (idx >= cEV * cH) return;
  int e = idx >> 7, c = idx & 127;
  atomicAdd(&nei[dst[e] * cH + c], vert[src[e] * cH + c]);
}

// per-graph super-node precompute: asup, s2m, s2mz, super_self, gh_s
__global__ __launch_bounds__(256) void supe_pre_k(
    const float* __restrict__ supe,
    const float* __restrict__ Wa_super_d, const float* __restrict__ Ws2m_d,
    const float* __restrict__ Wzm2_d, const float* __restrict__ Wsup_d,
    const float* __restrict__ Whh_s, const float* __restrict__ bhh_s,
    float* __restrict__ asup, float* __restrict__ s2m, float* __restrict__ s2mz,
    float* __restrict__ sself, float* __restrict__ gh_s)
{
  __shared__ float srow[cH];
  __shared__ float s2ml[cH];
  int b = blockIdx.x, t = threadIdx.x;
  if (t < cH) srow[t] = supe[b * cH + t];
  __syncthreads();
  // asup[b, 0:1024]
  for (int j = 0; j < 4; j++) {
    int c = t + j * 256;
    int head = c >> 7, e = c & 127;
    const float* Wp = Wa_super_d + head * 16384 + e;
    float s = 0.f;
    for (int d2 = 0; d2 < cH; d2++) s += srow[d2] * Wp[d2 * 128];
    asup[b * 1024 + c] = tanhf(s);
  }
  if (t < cH) {
    float s = 0.f;
    for (int d2 = 0; d2 < cH; d2++) s += srow[d2] * Ws2m_d[d2 * 128 + t];
    float v = tanhf(s);
    s2ml[t] = v; s2m[b * cH + t] = v;
  } else {
    int c = t - cH;
    float s = 0.f;
    for (int d2 = 0; d2 < cH; d2++) s += srow[d2] * Wsup_d[d2 * 128 + c];
    sself[b * cH + c] = tanhf(s);
  }
  // gh_s = supe @ Whh_s + bhh_s  (384 cols)
  {
    int c = t;
    float s = 0.f;
    for (int d2 = 0; d2 < cH; d2++) s += srow[d2] * Whh_s[d2 * 384 + c];
    gh_s[b * 384 + c] = s + bhh_s[c];
    if (t < cH) {
      int c2 = 256 + t;
      float s2 = 0.f;
      for (int d2 = 0; d2 < cH; d2++) s2 += srow[d2] * Whh_s[d2 * 384 + c2];
      gh_s[b * 384 + c2] = s2 + bhh_s[c2];
    }
  }
  __syncthreads();
  if (t < cH) {
    float s = 0.f;
    for (int d2 = 0; d2 < cH; d2++) s += s2ml[d2] * Wzm2_d[d2 * 128 + t];
    s2mz[b * cH + t] = s;
  }
}

// per-graph attention scores + segment softmax
__global__ __launch_bounds__(256) void attn_k(
    const float* __restrict__ am, const float* __restrict__ asup,
    const float* __restrict__ Wb_d, float* __restrict__ attn)
{
  __shared__ float pw[1024];
  __shared__ float sc[cNC][cK8];
  int b = blockIdx.x, t = threadIdx.x;
  for (int j = 0; j < 4; j++) {
    int c = t + j * 256;
    pw[c] = asup[b * 1024 + c] * Wb_d[c];
  }
  __syncthreads();
  int nl = t >> 3, k = t & 7;
  int n = b * cNC + nl;
  const float* ar = am + (long)n * 1024 + k * 128;
  const float* pr = pw + k * 128;
  float s = 0.f;
  for (int e = 0; e < 128; e++) s += ar[e] * pr[e];
  sc[nl][k] = s;
  __syncthreads();
  float mx = -1e30f;
  for (int i = 0; i < cNC; i++) mx = fmaxf(mx, sc[i][k]);
  float den = 0.f;
  for (int i = 0; i < cNC; i++) den += __expf(sc[i][k] - mx);
  attn[n * cK8 + k] = __expf(s - mx) / den;
}

// per-graph m2s + main_to_super = tanh(m2s @ Wm2s)
__global__ __launch_bounds__(256) void m2s_k(
    const float* __restrict__ attn, const float* __restrict__ msg,
    const float* __restrict__ Wm2s_d, float* __restrict__ mts)
{
  __shared__ float m2s[1024];
  __shared__ float at[cNC][cK8];
  int b = blockIdx.x, t = threadIdx.x;
  at[t >> 3][t & 7] = attn[(b * cNC + (t >> 3)) * cK8 + (t & 7)];
  __syncthreads();
  for (int j = 0; j < 4; j++) {
    int c = t + j * 256;
    int k = c >> 7;
    float s = 0.f;
    for (int i = 0; i < cNC; i++) s += at[i][k] * msg[(long)(b * cNC + i) * 1024 + c];
    m2s[c] = s;
  }
  __syncthreads();
  if (t < cH) {
    float s = 0.f;
    for (int j = 0; j < 1024; j++) s += m2s[j] * Wm2s_d[j * 128 + t];
    mts[b * cH + t] = tanhf(s);
  }
}

__global__ void ew_xgru_k(const float* __restrict__ zmp, const float* __restrict__ s2mz,
                          const float* __restrict__ s2m, const float* __restrict__ ms,
                          const int* __restrict__ vbatch, float* __restrict__ xg){
  int idx = blockIdx.x * 256 + threadIdx.x;
  if (idx >= cNV * cH) return;
  int n = idx >> 7, c = idx & 127;
  int b = vbatch[n];
  float zm = sigm(zmp[idx] + s2mz[b * cH + c]);
  xg[idx] = (1.f - zm) * ms[idx] + zm * s2m[b * cH + c];
}

__global__ void ew_gru_k(const float* __restrict__ gi, const float* __restrict__ gh,
                         float* __restrict__ h){
  int idx = blockIdx.x * 256 + threadIdx.x;
  if (idx >= cNV * cH) return;
  int n = idx >> 7, c = idx & 127;
  const float* gir = gi + (long)n * 384;
  const float* ghr = gh + (long)n * 384;
  float r = sigm(gir[c] + ghr[c]);
  float z = sigm(gir[128 + c] + ghr[128 + c]);
  float nn = tanhf(gir[256 + c] + r * ghr[256 + c]);
  h[idx] = (1.f - z) * nn + z * h[idx];
}

__global__ __launch_bounds__(128) void super_upd_k(
    const float* __restrict__ sself, const float* __restrict__ mts,
    const float* __restrict__ gh_s,
    const float* __restrict__ Wzs1_d, const float* __restrict__ Wzs2_d,
    const float* __restrict__ Wih_s, const float* __restrict__ bih_s,
    float* __restrict__ supe)
{
  __shared__ float ss[cH], mt[cH], xs[cH], sr[cH];
  int b = blockIdx.x, t = threadIdx.x;
  ss[t] = sself[b * cH + t];
  mt[t] = mts[b * cH + t];
  sr[t] = supe[b * cH + t];
  __syncthreads();
  float s1 = 0.f, s2 = 0.f;
  for (int d2 = 0; d2 < cH; d2++) {
    s1 += ss[d2] * Wzs1_d[d2 * 128 + t];
    s2 += mt[d2] * Wzs2_d[d2 * 128 + t];
  }
  float zs = sigm(s1 + s2);
  xs[t] = (1.f - zs) * ss[t] + zs * mt[t];
  __syncthreads();
  float g0 = 0.f, g1 = 0.f, g2 = 0.f;
  for (int d2 = 0; d2 < cH; d2++) {
    float x = xs[d2];
    g0 += x * Wih_s[d2 * 384 + t];
    g1 += x * Wih_s[d2 * 384 + 128 + t];
    g2 += x * Wih_s[d2 * 384 + 256 + t];
  }
  g0 += bih_s[t]; g1 += bih_s[128 + t]; g2 += bih_s[256 + t];
  float r = sigm(g0 + gh_s[b * 384 + t]);
  float z = sigm(g1 + gh_s[b * 384 + 128 + t]);
  float nn = tanhf(g2 + r * gh_s[b * 384 + 256 + t]);
  supe[b * cH + t] = (1.f - z) * nn + z * sr[t];
}

// ---------------- site-graph kernels ----------------
__global__ void scatter_site_k(const float* __restrict__ h, const int* __restrict__ src,
                               const int* __restrict__ dst, float* __restrict__ nei,
                               int dshift){
  long idx = (long)blockIdx.x * 256 + threadIdx.x;
  int din = 1 << dshift;
  if (idx >= (long)cES * din) return;
  int e = (int)(idx >> dshift);
  int c = (int)(idx & (din - 1));
  atomicAdd(&nei[(long)dst[e] * din + c], h[(long)src[e] * din + c]);
}

// ---------------- interaction ----------------
__global__ __launch_bounds__(256) void pair_k(
    const float* __restrict__ pa, const float* __restrict__ pg, float* __restrict__ out)
{
  __shared__ float pal[cNS][cHI];      // 32 KB
  __shared__ float pgl[cNC][cHI + 1];  // padded vs bank conflicts
  int g = blockIdx.x, i = blockIdx.y;
  int t = threadIdx.x;
  for (int l = t; l < cNS * cHI; l += 256) {
    int s = l >> 6, hh = l & 63;
    pal[s][hh] = pa[(long)(g * cNS + s) * 448 + i * 64 + hh];
  }
  for (int l = t; l < cNC * cHI; l += 256) {
    int c = l >> 6, hh = l & 63;
    pgl[c][hh] = pg[(long)(g * cNC + c) * 448 + i * 64 + hh];
  }
  __syncthreads();
  for (int o = t; o < cNS * cNC; o += 256) {
    int s = o >> 5, c = o & 31;
    float sum = 0.f;
    #pragma unroll 8
    for (int hh = 0; hh < cHI; hh++) sum += pal[s][hh] * pgl[c][hh];
    long p = (long)g * (cNS * cNC) + o;
    out[p * 7 + i] = sum;
  }
}

// ---------------- launch ----------------
extern "C" void kernel_launch(void* const* d_in, const int* in_sizes, int n_in,
                              void* d_out, int out_size, void* d_ws, size_t ws_size,
                              hipStream_t stream) {
  // workspace layout (fp32 elements)
  constexpr long OFF_VERT = 0;            // 524288
  constexpr long OFF_SUPE = 524288;       // 16384
  constexpr long OFF_SITE = 1064960;      // 2097152
  constexpr long OFF_ATTN = 3162112;      // 32768
  constexpr long OFF_ASUP = 3194880;      // 131072
  constexpr long OFF_S2M = 3325952;       // 16384
  constexpr long OFF_S2MZ = 3342336;      // 16384
  constexpr long OFF_SSELF = 3358720;     // 16384
  constexpr long OFF_GHS = 3375104;       // 49152
  constexpr long OFF_MTS = 3424256;       // 16384
  constexpr long OFF_NEI = 3440640;       // 524288
  constexpr long OFF_TMPA = 3964928;      // 524288  (nei_s aliases TMPA..XGRU = 2097152)
  constexpr long OFF_MS = 4489216;        // 524288
  constexpr long OFF_ZMP = 5013504;       // 524288
  constexpr long OFF_XGRU = 5537792;      // 524288
  constexpr long OFF_GHM = 6062080;       // 1572864 (pg aliases here in interaction phase)
  constexpr long OFF_GIM = 7634944;       // 1572864
  constexpr long OFF_AM = 9207808;        // 4194304 (pa aliases am..msg in interaction)
  constexpr long OFF_MSG = 13402112;      // 4194304
  constexpr long OFF_H1 = 17596416;       // 2097152
  constexpr long OFF_H2 = 19693568;       // 2097152
  constexpr long OFF_H3 = 21790720;       // 2097152
  constexpr long WS_FLOATS = 23887872;    // ~95.6 MB
  if (ws_size < (size_t)WS_FLOATS * 4) return;  // fail loudly (output stays wrong)

  const float* x_vert  = (const float*)d_in[0];
  const int*   vsrc    = (const int*)d_in[1];
  const int*   vdst    = (const int*)d_in[2];
  const int*   vbatch  = (const int*)d_in[3];
  const float* W_emb   = (const float*)d_in[4];
  const float* b_emb   = (const float*)d_in[5];
  const float* Wa_main = (const float*)d_in[6];
  const float* Wa_super= (const float*)d_in[7];
  const float* Wv      = (const float*)d_in[8];
  const float* Wb      = (const float*)d_in[9];
  const float* Wm2s    = (const float*)d_in[10];
  const float* Ws2m    = (const float*)d_in[11];
  const float* Wsup    = (const float*)d_in[12];
  const float* Wself   = (const float*)d_in[13];
  const float* Wzm1    = (const float*)d_in[14];
  const float* Wzm2    = (const float*)d_in[15];
  const float* Wzs1    = (const float*)d_in[16];
  const float* Wzs2    = (const float*)d_in[17];
  const float* Wih_m   = (const float*)d_in[18];
  const float* Whh_m   = (const float*)d_in[19];
  const float* bih_m   = (const float*)d_in[20];
  const float* bhh_m   = (const float*)d_in[21];
  const float* Wih_s   = (const float*)d_in[22];
  const float* Whh_s   = (const float*)d_in[23];
  const float* bih_s   = (const float*)d_in[24];
  const float* bhh_s   = (const float*)d_in[25];
  const float* x_site  = (const float*)d_in[26];
  const int*   ssrc    = (const int*)d_in[27];
  const int*   sdst    = (const int*)d_in[28];
  const float* W0      = (const float*)d_in[29];
  const float* b0      = (const float*)d_in[30];
  const float* Wconv   = (const float*)d_in[31];
  const float* bconv   = (const float*)d_in[32];
  const float* Wout    = (const float*)d_in[33];
  const float* bout    = (const float*)d_in[34];
  const float* Wis     = (const float*)d_in[35];
  const float* bis     = (const float*)d_in[36];
  const float* Wic     = (const float*)d_in[37];
  const float* bic     = (const float*)d_in[38];
  float* out = (float*)d_out;

  float* ws = (float*)d_ws;
  float* vert = ws + OFF_VERT;
  float* supe = ws + OFF_SUPE;
  float* site = ws + OFF_SITE;
  float* attn = ws + OFF_ATTN;
  float* asup = ws + OFF_ASUP;
  float* s2m = ws + OFF_S2M;
  float* s2mz = ws + OFF_S2MZ;
  float* sself = ws + OFF_SSELF;
  float* gh_s = ws + OFF_GHS;
  float* mts = ws + OFF_MTS;
  float* nei = ws + OFF_NEI;
  float* tmpA = ws + OFF_TMPA;
  float* ms = ws + OFF_MS;
  float* zmp = ws + OFF_ZMP;
  float* xgru = ws + OFF_XGRU;
  float* gh_m = ws + OFF_GHM;
  float* gim = ws + OFF_GIM;
  float* am = ws + OFF_AM;
  float* msg = ws + OFF_MSG;
  float* h1 = ws + OFF_H1;
  float* h2 = ws + OFF_H2;
  float* h3 = ws + OFF_H3;
  float* nei_s = ws + OFF_TMPA;   // alias: site phase only
  float* pa = ws + OFF_AM;        // alias: interaction phase only
  float* pg = ws + OFF_GHM;       // alias: interaction phase only

  auto gemm = [&](const float* A0, const float* A1, const float* A2, const float* A3,
                  int k1, int k2, int k3, int K, int M,
                  const float* W, int ldw, int cshift, int cs, const float* bias,
                  float* C, int N, int act){
    dim3 g(N / 64, (M + 63) / 64);
    gemm_seg<<<g, 256, 0, stream>>>(A0, A1, A2, A3, k1, k2, k3, K, M,
                                    W, ldw, cshift, cs, bias, C, N, act);
  };
  auto zero = [&](float* p, long n){
    zero_k<<<dim3((unsigned)((n + 255) / 256)), 256, 0, stream>>>(p, n);
  };

  // ---- embedding + super init ----
  gemm(x_vert, x_vert, x_vert, x_vert, 82, 82, 82, 82, cNV,
       W_emb, 128, 30, 0, b_emb, vert, 128, 1);
  supe_init_k<<<cB, 128, 0, stream>>>(vert, supe);

  // ---- GWM iterations ----
  for (int d = 0; d < 3; d++) {
    const float* Wa_main_d = Wa_main + (long)d * 131072;
    const float* Wa_super_d = Wa_super + (long)d * 131072;
    const float* Wv_d = Wv + (long)d * 131072;
    const float* Wb_d = Wb + (long)d * 1024;
    const float* Wm2s_d = Wm2s + (long)d * 131072;
    const float* Ws2m_d = Ws2m + (long)d * 16384;
    const float* Wsup_d = Wsup + (long)d * 16384;
    const float* Wself_d = Wself + (long)d * 16384;
    const float* Wzm1_d = Wzm1 + (long)d * 16384;
    const float* Wzm2_d = Wzm2 + (long)d * 16384;
    const float* Wzs1_d = Wzs1 + (long)d * 16384;
    const float* Wzs2_d = Wzs2 + (long)d * 16384;

    zero(nei, (long)cNV * cH);
    scatter_vert_k<<<(cEV * cH) / 256, 256, 0, stream>>>(vert, vsrc, vdst, nei);
    add_k<<<(cNV * cH) / 256, 256, 0, stream>>>(vert, nei, tmpA, cNV * cH);
    gemm(tmpA, tmpA, tmpA, tmpA, 128, 128, 128, 128, cNV,
         Wself_d, 128, 30, 0, nullptr, ms, 128, 1);                       // main_self
    gemm(vert, vert, vert, vert, 128, 128, 128, 128, cNV,
         Wa_main_d, 128, 7, 16384, nullptr, am, 1024, 2);                 // am = tanh
    gemm(vert, vert, vert, vert, 128, 128, 128, 128, cNV,
         Wv_d, 128, 7, 16384, nullptr, msg, 1024, 0);                     // msg
    gemm(vert, vert, vert, vert, 128, 128, 128, 128, cNV,
         Whh_m, 384, 30, 0, bhh_m, gh_m, 384, 0);                         // gh (GRU)
    supe_pre_k<<<cB, 256, 0, stream>>>(supe, Wa_super_d, Ws2m_d, Wzm2_d, Wsup_d,
                                       Whh_s, bhh_s, asup, s2m, s2mz, sself, gh_s);
    attn_k<<<cB, 256, 0, stream>>>(am, asup, Wb_d, attn);
    m2s_k<<<cB, 256, 0, stream>>>(attn, msg, Wm2s_d, mts);
    gemm(ms, ms, ms, ms, 128, 128, 128, 128, cNV,
         Wzm1_d, 128, 30, 0, nullptr, zmp, 128, 0);
    ew_xgru_k<<<(cNV * cH) / 256, 256, 0, stream>>>(zmp, s2mz, s2m, ms, vbatch, xgru);
    gemm(xgru, xgru, xgru, xgru, 128, 128, 128, 128, cNV,
         Wih_m, 384, 30, 0, bih_m, gim, 384, 0);
    ew_gru_k<<<(cNV * cH) / 256, 256, 0, stream>>>(gim, gh_m, vert);
    super_upd_k<<<cB, 128, 0, stream>>>(sself, mts, gh_s, Wzs1_d, Wzs2_d,
                                        Wih_s, bih_s, supe);
  }

  // ---- AtomConv on protein sites ----
  // iter 0: din=32
  zero(nei_s, (long)cNSITE * 32);
  scatter_site_k<<<((long)cES * 32) / 256, 256, 0, stream>>>(x_site, ssrc, sdst, nei_s, 5);
  gemm(x_site, nei_s, x_site, x_site, 32, 64, 64, 64, cNSITE,
       W0, 128, 30, 0, b0, h1, 128, 1);
  // iter 1
  zero(nei_s, (long)cNSITE * 128);
  scatter_site_k<<<((long)cES * 128) / 256, 256, 0, stream>>>(h1, ssrc, sdst, nei_s, 7);
  gemm(h1, nei_s, h1, h1, 128, 256, 256, 256, cNSITE,
       Wconv, 128, 30, 0, bconv, h2, 128, 1);
  // iter 2
  zero(nei_s, (long)cNSITE * 128);
  scatter_site_k<<<((long)cES * 128) / 256, 256, 0, stream>>>(h2, ssrc, sdst, nei_s, 7);
  gemm(h2, nei_s, h2, h2, 128, 256, 256, 256, cNSITE,
       Wconv + 32768, 128, 30, 0, bconv + 128, h3, 128, 1);
  // site = leaky(concat(x_site, h1, h2, h3) @ Wout + bout)
  gemm(x_site, h1, h2, h3, 32, 160, 288, 416, cNSITE,
       Wout, 128, 30, 0, bout, site, 128, 1);

  // ---- Interaction ----
  gemm(site, site, site, site, 128, 128, 128, 128, cNSITE,
       Wis, 64, 6, 8192, bis, pa, 448, 1);
  gemm(vert, vert, vert, vert, 128, 128, 128, 128, cNV,
       Wic, 64, 6, 8192, bic, pg, 448, 1);
  pair_k<<<dim3(cB, 7), 256, 0, stream>>>(pa, pg, out);
}

// Round 6
// 1255.440 us; speedup vs baseline: 1.1872x; 1.1872x over previous
//
#include <hip/hip_runtime.h>
#include <hip/hip_bf16.h>

// Problem constants (match reference setup_inputs)
static constexpr int cNV = 4096, cEV = 16384, cB = 128, cNC = 32, cNS = 128;
static constexpr int cNSITE = 16384, cES = 131072;
static constexpr int cH = 128, cK8 = 8, cHI = 64;

__device__ __forceinline__ float leakyf(float x){ return x > 0.f ? x : 0.1f * x; }
__device__ __forceinline__ float sigm(float x){ return 1.f / (1.f + __expf(-x)); }

typedef __attribute__((ext_vector_type(4))) short short4v;
typedef __attribute__((ext_vector_type(4))) float f32x4;

__device__ __forceinline__ unsigned short f2bu(float x){
  __hip_bfloat16 h = __float2bfloat16(x);
  return *(unsigned short*)&h;
}

// ---------------- elementwise helpers ----------------
__global__ void zero_k(float* __restrict__ p, long n){
  long i = (long)blockIdx.x * 256 + threadIdx.x;
  if (i < n) p[i] = 0.f;
}

__global__ void add_k(const float* __restrict__ a, const float* __restrict__ b,
                      float* __restrict__ c, int n){
  int i = blockIdx.x * 256 + threadIdx.x;
  if (i < n) c[i] = a[i] + b[i];
}

// ---------------- MFMA segmented-A GEMM ----------------
// C[M,N] = act( concat_K(A0..A3) @ W + bias ), A/W fp32 in memory, bf16 MFMA
// compute with fp32 accumulate. W column addressing as before (cshift/cs).
// Tile 64x64, 4 waves (2x2), per-wave 32x32 via 2x2 mfma_f32_16x16x16bf16_1k.
__global__ __launch_bounds__(256) void gemm_mfma(
    const float* __restrict__ A0, const float* __restrict__ A1,
    const float* __restrict__ A2, const float* __restrict__ A3,
    int k1, int k2, int k3, int K, int M,
    const float* __restrict__ W, int ldw, int cshift, int cs,
    const float* __restrict__ bias,
    float* __restrict__ C, int N, int act)
{
  __shared__ __align__(16) unsigned short As[64 * 40];  // [row][40] bf16, k contiguous
  __shared__ __align__(16) unsigned short Bs[64 * 40];  // [col][40] bf16, k contiguous
  const int t = threadIdx.x;
  const int l = t & 63, w = t >> 6;
  const int wr = w >> 1, wc = w & 1;
  const int m0 = blockIdx.y * 64, n0 = blockIdx.x * 64;
  const long wbase = (long)(n0 >> cshift) * cs + (long)(n0 & ((1 << cshift) - 1));
  const int w1 = k2 - k1, w2 = k3 - k2, w3 = K - k3;

  f32x4 acc[2][2];
  #pragma unroll
  for (int i = 0; i < 2; i++)
    #pragma unroll
    for (int j = 0; j < 2; j++)
      acc[i][j] = (f32x4){0.f, 0.f, 0.f, 0.f};

  const int arow = t >> 2, akq = (t & 3) * 8;   // A: coalesced over k
  const int bcol = t & 63, bkq = (t >> 6) * 8;  // B: coalesced over columns
  const int lr = l & 15, lh = l >> 4;

  for (int kt = 0; kt < K; kt += 32) {
    // ---- stage A tile (64 rows x 32 k) as bf16 ----
    {
      const int mg = m0 + arow;
      float av[8];
      #pragma unroll
      for (int j = 0; j < 8; j++) {
        int kg = kt + akq + j;
        float v = 0.f;
        if (kg < K) {
          if (kg < k1)      v = A0[(long)mg * k1 + kg];
          else if (kg < k2) v = A1[(long)mg * w1 + (kg - k1)];
          else if (kg < k3) v = A2[(long)mg * w2 + (kg - k2)];
          else              v = A3[(long)mg * w3 + (kg - k3)];
        }
        av[j] = v;
      }
      uint4 pk;
      pk.x = (unsigned)f2bu(av[0]) | ((unsigned)f2bu(av[1]) << 16);
      pk.y = (unsigned)f2bu(av[2]) | ((unsigned)f2bu(av[3]) << 16);
      pk.z = (unsigned)f2bu(av[4]) | ((unsigned)f2bu(av[5]) << 16);
      pk.w = (unsigned)f2bu(av[6]) | ((unsigned)f2bu(av[7]) << 16);
      *(uint4*)&As[arow * 40 + akq] = pk;
    }
    // ---- stage B tile (64 cols x 32 k) as bf16, transposed to [col][k] ----
    {
      float bv[8];
      #pragma unroll
      for (int j = 0; j < 8; j++) {
        int kg = kt + bkq + j;
        bv[j] = (kg < K) ? W[(long)kg * ldw + wbase + bcol] : 0.f;
      }
      uint4 pk;
      pk.x = (unsigned)f2bu(bv[0]) | ((unsigned)f2bu(bv[1]) << 16);
      pk.y = (unsigned)f2bu(bv[2]) | ((unsigned)f2bu(bv[3]) << 16);
      pk.z = (unsigned)f2bu(bv[4]) | ((unsigned)f2bu(bv[5]) << 16);
      pk.w = (unsigned)f2bu(bv[6]) | ((unsigned)f2bu(bv[7]) << 16);
      *(uint4*)&Bs[bcol * 40 + bkq] = pk;
    }
    __syncthreads();
    // ---- compute: 2 k-substeps x 2x2 tiles of 16x16x16 bf16 MFMA ----
    #pragma unroll
    for (int ks = 0; ks < 2; ks++) {
      short4v a0 = *(short4v*)&As[(wr * 32 + 0 * 16 + lr) * 40 + ks * 16 + lh * 4];
      short4v a1 = *(short4v*)&As[(wr * 32 + 1 * 16 + lr) * 40 + ks * 16 + lh * 4];
      short4v b0 = *(short4v*)&Bs[(wc * 32 + 0 * 16 + lr) * 40 + ks * 16 + lh * 4];
      short4v b1 = *(short4v*)&Bs[(wc * 32 + 1 * 16 + lr) * 40 + ks * 16 + lh * 4];
      acc[0][0] = __builtin_amdgcn_mfma_f32_16x16x16bf16_1k(a0, b0, acc[0][0], 0, 0, 0);
      acc[0][1] = __builtin_amdgcn_mfma_f32_16x16x16bf16_1k(a0, b1, acc[0][1], 0, 0, 0);
      acc[1][0] = __builtin_amdgcn_mfma_f32_16x16x16bf16_1k(a1, b0, acc[1][0], 0, 0, 0);
      acc[1][1] = __builtin_amdgcn_mfma_f32_16x16x16bf16_1k(a1, b1, acc[1][1], 0, 0, 0);
    }
    __syncthreads();
  }
  // ---- epilogue: bias + activation, fp32 store ----
  #pragma unroll
  for (int ri = 0; ri < 2; ri++) {
    #pragma unroll
    for (int ci = 0; ci < 2; ci++) {
      int col = n0 + wc * 32 + ci * 16 + lr;
      float bv = (bias != nullptr) ? bias[col] : 0.f;
      #pragma unroll
      for (int e = 0; e < 4; e++) {
        int row = m0 + wr * 32 + ri * 16 + lh * 4 + e;
        float v = acc[ri][ci][e] + bv;
        if (act == 1) v = leakyf(v);
        else if (act == 2) v = tanhf(v);
        else if (act == 3) v = sigm(v);
        C[(long)row * N + col] = v;
      }
    }
  }
}

// ---------------- compound-graph kernels ----------------
__global__ void supe_init_k(const float* __restrict__ vert, float* __restrict__ supe){
  int b = blockIdx.x, c = threadIdx.x;
  float s = 0.f;
  for (int i = 0; i < cNC; i++) s += vert[(b * cNC + i) * cH + c];
  supe[b * cH + c] = s;
}

__global__ void scatter_vert_k(const float* __restrict__ vert, const int* __restrict__ src,
                               const int* __restrict__ dst, float* __restrict__ nei){
  int idx = blockIdx.x * 256 + threadIdx.x;
  if (idx >= cEV * cH) return;
  int e = idx >> 7, c = idx & 127;
  atomicAdd(&nei[dst[e] * cH + c], vert[src[e] * cH + c]);
}

// per-graph super-node precompute: asup, s2m, s2mz, super_self, gh_s
__global__ __launch_bounds__(256) void supe_pre_k(
    const float* __restrict__ supe,
    const float* __restrict__ Wa_super_d, const float* __restrict__ Ws2m_d,
    const float* __restrict__ Wzm2_d, const float* __restrict__ Wsup_d,
    const float* __restrict__ Whh_s, const float* __restrict__ bhh_s,
    float* __restrict__ asup, float* __restrict__ s2m, float* __restrict__ s2mz,
    float* __restrict__ sself, float* __restrict__ gh_s)
{
  __shared__ float srow[cH];
  __shared__ float s2ml[cH];
  int b = blockIdx.x, t = threadIdx.x;
  if (t < cH) srow[t] = supe[b * cH + t];
  __syncthreads();
  // asup[b, 0:1024]
  for (int j = 0; j < 4; j++) {
    int c = t + j * 256;
    int head = c >> 7, e = c & 127;
    const float* Wp = Wa_super_d + head * 16384 + e;
    float s = 0.f;
    for (int d2 = 0; d2 < cH; d2++) s += srow[d2] * Wp[d2 * 128];
    asup[b * 1024 + c] = tanhf(s);
  }
  if (t < cH) {
    float s = 0.f;
    for (int d2 = 0; d2 < cH; d2++) s += srow[d2] * Ws2m_d[d2 * 128 + t];
    float v = tanhf(s);
    s2ml[t] = v; s2m[b * cH + t] = v;
  } else {
    int c = t - cH;
    float s = 0.f;
    for (int d2 = 0; d2 < cH; d2++) s += srow[d2] * Wsup_d[d2 * 128 + c];
    sself[b * cH + c] = tanhf(s);
  }
  // gh_s = supe @ Whh_s + bhh_s  (384 cols)
  {
    int c = t;
    float s = 0.f;
    for (int d2 = 0; d2 < cH; d2++) s += srow[d2] * Whh_s[d2 * 384 + c];
    gh_s[b * 384 + c] = s + bhh_s[c];
    if (t < cH) {
      int c2 = 256 + t;
      float s2 = 0.f;
      for (int d2 = 0; d2 < cH; d2++) s2 += srow[d2] * Whh_s[d2 * 384 + c2];
      gh_s[b * 384 + c2] = s2 + bhh_s[c2];
    }
  }
  __syncthreads();
  if (t < cH) {
    float s = 0.f;
    for (int d2 = 0; d2 < cH; d2++) s += s2ml[d2] * Wzm2_d[d2 * 128 + t];
    s2mz[b * cH + t] = s;
  }
}

// per-graph attention scores + segment softmax
__global__ __launch_bounds__(256) void attn_k(
    const float* __restrict__ am, const float* __restrict__ asup,
    const float* __restrict__ Wb_d, float* __restrict__ attn)
{
  __shared__ float pw[1024];
  __shared__ float sc[cNC][cK8];
  int b = blockIdx.x, t = threadIdx.x;
  for (int j = 0; j < 4; j++) {
    int c = t + j * 256;
    pw[c] = asup[b * 1024 + c] * Wb_d[c];
  }
  __syncthreads();
  int nl = t >> 3, k = t & 7;
  int n = b * cNC + nl;
  const float* ar = am + (long)n * 1024 + k * 128;
  const float* pr = pw + k * 128;
  float s = 0.f;
  for (int e = 0; e < 128; e++) s += ar[e] * pr[e];
  sc[nl][k] = s;
  __syncthreads();
  float mx = -1e30f;
  for (int i = 0; i < cNC; i++) mx = fmaxf(mx, sc[i][k]);
  float den = 0.f;
  for (int i = 0; i < cNC; i++) den += __expf(sc[i][k] - mx);
  attn[n * cK8 + k] = __expf(s - mx) / den;
}

// per-graph m2s + main_to_super = tanh(m2s @ Wm2s)
__global__ __launch_bounds__(256) void m2s_k(
    const float* __restrict__ attn, const float* __restrict__ msg,
    const float* __restrict__ Wm2s_d, float* __restrict__ mts)
{
  __shared__ float m2s[1024];
  __shared__ float at[cNC][cK8];
  int b = blockIdx.x, t = threadIdx.x;
  at[t >> 3][t & 7] = attn[(b * cNC + (t >> 3)) * cK8 + (t & 7)];
  __syncthreads();
  for (int j = 0; j < 4; j++) {
    int c = t + j * 256;
    int k = c >> 7;
    float s = 0.f;
    for (int i = 0; i < cNC; i++) s += at[i][k] * msg[(long)(b * cNC + i) * 1024 + c];
    m2s[c] = s;
  }
  __syncthreads();
  if (t < cH) {
    float s = 0.f;
    for (int j = 0; j < 1024; j++) s += m2s[j] * Wm2s_d[j * 128 + t];
    mts[b * cH + t] = tanhf(s);
  }
}

__global__ void ew_xgru_k(const float* __restrict__ zmp, const float* __restrict__ s2mz,
                          const float* __restrict__ s2m, const float* __restrict__ ms,
                          const int* __restrict__ vbatch, float* __restrict__ xg){
  int idx = blockIdx.x * 256 + threadIdx.x;
  if (idx >= cNV * cH) return;
  int n = idx >> 7, c = idx & 127;
  int b = vbatch[n];
  float zm = sigm(zmp[idx] + s2mz[b * cH + c]);
  xg[idx] = (1.f - zm) * ms[idx] + zm * s2m[b * cH + c];
}

__global__ void ew_gru_k(const float* __restrict__ gi, const float* __restrict__ gh,
                         float* __restrict__ h){
  int idx = blockIdx.x * 256 + threadIdx.x;
  if (idx >= cNV * cH) return;
  int n = idx >> 7, c = idx & 127;
  const float* gir = gi + (long)n * 384;
  const float* ghr = gh + (long)n * 384;
  float r = sigm(gir[c] + ghr[c]);
  float z = sigm(gir[128 + c] + ghr[128 + c]);
  float nn = tanhf(gir[256 + c] + r * ghr[256 + c]);
  h[idx] = (1.f - z) * nn + z * h[idx];
}

__global__ __launch_bounds__(128) void super_upd_k(
    const float* __restrict__ sself, const float* __restrict__ mts,
    const float* __restrict__ gh_s,
    const float* __restrict__ Wzs1_d, const float* __restrict__ Wzs2_d,
    const float* __restrict__ Wih_s, const float* __restrict__ bih_s,
    float* __restrict__ supe)
{
  __shared__ float ss[cH], mt[cH], xs[cH], sr[cH];
  int b = blockIdx.x, t = threadIdx.x;
  ss[t] = sself[b * cH + t];
  mt[t] = mts[b * cH + t];
  sr[t] = supe[b * cH + t];
  __syncthreads();
  float s1 = 0.f, s2 = 0.f;
  for (int d2 = 0; d2 < cH; d2++) {
    s1 += ss[d2] * Wzs1_d[d2 * 128 + t];
    s2 += mt[d2] * Wzs2_d[d2 * 128 + t];
  }
  float zs = sigm(s1 + s2);
  xs[t] = (1.f - zs) * ss[t] + zs * mt[t];
  __syncthreads();
  float g0 = 0.f, g1 = 0.f, g2 = 0.f;
  for (int d2 = 0; d2 < cH; d2++) {
    float x = xs[d2];
    g0 += x * Wih_s[d2 * 384 + t];
    g1 += x * Wih_s[d2 * 384 + 128 + t];
    g2 += x * Wih_s[d2 * 384 + 256 + t];
  }
  g0 += bih_s[t]; g1 += bih_s[128 + t]; g2 += bih_s[256 + t];
  float r = sigm(g0 + gh_s[b * 384 + t]);
  float z = sigm(g1 + gh_s[b * 384 + 128 + t]);
  float nn = tanhf(g2 + r * gh_s[b * 384 + 256 + t]);
  supe[b * cH + t] = (1.f - z) * nn + z * sr[t];
}

// ---------------- site-graph kernels ----------------
__global__ void scatter_site_k(const float* __restrict__ h, const int* __restrict__ src,
                               const int* __restrict__ dst, float* __restrict__ nei,
                               int dshift){
  long idx = (long)blockIdx.x * 256 + threadIdx.x;
  int din = 1 << dshift;
  if (idx >= (long)cES * din) return;
  int e = (int)(idx >> dshift);
  int c = (int)(idx & (din - 1));
  atomicAdd(&nei[(long)dst[e] * din + c], h[(long)src[e] * din + c]);
}

// ---------------- interaction ----------------
__global__ __launch_bounds__(256) void pair_k(
    const float* __restrict__ pa, const float* __restrict__ pg, float* __restrict__ out)
{
  __shared__ float pal[cNS][cHI];      // 32 KB
  __shared__ float pgl[cNC][cHI + 1];  // padded vs bank conflicts
  int g = blockIdx.x, i = blockIdx.y;
  int t = threadIdx.x;
  for (int l = t; l < cNS * cHI; l += 256) {
    int s = l >> 6, hh = l & 63;
    pal[s][hh] = pa[(long)(g * cNS + s) * 448 + i * 64 + hh];
  }
  for (int l = t; l < cNC * cHI; l += 256) {
    int c = l >> 6, hh = l & 63;
    pgl[c][hh] = pg[(long)(g * cNC + c) * 448 + i * 64 + hh];
  }
  __syncthreads();
  for (int o = t; o < cNS * cNC; o += 256) {
    int s = o >> 5, c = o & 31;
    float sum = 0.f;
    #pragma unroll 8
    for (int hh = 0; hh < cHI; hh++) sum += pal[s][hh] * pgl[c][hh];
    long p = (long)g * (cNS * cNC) + o;
    out[p * 7 + i] = sum;
  }
}

// ---------------- launch ----------------
extern "C" void kernel_launch(void* const* d_in, const int* in_sizes, int n_in,
                              void* d_out, int out_size, void* d_ws, size_t ws_size,
                              hipStream_t stream) {
  // workspace layout (fp32 elements)
  constexpr long OFF_VERT = 0;            // 524288
  constexpr long OFF_SUPE = 524288;       // 16384
  constexpr long OFF_SITE = 1064960;      // 2097152
  constexpr long OFF_ATTN = 3162112;      // 32768
  constexpr long OFF_ASUP = 3194880;      // 131072
  constexpr long OFF_S2M = 3325952;       // 16384
  constexpr long OFF_S2MZ = 3342336;      // 16384
  constexpr long OFF_SSELF = 3358720;     // 16384
  constexpr long OFF_GHS = 3375104;       // 49152
  constexpr long OFF_MTS = 3424256;       // 16384
  constexpr long OFF_NEI = 3440640;       // 524288
  constexpr long OFF_TMPA = 3964928;      // 524288  (nei_s aliases TMPA..XGRU = 2097152)
  constexpr long OFF_MS = 4489216;        // 524288
  constexpr long OFF_ZMP = 5013504;       // 524288
  constexpr long OFF_XGRU = 5537792;      // 524288
  constexpr long OFF_GHM = 6062080;       // 1572864 (pg aliases here in interaction phase)
  constexpr long OFF_GIM = 7634944;       // 1572864
  constexpr long OFF_AM = 9207808;        // 4194304 (pa aliases am..msg in interaction)
  constexpr long OFF_MSG = 13402112;      // 4194304
  constexpr long OFF_H1 = 17596416;       // 2097152
  constexpr long OFF_H2 = 19693568;       // 2097152
  constexpr long OFF_H3 = 21790720;       // 2097152
  constexpr long WS_FLOATS = 23887872;    // ~95.6 MB
  if (ws_size < (size_t)WS_FLOATS * 4) return;  // fail loudly (output stays wrong)

  const float* x_vert  = (const float*)d_in[0];
  const int*   vsrc    = (const int*)d_in[1];
  const int*   vdst    = (const int*)d_in[2];
  const int*   vbatch  = (const int*)d_in[3];
  const float* W_emb   = (const float*)d_in[4];
  const float* b_emb   = (const float*)d_in[5];
  const float* Wa_main = (const float*)d_in[6];
  const float* Wa_super= (const float*)d_in[7];
  const float* Wv      = (const float*)d_in[8];
  const float* Wb      = (const float*)d_in[9];
  const float* Wm2s    = (const float*)d_in[10];
  const float* Ws2m    = (const float*)d_in[11];
  const float* Wsup    = (const float*)d_in[12];
  const float* Wself   = (const float*)d_in[13];
  const float* Wzm1    = (const float*)d_in[14];
  const float* Wzm2    = (const float*)d_in[15];
  const float* Wzs1    = (const float*)d_in[16];
  const float* Wzs2    = (const float*)d_in[17];
  const float* Wih_m   = (const float*)d_in[18];
  const float* Whh_m   = (const float*)d_in[19];
  const float* bih_m   = (const float*)d_in[20];
  const float* bhh_m   = (const float*)d_in[21];
  const float* Wih_s   = (const float*)d_in[22];
  const float* Whh_s   = (const float*)d_in[23];
  const float* bih_s   = (const float*)d_in[24];
  const float* bhh_s   = (const float*)d_in[25];
  const float* x_site  = (const float*)d_in[26];
  const int*   ssrc    = (const int*)d_in[27];
  const int*   sdst    = (const int*)d_in[28];
  const float* W0      = (const float*)d_in[29];
  const float* b0      = (const float*)d_in[30];
  const float* Wconv   = (const float*)d_in[31];
  const float* bconv   = (const float*)d_in[32];
  const float* Wout    = (const float*)d_in[33];
  const float* bout    = (const float*)d_in[34];
  const float* Wis     = (const float*)d_in[35];
  const float* bis     = (const float*)d_in[36];
  const float* Wic     = (const float*)d_in[37];
  const float* bic     = (const float*)d_in[38];
  float* out = (float*)d_out;

  float* ws = (float*)d_ws;
  float* vert = ws + OFF_VERT;
  float* supe = ws + OFF_SUPE;
  float* site = ws + OFF_SITE;
  float* attn = ws + OFF_ATTN;
  float* asup = ws + OFF_ASUP;
  float* s2m = ws + OFF_S2M;
  float* s2mz = ws + OFF_S2MZ;
  float* sself = ws + OFF_SSELF;
  float* gh_s = ws + OFF_GHS;
  float* mts = ws + OFF_MTS;
  float* nei = ws + OFF_NEI;
  float* tmpA = ws + OFF_TMPA;
  float* ms = ws + OFF_MS;
  float* zmp = ws + OFF_ZMP;
  float* xgru = ws + OFF_XGRU;
  float* gh_m = ws + OFF_GHM;
  float* gim = ws + OFF_GIM;
  float* am = ws + OFF_AM;
  float* msg = ws + OFF_MSG;
  float* h1 = ws + OFF_H1;
  float* h2 = ws + OFF_H2;
  float* h3 = ws + OFF_H3;
  float* nei_s = ws + OFF_TMPA;   // alias: site phase only
  float* pa = ws + OFF_AM;        // alias: interaction phase only
  float* pg = ws + OFF_GHM;       // alias: interaction phase only

  auto gemm = [&](const float* A0, const float* A1, const float* A2, const float* A3,
                  int k1, int k2, int k3, int K, int M,
                  const float* W, int ldw, int cshift, int cs, const float* bias,
                  float* C, int N, int act){
    dim3 g(N / 64, (M + 63) / 64);
    gemm_mfma<<<g, 256, 0, stream>>>(A0, A1, A2, A3, k1, k2, k3, K, M,
                                     W, ldw, cshift, cs, bias, C, N, act);
  };
  auto zero = [&](float* p, long n){
    zero_k<<<dim3((unsigned)((n + 255) / 256)), 256, 0, stream>>>(p, n);
  };

  // ---- embedding + super init ----
  gemm(x_vert, x_vert, x_vert, x_vert, 82, 82, 82, 82, cNV,
       W_emb, 128, 30, 0, b_emb, vert, 128, 1);
  supe_init_k<<<cB, 128, 0, stream>>>(vert, supe);

  // ---- GWM iterations ----
  for (int d = 0; d < 3; d++) {
    const float* Wa_main_d = Wa_main + (long)d * 131072;
    const float* Wa_super_d = Wa_super + (long)d * 131072;
    const float* Wv_d = Wv + (long)d * 131072;
    const float* Wb_d = Wb + (long)d * 1024;
    const float* Wm2s_d = Wm2s + (long)d * 131072;
    const float* Ws2m_d = Ws2m + (long)d * 16384;
    const float* Wsup_d = Wsup + (long)d * 16384;
    const float* Wself_d = Wself + (long)d * 16384;
    const float* Wzm1_d = Wzm1 + (long)d * 16384;
    const float* Wzm2_d = Wzm2 + (long)d * 16384;
    const float* Wzs1_d = Wzs1 + (long)d * 16384;
    const float* Wzs2_d = Wzs2 + (long)d * 16384;

    zero(nei, (long)cNV * cH);
    scatter_vert_k<<<(cEV * cH) / 256, 256, 0, stream>>>(vert, vsrc, vdst, nei);
    add_k<<<(cNV * cH) / 256, 256, 0, stream>>>(vert, nei, tmpA, cNV * cH);
    gemm(tmpA, tmpA, tmpA, tmpA, 128, 128, 128, 128, cNV,
         Wself_d, 128, 30, 0, nullptr, ms, 128, 1);                       // main_self
    gemm(vert, vert, vert, vert, 128, 128, 128, 128, cNV,
         Wa_main_d, 128, 7, 16384, nullptr, am, 1024, 2);                 // am = tanh
    gemm(vert, vert, vert, vert, 128, 128, 128, 128, cNV,
         Wv_d, 128, 7, 16384, nullptr, msg, 1024, 0);                     // msg
    gemm(vert, vert, vert, vert, 128, 128, 128, 128, cNV,
         Whh_m, 384, 30, 0, bhh_m, gh_m, 384, 0);                         // gh (GRU)
    supe_pre_k<<<cB, 256, 0, stream>>>(supe, Wa_super_d, Ws2m_d, Wzm2_d, Wsup_d,
                                       Whh_s, bhh_s, asup, s2m, s2mz, sself, gh_s);
    attn_k<<<cB, 256, 0, stream>>>(am, asup, Wb_d, attn);
    m2s_k<<<cB, 256, 0, stream>>>(attn, msg, Wm2s_d, mts);
    gemm(ms, ms, ms, ms, 128, 128, 128, 128, cNV,
         Wzm1_d, 128, 30, 0, nullptr, zmp, 128, 0);
    ew_xgru_k<<<(cNV * cH) / 256, 256, 0, stream>>>(zmp, s2mz, s2m, ms, vbatch, xgru);
    gemm(xgru, xgru, xgru, xgru, 128, 128, 128, 128, cNV,
         Wih_m, 384, 30, 0, bih_m, gim, 384, 0);
    ew_gru_k<<<(cNV * cH) / 256, 256, 0, stream>>>(gim, gh_m, vert);
    super_upd_k<<<cB, 128, 0, stream>>>(sself, mts, gh_s, Wzs1_d, Wzs2_d,
                                        Wih_s, bih_s, supe);
  }

  // ---- AtomConv on protein sites ----
  // iter 0: din=32
  zero(nei_s, (long)cNSITE * 32);
  scatter_site_k<<<((long)cES * 32) / 256, 256, 0, stream>>>(x_site, ssrc, sdst, nei_s, 5);
  gemm(x_site, nei_s, x_site, x_site, 32, 64, 64, 64, cNSITE,
       W0, 128, 30, 0, b0, h1, 128, 1);
  // iter 1
  zero(nei_s, (long)cNSITE * 128);
  scatter_site_k<<<((long)cES * 128) / 256, 256, 0, stream>>>(h1, ssrc, sdst, nei_s, 7);
  gemm(h1, nei_s, h1, h1, 128, 256, 256, 256, cNSITE,
       Wconv, 128, 30, 0, bconv, h2, 128, 1);
  // iter 2
  zero(nei_s, (long)cNSITE * 128);
  scatter_site_k<<<((long)cES * 128) / 256, 256, 0, stream>>>(h2, ssrc, sdst, nei_s, 7);
  gemm(h2, nei_s, h2, h2, 128, 256, 256, 256, cNSITE,
       Wconv + 32768, 128, 30, 0, bconv + 128, h3, 128, 1);
  // site = leaky(concat(x_site, h1, h2, h3) @ Wout + bout)
  gemm(x_site, h1, h2, h3, 32, 160, 288, 416, cNSITE,
       Wout, 128, 30, 0, bout, site, 128, 1);

  // ---- Interaction ----
  gemm(site, site, site, site, 128, 128, 128, 128, cNSITE,
       Wis, 64, 6, 8192, bis, pa, 448, 1);
  gemm(vert, vert, vert, vert, 128, 128, 128, 128, cNV,
       Wic, 64, 6, 8192, bic, pg, 448, 1);
  pair_k<<<dim3(cB, 7), 256, 0, stream>>>(pa, pg, out);
}

// Round 7
// 1253.487 us; speedup vs baseline: 1.1891x; 1.0016x over previous
//
#include <hip/hip_runtime.h>
#include <hip/hip_bf16.h>

// Problem constants (match reference setup_inputs)
static constexpr int cNV = 4096, cEV = 16384, cB = 128, cNC = 32, cNS = 128;
static constexpr int cNSITE = 16384, cES = 131072;
static constexpr int cH = 128, cK8 = 8, cHI = 64;

__device__ __forceinline__ float leakyf(float x){ return x > 0.f ? x : 0.1f * x; }
__device__ __forceinline__ float sigm(float x){ return 1.f / (1.f + __expf(-x)); }

typedef __attribute__((ext_vector_type(4))) short short4v;
typedef __attribute__((ext_vector_type(4))) float f32x4;

__device__ __forceinline__ unsigned short f2bu(float x){
  __hip_bfloat16 h = __float2bfloat16(x);
  return *(unsigned short*)&h;
}

// ---------------- elementwise helpers ----------------
__global__ void zero_k(float* __restrict__ p, long n){
  long i = (long)blockIdx.x * 256 + threadIdx.x;
  if (i < n) p[i] = 0.f;
}

// ---------------- MFMA segmented-A GEMM ----------------
// C[M,N] = act( concat_K(A0..A3) @ W + bias ), A/W fp32 in memory, bf16 MFMA
// compute with fp32 accumulate. W column addressing via (cshift, cs).
// Tile 64x64, 4 waves (2x2), per-wave 32x32 via 2x2 mfma_f32_16x16x16bf16_1k.
// XCD-aware swizzle: consecutive native block ids round-robin over 8 XCDs;
// remap so each XCD owns a contiguous y-chunk (A-rows) -> A stays in its L2.
// addA (optional): A := A0 + addA elementwise (requires single segment k1==K).
__global__ __launch_bounds__(256) void gemm_mfma(
    const float* __restrict__ A0, const float* __restrict__ A1,
    const float* __restrict__ A2, const float* __restrict__ A3,
    const float* __restrict__ addA,
    int k1, int k2, int k3, int K, int M,
    const float* __restrict__ W, int ldw, int cshift, int cs,
    const float* __restrict__ bias,
    float* __restrict__ C, int N, int act)
{
  __shared__ __align__(16) unsigned short As[64 * 40];  // [row][40] bf16, k contiguous
  __shared__ __align__(16) unsigned short Bs[64 * 40];  // [col][40] bf16, k contiguous
  const int t = threadIdx.x;
  const int l = t & 63, w = t >> 6;
  const int wr = w >> 1, wc = w & 1;

  // bijective XCD swizzle (grid size is always a multiple of 8 here)
  const int nwg = gridDim.x * gridDim.y;
  const int bid = blockIdx.y * gridDim.x + blockIdx.x;
  const int cpx = nwg >> 3;
  const int swz = (bid & 7) * cpx + (bid >> 3);
  const int bx = swz % gridDim.x, by = swz / gridDim.x;

  const int m0 = by * 64, n0 = bx * 64;
  const long wbase = (long)(n0 >> cshift) * cs + (long)(n0 & ((1 << cshift) - 1));
  const int w1 = k2 - k1, w2 = k3 - k2, w3 = K - k3;

  f32x4 acc[2][2];
  #pragma unroll
  for (int i = 0; i < 2; i++)
    #pragma unroll
    for (int j = 0; j < 2; j++)
      acc[i][j] = (f32x4){0.f, 0.f, 0.f, 0.f};

  const int arow = t >> 2, akq = (t & 3) * 8;   // A: 8 consecutive k per thread
  const int bcol = t & 63, bkq = (t >> 6) * 8;  // B: coalesced over columns
  const int lr = l & 15, lh = l >> 4;

  for (int kt = 0; kt < K; kt += 32) {
    // ---- stage A tile (64 rows x 32 k) as bf16 ----
    {
      const int mg = m0 + arow;
      float av[8];
      #pragma unroll
      for (int j = 0; j < 8; j++) {
        int kg = kt + akq + j;
        float v = 0.f;
        if (kg < K) {
          if (kg < k1)      v = A0[(long)mg * k1 + kg];
          else if (kg < k2) v = A1[(long)mg * w1 + (kg - k1)];
          else if (kg < k3) v = A2[(long)mg * w2 + (kg - k2)];
          else              v = A3[(long)mg * w3 + (kg - k3)];
          if (addA != nullptr) v += addA[(long)mg * k1 + kg];
        }
        av[j] = v;
      }
      uint4 pk;
      pk.x = (unsigned)f2bu(av[0]) | ((unsigned)f2bu(av[1]) << 16);
      pk.y = (unsigned)f2bu(av[2]) | ((unsigned)f2bu(av[3]) << 16);
      pk.z = (unsigned)f2bu(av[4]) | ((unsigned)f2bu(av[5]) << 16);
      pk.w = (unsigned)f2bu(av[6]) | ((unsigned)f2bu(av[7]) << 16);
      *(uint4*)&As[arow * 40 + akq] = pk;
    }
    // ---- stage B tile (64 cols x 32 k) as bf16, transposed to [col][k] ----
    {
      float bv[8];
      #pragma unroll
      for (int j = 0; j < 8; j++) {
        int kg = kt + bkq + j;
        bv[j] = (kg < K) ? W[(long)kg * ldw + wbase + bcol] : 0.f;
      }
      uint4 pk;
      pk.x = (unsigned)f2bu(bv[0]) | ((unsigned)f2bu(bv[1]) << 16);
      pk.y = (unsigned)f2bu(bv[2]) | ((unsigned)f2bu(bv[3]) << 16);
      pk.z = (unsigned)f2bu(bv[4]) | ((unsigned)f2bu(bv[5]) << 16);
      pk.w = (unsigned)f2bu(bv[6]) | ((unsigned)f2bu(bv[7]) << 16);
      *(uint4*)&Bs[bcol * 40 + bkq] = pk;
    }
    __syncthreads();
    // ---- compute: 2 k-substeps x 2x2 tiles of 16x16x16 bf16 MFMA ----
    #pragma unroll
    for (int ks = 0; ks < 2; ks++) {
      short4v a0 = *(short4v*)&As[(wr * 32 + 0 * 16 + lr) * 40 + ks * 16 + lh * 4];
      short4v a1 = *(short4v*)&As[(wr * 32 + 1 * 16 + lr) * 40 + ks * 16 + lh * 4];
      short4v b0 = *(short4v*)&Bs[(wc * 32 + 0 * 16 + lr) * 40 + ks * 16 + lh * 4];
      short4v b1 = *(short4v*)&Bs[(wc * 32 + 1 * 16 + lr) * 40 + ks * 16 + lh * 4];
      acc[0][0] = __builtin_amdgcn_mfma_f32_16x16x16bf16_1k(a0, b0, acc[0][0], 0, 0, 0);
      acc[0][1] = __builtin_amdgcn_mfma_f32_16x16x16bf16_1k(a0, b1, acc[0][1], 0, 0, 0);
      acc[1][0] = __builtin_amdgcn_mfma_f32_16x16x16bf16_1k(a1, b0, acc[1][0], 0, 0, 0);
      acc[1][1] = __builtin_amdgcn_mfma_f32_16x16x16bf16_1k(a1, b1, acc[1][1], 0, 0, 0);
    }
    __syncthreads();
  }
  // ---- epilogue: bias + activation, fp32 store ----
  #pragma unroll
  for (int ri = 0; ri < 2; ri++) {
    #pragma unroll
    for (int ci = 0; ci < 2; ci++) {
      int col = n0 + wc * 32 + ci * 16 + lr;
      float bv = (bias != nullptr) ? bias[col] : 0.f;
      #pragma unroll
      for (int e = 0; e < 4; e++) {
        int row = m0 + wr * 32 + ri * 16 + lh * 4 + e;
        float v = acc[ri][ci][e] + bv;
        if (act == 1) v = leakyf(v);
        else if (act == 2) v = tanhf(v);
        else if (act == 3) v = sigm(v);
        C[(long)row * N + col] = v;
      }
    }
  }
}

// ---------------- compound-graph kernels ----------------
__global__ void supe_init_k(const float* __restrict__ vert, float* __restrict__ supe){
  int b = blockIdx.x, c = threadIdx.x;
  float s = 0.f;
  for (int i = 0; i < cNC; i++) s += vert[(b * cNC + i) * cH + c];
  supe[b * cH + c] = s;
}

__global__ void scatter_vert_k(const float* __restrict__ vert, const int* __restrict__ src,
                               const int* __restrict__ dst, float* __restrict__ nei){
  int idx = blockIdx.x * 256 + threadIdx.x;
  if (idx >= cEV * cH) return;
  int e = idx >> 7, c = idx & 127;
  atomicAdd(&nei[dst[e] * cH + c], vert[src[e] * cH + c]);
}

// per-graph super-node precompute: asup, s2m, s2mz, super_self, gh_s
__global__ __launch_bounds__(256) void supe_pre_k(
    const float* __restrict__ supe,
    const float* __restrict__ Wa_super_d, const float* __restrict__ Ws2m_d,
    const float* __restrict__ Wzm2_d, const float* __restrict__ Wsup_d,
    const float* __restrict__ Whh_s, const float* __restrict__ bhh_s,
    float* __restrict__ asup, float* __restrict__ s2m, float* __restrict__ s2mz,
    float* __restrict__ sself, float* __restrict__ gh_s)
{
  __shared__ float srow[cH];
  __shared__ float s2ml[cH];
  int b = blockIdx.x, t = threadIdx.x;
  if (t < cH) srow[t] = supe[b * cH + t];
  __syncthreads();
  // asup[b, 0:1024]
  for (int j = 0; j < 4; j++) {
    int c = t + j * 256;
    int head = c >> 7, e = c & 127;
    const float* Wp = Wa_super_d + head * 16384 + e;
    float s = 0.f;
    for (int d2 = 0; d2 < cH; d2++) s += srow[d2] * Wp[d2 * 128];
    asup[b * 1024 + c] = tanhf(s);
  }
  if (t < cH) {
    float s = 0.f;
    for (int d2 = 0; d2 < cH; d2++) s += srow[d2] * Ws2m_d[d2 * 128 + t];
    float v = tanhf(s);
    s2ml[t] = v; s2m[b * cH + t] = v;
  } else {
    int c = t - cH;
    float s = 0.f;
    for (int d2 = 0; d2 < cH; d2++) s += srow[d2] * Wsup_d[d2 * 128 + c];
    sself[b * cH + c] = tanhf(s);
  }
  // gh_s = supe @ Whh_s + bhh_s  (384 cols)
  {
    int c = t;
    float s = 0.f;
    for (int d2 = 0; d2 < cH; d2++) s += srow[d2] * Whh_s[d2 * 384 + c];
    gh_s[b * 384 + c] = s + bhh_s[c];
    if (t < cH) {
      int c2 = 256 + t;
      float s2 = 0.f;
      for (int d2 = 0; d2 < cH; d2++) s2 += srow[d2] * Whh_s[d2 * 384 + c2];
      gh_s[b * 384 + c2] = s2 + bhh_s[c2];
    }
  }
  __syncthreads();
  if (t < cH) {
    float s = 0.f;
    for (int d2 = 0; d2 < cH; d2++) s += s2ml[d2] * Wzm2_d[d2 * 128 + t];
    s2mz[b * cH + t] = s;
  }
}

// per-graph attention scores + segment softmax
__global__ __launch_bounds__(256) void attn_k(
    const float* __restrict__ am, const float* __restrict__ asup,
    const float* __restrict__ Wb_d, float* __restrict__ attn)
{
  __shared__ float pw[1024];
  __shared__ float sc[cNC][cK8];
  int b = blockIdx.x, t = threadIdx.x;
  for (int j = 0; j < 4; j++) {
    int c = t + j * 256;
    pw[c] = asup[b * 1024 + c] * Wb_d[c];
  }
  __syncthreads();
  int nl = t >> 3, k = t & 7;
  int n = b * cNC + nl;
  const float* ar = am + (long)n * 1024 + k * 128;
  const float* pr = pw + k * 128;
  float s = 0.f;
  for (int e = 0; e < 128; e++) s += ar[e] * pr[e];
  sc[nl][k] = s;
  __syncthreads();
  float mx = -1e30f;
  for (int i = 0; i < cNC; i++) mx = fmaxf(mx, sc[i][k]);
  float den = 0.f;
  for (int i = 0; i < cNC; i++) den += __expf(sc[i][k] - mx);
  attn[n * cK8 + k] = __expf(s - mx) / den;
}

// per-graph m2s + main_to_super = tanh(m2s @ Wm2s)
__global__ __launch_bounds__(256) void m2s_k(
    const float* __restrict__ attn, const float* __restrict__ msg,
    const float* __restrict__ Wm2s_d, float* __restrict__ mts)
{
  __shared__ float m2s[1024];
  __shared__ float at[cNC][cK8];
  int b = blockIdx.x, t = threadIdx.x;
  at[t >> 3][t & 7] = attn[(b * cNC + (t >> 3)) * cK8 + (t & 7)];
  __syncthreads();
  for (int j = 0; j < 4; j++) {
    int c = t + j * 256;
    int k = c >> 7;
    float s = 0.f;
    for (int i = 0; i < cNC; i++) s += at[i][k] * msg[(long)(b * cNC + i) * 1024 + c];
    m2s[c] = s;
  }
  __syncthreads();
  if (t < cH) {
    float s = 0.f;
    for (int j = 0; j < 1024; j++) s += m2s[j] * Wm2s_d[j * 128 + t];
    mts[b * cH + t] = tanhf(s);
  }
}

__global__ void ew_xgru_k(const float* __restrict__ zmp, const float* __restrict__ s2mz,
                          const float* __restrict__ s2m, const float* __restrict__ ms,
                          const int* __restrict__ vbatch, float* __restrict__ xg){
  int idx = blockIdx.x * 256 + threadIdx.x;
  if (idx >= cNV * cH) return;
  int n = idx >> 7, c = idx & 127;
  int b = vbatch[n];
  float zm = sigm(zmp[idx] + s2mz[b * cH + c]);
  xg[idx] = (1.f - zm) * ms[idx] + zm * s2m[b * cH + c];
}

__global__ void ew_gru_k(const float* __restrict__ gi, const float* __restrict__ gh,
                         float* __restrict__ h){
  int idx = blockIdx.x * 256 + threadIdx.x;
  if (idx >= cNV * cH) return;
  int n = idx >> 7, c = idx & 127;
  const float* gir = gi + (long)n * 384;
  const float* ghr = gh + (long)n * 384;
  float r = sigm(gir[c] + ghr[c]);
  float z = sigm(gir[128 + c] + ghr[128 + c]);
  float nn = tanhf(gir[256 + c] + r * ghr[256 + c]);
  h[idx] = (1.f - z) * nn + z * h[idx];
}

__global__ __launch_bounds__(128) void super_upd_k(
    const float* __restrict__ sself, const float* __restrict__ mts,
    const float* __restrict__ gh_s,
    const float* __restrict__ Wzs1_d, const float* __restrict__ Wzs2_d,
    const float* __restrict__ Wih_s, const float* __restrict__ bih_s,
    float* __restrict__ supe)
{
  __shared__ float ss[cH], mt[cH], xs[cH], sr[cH];
  int b = blockIdx.x, t = threadIdx.x;
  ss[t] = sself[b * cH + t];
  mt[t] = mts[b * cH + t];
  sr[t] = supe[b * cH + t];
  __syncthreads();
  float s1 = 0.f, s2 = 0.f;
  for (int d2 = 0; d2 < cH; d2++) {
    s1 += ss[d2] * Wzs1_d[d2 * 128 + t];
    s2 += mt[d2] * Wzs2_d[d2 * 128 + t];
  }
  float zs = sigm(s1 + s2);
  xs[t] = (1.f - zs) * ss[t] + zs * mt[t];
  __syncthreads();
  float g0 = 0.f, g1 = 0.f, g2 = 0.f;
  for (int d2 = 0; d2 < cH; d2++) {
    float x = xs[d2];
    g0 += x * Wih_s[d2 * 384 + t];
    g1 += x * Wih_s[d2 * 384 + 128 + t];
    g2 += x * Wih_s[d2 * 384 + 256 + t];
  }
  g0 += bih_s[t]; g1 += bih_s[128 + t]; g2 += bih_s[256 + t];
  float r = sigm(g0 + gh_s[b * 384 + t]);
  float z = sigm(g1 + gh_s[b * 384 + 128 + t]);
  float nn = tanhf(g2 + r * gh_s[b * 384 + 256 + t]);
  supe[b * cH + t] = (1.f - z) * nn + z * sr[t];
}

// ---------------- site-graph kernels ----------------
__global__ void scatter_site_k(const float* __restrict__ h, const int* __restrict__ src,
                               const int* __restrict__ dst, float* __restrict__ nei,
                               int dshift){
  long idx = (long)blockIdx.x * 256 + threadIdx.x;
  int din = 1 << dshift;
  if (idx >= (long)cES * din) return;
  int e = (int)(idx >> dshift);
  int c = (int)(idx & (din - 1));
  atomicAdd(&nei[(long)dst[e] * din + c], h[(long)src[e] * din + c]);
}

// ---------------- interaction ----------------
__global__ __launch_bounds__(256) void pair_k(
    const float* __restrict__ pa, const float* __restrict__ pg, float* __restrict__ out)
{
  __shared__ float pal[cNS][cHI];      // 32 KB
  __shared__ float pgl[cNC][cHI + 1];  // padded vs bank conflicts
  int g = blockIdx.x, i = blockIdx.y;
  int t = threadIdx.x;
  for (int l = t; l < cNS * cHI; l += 256) {
    int s = l >> 6, hh = l & 63;
    pal[s][hh] = pa[(long)(g * cNS + s) * 448 + i * 64 + hh];
  }
  for (int l = t; l < cNC * cHI; l += 256) {
    int c = l >> 6, hh = l & 63;
    pgl[c][hh] = pg[(long)(g * cNC + c) * 448 + i * 64 + hh];
  }
  __syncthreads();
  for (int o = t; o < cNS * cNC; o += 256) {
    int s = o >> 5, c = o & 31;
    float sum = 0.f;
    #pragma unroll 8
    for (int hh = 0; hh < cHI; hh++) sum += pal[s][hh] * pgl[c][hh];
    long p = (long)g * (cNS * cNC) + o;
    out[p * 7 + i] = sum;
  }
}

// ---------------- launch ----------------
extern "C" void kernel_launch(void* const* d_in, const int* in_sizes, int n_in,
                              void* d_out, int out_size, void* d_ws, size_t ws_size,
                              hipStream_t stream) {
  // workspace layout (fp32 elements)
  constexpr long OFF_VERT = 0;            // 524288
  constexpr long OFF_SUPE = 524288;       // 16384
  constexpr long OFF_SITE = 1064960;      // 2097152
  constexpr long OFF_ATTN = 3162112;      // 32768
  constexpr long OFF_ASUP = 3194880;      // 131072
  constexpr long OFF_S2M = 3325952;       // 16384
  constexpr long OFF_S2MZ = 3342336;      // 16384
  constexpr long OFF_SSELF = 3358720;     // 16384
  constexpr long OFF_GHS = 3375104;       // 49152
  constexpr long OFF_MTS = 3424256;       // 16384
  constexpr long OFF_NEI = 3440640;       // 524288
  constexpr long OFF_TMPA = 3964928;      // 524288  (nei_s aliases TMPA..XGRU = 2097152)
  constexpr long OFF_MS = 4489216;        // 524288
  constexpr long OFF_ZMP = 5013504;       // 524288
  constexpr long OFF_XGRU = 5537792;      // 524288
  constexpr long OFF_GHM = 6062080;       // 1572864 (pg aliases here in interaction phase)
  constexpr long OFF_GIM = 7634944;       // 1572864
  constexpr long OFF_AM = 9207808;        // 4194304 (pa aliases am..msg in interaction)
  constexpr long OFF_MSG = 13402112;      // 4194304
  constexpr long OFF_H1 = 17596416;       // 2097152
  constexpr long OFF_H2 = 19693568;       // 2097152
  constexpr long OFF_H3 = 21790720;       // 2097152
  constexpr long WS_FLOATS = 23887872;    // ~95.6 MB
  if (ws_size < (size_t)WS_FLOATS * 4) return;  // fail loudly (output stays wrong)

  const float* x_vert  = (const float*)d_in[0];
  const int*   vsrc    = (const int*)d_in[1];
  const int*   vdst    = (const int*)d_in[2];
  const int*   vbatch  = (const int*)d_in[3];
  const float* W_emb   = (const float*)d_in[4];
  const float* b_emb   = (const float*)d_in[5];
  const float* Wa_main = (const float*)d_in[6];
  const float* Wa_super= (const float*)d_in[7];
  const float* Wv      = (const float*)d_in[8];
  const float* Wb      = (const float*)d_in[9];
  const float* Wm2s    = (const float*)d_in[10];
  const float* Ws2m    = (const float*)d_in[11];
  const float* Wsup    = (const float*)d_in[12];
  const float* Wself   = (const float*)d_in[13];
  const float* Wzm1    = (const float*)d_in[14];
  const float* Wzm2    = (const float*)d_in[15];
  const float* Wzs1    = (const float*)d_in[16];
  const float* Wzs2    = (const float*)d_in[17];
  const float* Wih_m   = (const float*)d_in[18];
  const float* Whh_m   = (const float*)d_in[19];
  const float* bih_m   = (const float*)d_in[20];
  const float* bhh_m   = (const float*)d_in[21];
  const float* Wih_s   = (const float*)d_in[22];
  const float* Whh_s   = (const float*)d_in[23];
  const float* bih_s   = (const float*)d_in[24];
  const float* bhh_s   = (const float*)d_in[25];
  const float* x_site  = (const float*)d_in[26];
  const int*   ssrc    = (const int*)d_in[27];
  const int*   sdst    = (const int*)d_in[28];
  const float* W0      = (const float*)d_in[29];
  const float* b0      = (const float*)d_in[30];
  const float* Wconv   = (const float*)d_in[31];
  const float* bconv   = (const float*)d_in[32];
  const float* Wout    = (const float*)d_in[33];
  const float* bout    = (const float*)d_in[34];
  const float* Wis     = (const float*)d_in[35];
  const float* bis     = (const float*)d_in[36];
  const float* Wic     = (const float*)d_in[37];
  const float* bic     = (const float*)d_in[38];
  float* out = (float*)d_out;

  float* ws = (float*)d_ws;
  float* vert = ws + OFF_VERT;
  float* supe = ws + OFF_SUPE;
  float* site = ws + OFF_SITE;
  float* attn = ws + OFF_ATTN;
  float* asup = ws + OFF_ASUP;
  float* s2m = ws + OFF_S2M;
  float* s2mz = ws + OFF_S2MZ;
  float* sself = ws + OFF_SSELF;
  float* gh_s = ws + OFF_GHS;
  float* mts = ws + OFF_MTS;
  float* nei = ws + OFF_NEI;
  float* ms = ws + OFF_MS;
  float* zmp = ws + OFF_ZMP;
  float* xgru = ws + OFF_XGRU;
  float* gh_m = ws + OFF_GHM;
  float* gim = ws + OFF_GIM;
  float* am = ws + OFF_AM;
  float* msg = ws + OFF_MSG;
  float* h1 = ws + OFF_H1;
  float* h2 = ws + OFF_H2;
  float* h3 = ws + OFF_H3;
  float* nei_s = ws + OFF_TMPA;   // alias: site phase only
  float* pa = ws + OFF_AM;        // alias: interaction phase only
  float* pg = ws + OFF_GHM;       // alias: interaction phase only

  auto gemm = [&](const float* A0, const float* A1, const float* A2, const float* A3,
                  int k1, int k2, int k3, int K, int M,
                  const float* W, int ldw, int cshift, int cs, const float* bias,
                  float* C, int N, int act, const float* addA = nullptr){
    dim3 g(N / 64, (M + 63) / 64);
    gemm_mfma<<<g, 256, 0, stream>>>(A0, A1, A2, A3, addA, k1, k2, k3, K, M,
                                     W, ldw, cshift, cs, bias, C, N, act);
  };
  auto zero = [&](float* p, long n){
    zero_k<<<dim3((unsigned)((n + 255) / 256)), 256, 0, stream>>>(p, n);
  };

  // ---- embedding + super init ----
  gemm(x_vert, x_vert, x_vert, x_vert, 82, 82, 82, 82, cNV,
       W_emb, 128, 30, 0, b_emb, vert, 128, 1);
  supe_init_k<<<cB, 128, 0, stream>>>(vert, supe);

  // ---- GWM iterations ----
  for (int d = 0; d < 3; d++) {
    const float* Wa_main_d = Wa_main + (long)d * 131072;
    const float* Wa_super_d = Wa_super + (long)d * 131072;
    const float* Wv_d = Wv + (long)d * 131072;
    const float* Wb_d = Wb + (long)d * 1024;
    const float* Wm2s_d = Wm2s + (long)d * 131072;
    const float* Ws2m_d = Ws2m + (long)d * 16384;
    const float* Wsup_d = Wsup + (long)d * 16384;
    const float* Wself_d = Wself + (long)d * 16384;
    const float* Wzm1_d = Wzm1 + (long)d * 16384;
    const float* Wzm2_d = Wzm2 + (long)d * 16384;
    const float* Wzs1_d = Wzs1 + (long)d * 16384;
    const float* Wzs2_d = Wzs2 + (long)d * 16384;

    zero(nei, (long)cNV * cH);
    scatter_vert_k<<<(cEV * cH) / 256, 256, 0, stream>>>(vert, vsrc, vdst, nei);
    gemm(vert, vert, vert, vert, 128, 128, 128, 128, cNV,
         Wself_d, 128, 30, 0, nullptr, ms, 128, 1, nei);                  // main_self (A=vert+nei)
    gemm(vert, vert, vert, vert, 128, 128, 128, 128, cNV,
         Wa_main_d, 128, 7, 16384, nullptr, am, 1024, 2);                 // am = tanh
    gemm(vert, vert, vert, vert, 128, 128, 128, 128, cNV,
         Wv_d, 128, 7, 16384, nullptr, msg, 1024, 0);                     // msg
    gemm(vert, vert, vert, vert, 128, 128, 128, 128, cNV,
         Whh_m, 384, 30, 0, bhh_m, gh_m, 384, 0);                         // gh (GRU)
    supe_pre_k<<<cB, 256, 0, stream>>>(supe, Wa_super_d, Ws2m_d, Wzm2_d, Wsup_d,
                                       Whh_s, bhh_s, asup, s2m, s2mz, sself, gh_s);
    attn_k<<<cB, 256, 0, stream>>>(am, asup, Wb_d, attn);
    m2s_k<<<cB, 256, 0, stream>>>(attn, msg, Wm2s_d, mts);
    gemm(ms, ms, ms, ms, 128, 128, 128, 128, cNV,
         Wzm1_d, 128, 30, 0, nullptr, zmp, 128, 0);
    ew_xgru_k<<<(cNV * cH) / 256, 256, 0, stream>>>(zmp, s2mz, s2m, ms, vbatch, xgru);
    gemm(xgru, xgru, xgru, xgru, 128, 128, 128, 128, cNV,
         Wih_m, 384, 30, 0, bih_m, gim, 384, 0);
    ew_gru_k<<<(cNV * cH) / 256, 256, 0, stream>>>(gim, gh_m, vert);
    super_upd_k<<<cB, 128, 0, stream>>>(sself, mts, gh_s, Wzs1_d, Wzs2_d,
                                        Wih_s, bih_s, supe);
  }

  // ---- AtomConv on protein sites ----
  // iter 0: din=32
  zero(nei_s, (long)cNSITE * 32);
  scatter_site_k<<<((long)cES * 32) / 256, 256, 0, stream>>>(x_site, ssrc, sdst, nei_s, 5);
  gemm(x_site, nei_s, x_site, x_site, 32, 64, 64, 64, cNSITE,
       W0, 128, 30, 0, b0, h1, 128, 1);
  // iter 1
  zero(nei_s, (long)cNSITE * 128);
  scatter_site_k<<<((long)cES * 128) / 256, 256, 0, stream>>>(h1, ssrc, sdst, nei_s, 7);
  gemm(h1, nei_s, h1, h1, 128, 256, 256, 256, cNSITE,
       Wconv, 128, 30, 0, bconv, h2, 128, 1);
  // iter 2
  zero(nei_s, (long)cNSITE * 128);
  scatter_site_k<<<((long)cES * 128) / 256, 256, 0, stream>>>(h2, ssrc, sdst, nei_s, 7);
  gemm(h2, nei_s, h2, h2, 128, 256, 256, 256, cNSITE,
       Wconv + 32768, 128, 30, 0, bconv + 128, h3, 128, 1);
  // site = leaky(concat(x_site, h1, h2, h3) @ Wout + bout)
  gemm(x_site, h1, h2, h3, 32, 160, 288, 416, cNSITE,
       Wout, 128, 30, 0, bout, site, 128, 1);

  // ---- Interaction ----
  gemm(site, site, site, site, 128, 128, 128, 128, cNSITE,
       Wis, 64, 6, 8192, bis, pa, 448, 1);
  gemm(vert, vert, vert, vert, 128, 128, 128, 128, cNV,
       Wic, 64, 6, 8192, bic, pg, 448, 1);
  pair_k<<<dim3(cB, 7), 256, 0, stream>>>(pa, pg, out);
}

// Round 8
// 1180.441 us; speedup vs baseline: 1.2626x; 1.0619x over previous
//
#include <hip/hip_runtime.h>
#include <hip/hip_bf16.h>

// Problem constants (match reference setup_inputs)
static constexpr int cNV = 4096, cEV = 16384, cB = 128, cNC = 32, cNS = 128;
static constexpr int cNSITE = 16384, cES = 131072;
static constexpr int cH = 128, cK8 = 8, cHI = 64;

__device__ __forceinline__ float leakyf(float x){ return x > 0.f ? x : 0.1f * x; }
__device__ __forceinline__ float sigm(float x){ return 1.f / (1.f + __expf(-x)); }

typedef __attribute__((ext_vector_type(4))) short short4v;
typedef __attribute__((ext_vector_type(4))) float f32x4;

__device__ __forceinline__ unsigned short f2bu(float x){
  __hip_bfloat16 h = __float2bfloat16(x);
  return *(unsigned short*)&h;
}

// ---------------- elementwise helpers ----------------
__global__ void zero_k(float* __restrict__ p, long n){
  long i = (long)blockIdx.x * 256 + threadIdx.x;
  if (i < n) p[i] = 0.f;
}

// ---------------- grouped MFMA GEMM ----------------
// C_s[M,N_s] = act_s( concat_K(A0..A3) @ W_s + bias_s ) for up to 4 weight
// segments s sharing the same A. fp32 in memory, bf16 MFMA, fp32 accumulate.
// K chunked by 128 with ONE barrier per chunk. Tile 64x64, 4 waves (2x2),
// per-wave 32x32 via 2x2 mfma_f32_16x16x16bf16_1k per k-16.
// W col addressing: addr(k,c) = k*ldw + (c>>cshift)*cs + (c & mask).
// act: 0 none, 1 leaky, 2 tanh, 3 sigm,
//      4 xgru-fuse: zm=sigm(v+ep1[b*128+col]); v=(1-zm)*A0[row,col]+zm*ep2[b*128+col]
//         (requires single segment, N==K==128; b=row>>5)
// addA_s: optional elementwise add to A during staging (requires k1==K).
struct GSegs {
  const float* W[4];
  const float* bias[4];
  const float* addA[4];
  float* C[4];
  int nb_end[4];   // exclusive end in global n-block space
  int N[4];
  int ldw[4];
  int cshift[4];
  int cs[4];
  int act[4];
  int nsegs;
};

__global__ __launch_bounds__(256) void gemm_g(
    const float* __restrict__ A0, const float* __restrict__ A1,
    const float* __restrict__ A2, const float* __restrict__ A3,
    int k1, int k2, int k3, int K, int M,
    GSegs segs, const float* __restrict__ ep1, const float* __restrict__ ep2)
{
  __shared__ __align__(16) unsigned short As[64 * 136];
  __shared__ __align__(16) unsigned short Bs[64 * 136];
  const int t = threadIdx.x;
  const int l = t & 63, w = t >> 6;
  const int wr = w >> 1, wc = w & 1;
  const int lr = l & 15, lh = l >> 4;

  // bijective XCD swizzle (all grids here are multiples of 8 blocks)
  const int nwg = gridDim.x * gridDim.y;
  const int bid = blockIdx.y * gridDim.x + blockIdx.x;
  const int cpx = nwg >> 3;
  const int swz = (bid & 7) * cpx + (bid >> 3);
  const int bx = swz % gridDim.x, by = swz / gridDim.x;

  // segment select (compile-time indices only)
  const float* W = nullptr; const float* bias = nullptr;
  const float* addA = nullptr; float* C = nullptr;
  int Nn = 0, ldw = 0, cshift = 0, cs = 0, act = 0, nb0 = 0;
  {
    int nbs = 0;
    #pragma unroll
    for (int s = 0; s < 4; s++) {
      if (s < segs.nsegs) {
        int e = segs.nb_end[s];
        if (bx >= nbs && bx < e) {
          W = segs.W[s]; bias = segs.bias[s]; addA = segs.addA[s]; C = segs.C[s];
          Nn = segs.N[s]; ldw = segs.ldw[s]; cshift = segs.cshift[s];
          cs = segs.cs[s]; act = segs.act[s]; nb0 = nbs;
        }
        nbs = e;
      }
    }
  }
  const int n0 = (bx - nb0) * 64;
  const int m0 = by * 64;
  const long wbase = (long)(n0 >> cshift) * cs + (long)(n0 & ((1 << cshift) - 1));
  const int w1 = k2 - k1, w2 = k3 - k2;

  f32x4 acc[2][2];
  #pragma unroll
  for (int i = 0; i < 2; i++)
    #pragma unroll
    for (int j = 0; j < 2; j++)
      acc[i][j] = (f32x4){0.f, 0.f, 0.f, 0.f};

  const int arow = t >> 2, ak0 = (t & 3) * 32;   // A: 32 consecutive k / thread
  const int bcol = t & 63, bk0 = (t >> 6) * 32;  // B: coalesced over columns
  const int mg = m0 + arow;

  for (int kt = 0; kt < K; kt += 128) {
    // ---- stage A slab (64 rows x 128 k) as bf16 (float2 loads) ----
    #pragma unroll
    for (int j = 0; j < 16; j++) {
      int kg = kt + ak0 + j * 2;
      float2 v = make_float2(0.f, 0.f);
      if (kg < K) {  // K and all segment boundaries are even
        if (kg < k1)      v = *(const float2*)&A0[(long)mg * k1 + kg];
        else if (kg < k2) v = *(const float2*)&A1[(long)mg * w1 + (kg - k1)];
        else if (kg < k3) v = *(const float2*)&A2[(long)mg * w2 + (kg - k2)];
        else              v = *(const float2*)&A3[(long)mg * (K - k3) + (kg - k3)];
        if (addA != nullptr) {
          float2 a = *(const float2*)&addA[(long)mg * k1 + kg];
          v.x += a.x; v.y += a.y;
        }
      }
      *(unsigned*)&As[arow * 136 + ak0 + j * 2] =
          (unsigned)f2bu(v.x) | ((unsigned)f2bu(v.y) << 16);
    }
    // ---- stage B slab (64 cols x 128 k) as bf16, [col][k] ----
    #pragma unroll
    for (int j = 0; j < 16; j++) {
      int kg = kt + bk0 + j * 2;
      float v0 = (kg < K) ? W[(long)kg * ldw + wbase + bcol] : 0.f;
      float v1 = (kg + 1 < K) ? W[(long)(kg + 1) * ldw + wbase + bcol] : 0.f;
      *(unsigned*)&Bs[bcol * 136 + bk0 + j * 2] =
          (unsigned)f2bu(v0) | ((unsigned)f2bu(v1) << 16);
    }
    __syncthreads();
    // ---- compute: 8 k-substeps, 2x2 fragments ----
    #pragma unroll
    for (int ks = 0; ks < 8; ks++) {
      short4v a0 = *(short4v*)&As[(wr * 32 + 0 * 16 + lr) * 136 + ks * 16 + lh * 4];
      short4v a1 = *(short4v*)&As[(wr * 32 + 1 * 16 + lr) * 136 + ks * 16 + lh * 4];
      short4v b0 = *(short4v*)&Bs[(wc * 32 + 0 * 16 + lr) * 136 + ks * 16 + lh * 4];
      short4v b1 = *(short4v*)&Bs[(wc * 32 + 1 * 16 + lr) * 136 + ks * 16 + lh * 4];
      acc[0][0] = __builtin_amdgcn_mfma_f32_16x16x16bf16_1k(a0, b0, acc[0][0], 0, 0, 0);
      acc[0][1] = __builtin_amdgcn_mfma_f32_16x16x16bf16_1k(a0, b1, acc[0][1], 0, 0, 0);
      acc[1][0] = __builtin_amdgcn_mfma_f32_16x16x16bf16_1k(a1, b0, acc[1][0], 0, 0, 0);
      acc[1][1] = __builtin_amdgcn_mfma_f32_16x16x16bf16_1k(a1, b1, acc[1][1], 0, 0, 0);
    }
    __syncthreads();
  }
  // ---- epilogue ----
  #pragma unroll
  for (int ri = 0; ri < 2; ri++) {
    #pragma unroll
    for (int ci = 0; ci < 2; ci++) {
      int col = n0 + wc * 32 + ci * 16 + lr;
      float bv = (bias != nullptr) ? bias[col] : 0.f;
      #pragma unroll
      for (int e = 0; e < 4; e++) {
        int row = m0 + wr * 32 + ri * 16 + lh * 4 + e;
        float v = acc[ri][ci][e] + bv;
        if (act == 1) v = leakyf(v);
        else if (act == 2) v = tanhf(v);
        else if (act == 3) v = sigm(v);
        else if (act == 4) {
          int b = row >> 5;
          float zm = sigm(v + ep1[b * 128 + col]);
          float msv = A0[(long)row * k1 + col];
          v = (1.f - zm) * msv + zm * ep2[b * 128 + col];
        }
        C[(long)row * Nn + col] = v;
      }
    }
  }
}

// ---------------- compound-graph kernels ----------------
__global__ void supe_init_k(const float* __restrict__ vert, float* __restrict__ supe){
  int b = blockIdx.x, c = threadIdx.x;
  float s = 0.f;
  for (int i = 0; i < cNC; i++) s += vert[(b * cNC + i) * cH + c];
  supe[b * cH + c] = s;
}

__global__ void scatter_vert_k(const float* __restrict__ vert, const int* __restrict__ src,
                               const int* __restrict__ dst, float* __restrict__ nei){
  int idx = blockIdx.x * 256 + threadIdx.x;
  if (idx >= cEV * cH) return;
  int e = idx >> 7, c = idx & 127;
  atomicAdd(&nei[dst[e] * cH + c], vert[src[e] * cH + c]);
}

// per-graph super-node precompute: asup, s2m, s2mz, super_self, gh_s
__global__ __launch_bounds__(256) void supe_pre_k(
    const float* __restrict__ supe,
    const float* __restrict__ Wa_super_d, const float* __restrict__ Ws2m_d,
    const float* __restrict__ Wzm2_d, const float* __restrict__ Wsup_d,
    const float* __restrict__ Whh_s, const float* __restrict__ bhh_s,
    float* __restrict__ asup, float* __restrict__ s2m, float* __restrict__ s2mz,
    float* __restrict__ sself, float* __restrict__ gh_s)
{
  __shared__ float srow[cH];
  __shared__ float s2ml[cH];
  int b = blockIdx.x, t = threadIdx.x;
  if (t < cH) srow[t] = supe[b * cH + t];
  __syncthreads();
  // asup[b, 0:1024]
  for (int j = 0; j < 4; j++) {
    int c = t + j * 256;
    int head = c >> 7, e = c & 127;
    const float* Wp = Wa_super_d + head * 16384 + e;
    float s = 0.f;
    for (int d2 = 0; d2 < cH; d2++) s += srow[d2] * Wp[d2 * 128];
    asup[b * 1024 + c] = tanhf(s);
  }
  if (t < cH) {
    float s = 0.f;
    for (int d2 = 0; d2 < cH; d2++) s += srow[d2] * Ws2m_d[d2 * 128 + t];
    float v = tanhf(s);
    s2ml[t] = v; s2m[b * cH + t] = v;
  } else {
    int c = t - cH;
    float s = 0.f;
    for (int d2 = 0; d2 < cH; d2++) s += srow[d2] * Wsup_d[d2 * 128 + c];
    sself[b * cH + c] = tanhf(s);
  }
  // gh_s = supe @ Whh_s + bhh_s  (384 cols)
  {
    int c = t;
    float s = 0.f;
    for (int d2 = 0; d2 < cH; d2++) s += srow[d2] * Whh_s[d2 * 384 + c];
    gh_s[b * 384 + c] = s + bhh_s[c];
    if (t < cH) {
      int c2 = 256 + t;
      float s2 = 0.f;
      for (int d2 = 0; d2 < cH; d2++) s2 += srow[d2] * Whh_s[d2 * 384 + c2];
      gh_s[b * 384 + c2] = s2 + bhh_s[c2];
    }
  }
  __syncthreads();
  if (t < cH) {
    float s = 0.f;
    for (int d2 = 0; d2 < cH; d2++) s += s2ml[d2] * Wzm2_d[d2 * 128 + t];
    s2mz[b * cH + t] = s;
  }
}

// per-graph attention scores + segment softmax
__global__ __launch_bounds__(256) void attn_k(
    const float* __restrict__ am, const float* __restrict__ asup,
    const float* __restrict__ Wb_d, float* __restrict__ attn)
{
  __shared__ float pw[1024];
  __shared__ float sc[cNC][cK8];
  int b = blockIdx.x, t = threadIdx.x;
  for (int j = 0; j < 4; j++) {
    int c = t + j * 256;
    pw[c] = asup[b * 1024 + c] * Wb_d[c];
  }
  __syncthreads();
  int nl = t >> 3, k = t & 7;
  int n = b * cNC + nl;
  const float* ar = am + (long)n * 1024 + k * 128;
  const float* pr = pw + k * 128;
  float s = 0.f;
  for (int e = 0; e < 128; e++) s += ar[e] * pr[e];
  sc[nl][k] = s;
  __syncthreads();
  float mx = -1e30f;
  for (int i = 0; i < cNC; i++) mx = fmaxf(mx, sc[i][k]);
  float den = 0.f;
  for (int i = 0; i < cNC; i++) den += __expf(sc[i][k] - mx);
  attn[n * cK8 + k] = __expf(s - mx) / den;
}

// per-graph m2s + main_to_super = tanh(m2s @ Wm2s)
__global__ __launch_bounds__(256) void m2s_k(
    const float* __restrict__ attn, const float* __restrict__ msg,
    const float* __restrict__ Wm2s_d, float* __restrict__ mts)
{
  __shared__ float m2s[1024];
  __shared__ float at[cNC][cK8];
  int b = blockIdx.x, t = threadIdx.x;
  at[t >> 3][t & 7] = attn[(b * cNC + (t >> 3)) * cK8 + (t & 7)];
  __syncthreads();
  for (int j = 0; j < 4; j++) {
    int c = t + j * 256;
    int k = c >> 7;
    float s = 0.f;
    for (int i = 0; i < cNC; i++) s += at[i][k] * msg[(long)(b * cNC + i) * 1024 + c];
    m2s[c] = s;
  }
  __syncthreads();
  if (t < cH) {
    float s = 0.f;
    for (int j = 0; j < 1024; j++) s += m2s[j] * Wm2s_d[j * 128 + t];
    mts[b * cH + t] = tanhf(s);
  }
}

__global__ void ew_gru_k(const float* __restrict__ gi, const float* __restrict__ gh,
                         float* __restrict__ h){
  int idx = blockIdx.x * 256 + threadIdx.x;
  if (idx >= cNV * cH) return;
  int n = idx >> 7, c = idx & 127;
  const float* gir = gi + (long)n * 384;
  const float* ghr = gh + (long)n * 384;
  float r = sigm(gir[c] + ghr[c]);
  float z = sigm(gir[128 + c] + ghr[128 + c]);
  float nn = tanhf(gir[256 + c] + r * ghr[256 + c]);
  h[idx] = (1.f - z) * nn + z * h[idx];
}

__global__ __launch_bounds__(128) void super_upd_k(
    const float* __restrict__ sself, const float* __restrict__ mts,
    const float* __restrict__ gh_s,
    const float* __restrict__ Wzs1_d, const float* __restrict__ Wzs2_d,
    const float* __restrict__ Wih_s, const float* __restrict__ bih_s,
    float* __restrict__ supe)
{
  __shared__ float ss[cH], mt[cH], xs[cH], sr[cH];
  int b = blockIdx.x, t = threadIdx.x;
  ss[t] = sself[b * cH + t];
  mt[t] = mts[b * cH + t];
  sr[t] = supe[b * cH + t];
  __syncthreads();
  float s1 = 0.f, s2 = 0.f;
  for (int d2 = 0; d2 < cH; d2++) {
    s1 += ss[d2] * Wzs1_d[d2 * 128 + t];
    s2 += mt[d2] * Wzs2_d[d2 * 128 + t];
  }
  float zs = sigm(s1 + s2);
  xs[t] = (1.f - zs) * ss[t] + zs * mt[t];
  __syncthreads();
  float g0 = 0.f, g1 = 0.f, g2 = 0.f;
  for (int d2 = 0; d2 < cH; d2++) {
    float x = xs[d2];
    g0 += x * Wih_s[d2 * 384 + t];
    g1 += x * Wih_s[d2 * 384 + 128 + t];
    g2 += x * Wih_s[d2 * 384 + 256 + t];
  }
  g0 += bih_s[t]; g1 += bih_s[128 + t]; g2 += bih_s[256 + t];
  float r = sigm(g0 + gh_s[b * 384 + t]);
  float z = sigm(g1 + gh_s[b * 384 + 128 + t]);
  float nn = tanhf(g2 + r * gh_s[b * 384 + 256 + t]);
  supe[b * cH + t] = (1.f - z) * nn + z * sr[t];
}

// ---------------- site-graph kernels ----------------
__global__ void scatter_site_k(const float* __restrict__ h, const int* __restrict__ src,
                               const int* __restrict__ dst, float* __restrict__ nei,
                               int dshift){
  long idx = (long)blockIdx.x * 256 + threadIdx.x;
  int din = 1 << dshift;
  if (idx >= (long)cES * din) return;
  int e = (int)(idx >> dshift);
  int c = (int)(idx & (din - 1));
  atomicAdd(&nei[(long)dst[e] * din + c], h[(long)src[e] * din + c]);
}

// ---------------- interaction ----------------
__global__ __launch_bounds__(256) void pair_k(
    const float* __restrict__ pa, const float* __restrict__ pg, float* __restrict__ out)
{
  __shared__ float pal[cNS][cHI];      // 32 KB
  __shared__ float pgl[cNC][cHI + 1];  // padded vs bank conflicts
  int g = blockIdx.x, i = blockIdx.y;
  int t = threadIdx.x;
  for (int l = t; l < cNS * cHI; l += 256) {
    int s = l >> 6, hh = l & 63;
    pal[s][hh] = pa[(long)(g * cNS + s) * 448 + i * 64 + hh];
  }
  for (int l = t; l < cNC * cHI; l += 256) {
    int c = l >> 6, hh = l & 63;
    pgl[c][hh] = pg[(long)(g * cNC + c) * 448 + i * 64 + hh];
  }
  __syncthreads();
  for (int o = t; o < cNS * cNC; o += 256) {
    int s = o >> 5, c = o & 31;
    float sum = 0.f;
    #pragma unroll 8
    for (int hh = 0; hh < cHI; hh++) sum += pal[s][hh] * pgl[c][hh];
    long p = (long)g * (cNS * cNC) + o;
    out[p * 7 + i] = sum;
  }
}

// ---------------- launch ----------------
extern "C" void kernel_launch(void* const* d_in, const int* in_sizes, int n_in,
                              void* d_out, int out_size, void* d_ws, size_t ws_size,
                              hipStream_t stream) {
  // workspace layout (fp32 elements)
  constexpr long OFF_VERT = 0;            // 524288
  constexpr long OFF_SUPE = 524288;       // 16384
  constexpr long OFF_SITE = 1064960;      // 2097152
  constexpr long OFF_ATTN = 3162112;      // 32768
  constexpr long OFF_ASUP = 3194880;      // 131072
  constexpr long OFF_S2M = 3325952;       // 16384
  constexpr long OFF_S2MZ = 3342336;      // 16384
  constexpr long OFF_SSELF = 3358720;     // 16384
  constexpr long OFF_GHS = 3375104;       // 49152
  constexpr long OFF_MTS = 3424256;       // 16384
  constexpr long OFF_NEI = 3440640;       // 524288
  constexpr long OFF_TMPA = 3964928;      // 524288  (nei_s aliases TMPA..XGRU)
  constexpr long OFF_MS = 4489216;        // 524288
  constexpr long OFF_ZMP = 5013504;       // 524288 (unused now, kept for layout)
  constexpr long OFF_XGRU = 5537792;      // 524288
  constexpr long OFF_GHM = 6062080;       // 1572864 (pg aliases here in interaction)
  constexpr long OFF_GIM = 7634944;       // 1572864
  constexpr long OFF_AM = 9207808;        // 4194304 (pa aliases am..msg)
  constexpr long OFF_MSG = 13402112;      // 4194304
  constexpr long OFF_H1 = 17596416;       // 2097152
  constexpr long OFF_H2 = 19693568;       // 2097152
  constexpr long OFF_H3 = 21790720;       // 2097152
  constexpr long WS_FLOATS = 23887872;    // ~95.6 MB
  if (ws_size < (size_t)WS_FLOATS * 4) return;  // fail loudly (output stays wrong)

  const float* x_vert  = (const float*)d_in[0];
  const int*   vsrc    = (const int*)d_in[1];
  const int*   vdst    = (const int*)d_in[2];
  const float* W_emb   = (const float*)d_in[4];
  const float* b_emb   = (const float*)d_in[5];
  const float* Wa_main = (const float*)d_in[6];
  const float* Wa_super= (const float*)d_in[7];
  const float* Wv      = (const float*)d_in[8];
  const float* Wb      = (const float*)d_in[9];
  const float* Wm2s    = (const float*)d_in[10];
  const float* Ws2m    = (const float*)d_in[11];
  const float* Wsup    = (const float*)d_in[12];
  const float* Wself   = (const float*)d_in[13];
  const float* Wzm1    = (const float*)d_in[14];
  const float* Wzm2    = (const float*)d_in[15];
  const float* Wzs1    = (const float*)d_in[16];
  const float* Wzs2    = (const float*)d_in[17];
  const float* Wih_m   = (const float*)d_in[18];
  const float* Whh_m   = (const float*)d_in[19];
  const float* bih_m   = (const float*)d_in[20];
  const float* bhh_m   = (const float*)d_in[21];
  const float* Wih_s   = (const float*)d_in[22];
  const float* Whh_s   = (const float*)d_in[23];
  const float* bih_s   = (const float*)d_in[24];
  const float* bhh_s   = (const float*)d_in[25];
  const float* x_site  = (const float*)d_in[26];
  const int*   ssrc    = (const int*)d_in[27];
  const int*   sdst    = (const int*)d_in[28];
  const float* W0      = (const float*)d_in[29];
  const float* b0      = (const float*)d_in[30];
  const float* Wconv   = (const float*)d_in[31];
  const float* bconv   = (const float*)d_in[32];
  const float* Wout    = (const float*)d_in[33];
  const float* bout    = (const float*)d_in[34];
  const float* Wis     = (const float*)d_in[35];
  const float* bis     = (const float*)d_in[36];
  const float* Wic     = (const float*)d_in[37];
  const float* bic     = (const float*)d_in[38];
  float* out = (float*)d_out;

  float* ws = (float*)d_ws;
  float* vert = ws + OFF_VERT;
  float* supe = ws + OFF_SUPE;
  float* site = ws + OFF_SITE;
  float* attn = ws + OFF_ATTN;
  float* asup = ws + OFF_ASUP;
  float* s2m = ws + OFF_S2M;
  float* s2mz = ws + OFF_S2MZ;
  float* sself = ws + OFF_SSELF;
  float* gh_s = ws + OFF_GHS;
  float* mts = ws + OFF_MTS;
  float* nei = ws + OFF_NEI;
  float* ms = ws + OFF_MS;
  float* xgru = ws + OFF_XGRU;
  float* gh_m = ws + OFF_GHM;
  float* gim = ws + OFF_GIM;
  float* am = ws + OFF_AM;
  float* msg = ws + OFF_MSG;
  float* h1 = ws + OFF_H1;
  float* h2 = ws + OFF_H2;
  float* h3 = ws + OFF_H3;
  float* nei_s = ws + OFF_TMPA;   // alias: site phase only
  float* pa = ws + OFF_AM;        // alias: interaction phase only
  float* pg = ws + OFF_GHM;       // alias: interaction phase only

  auto zero = [&](float* p, long n){
    zero_k<<<dim3((unsigned)((n + 255) / 256)), 256, 0, stream>>>(p, n);
  };
  // single-segment GEMM helper
  auto gemm1 = [&](const float* A0, const float* A1, const float* A2, const float* A3,
                   int k1, int k2, int k3, int K, int M,
                   const float* W, int ldw, int cshift, int cs, const float* bias,
                   float* C, int N, int act, const float* addA = nullptr,
                   const float* ep1 = nullptr, const float* ep2 = nullptr){
    GSegs s{};
    s.W[0] = W; s.bias[0] = bias; s.addA[0] = addA; s.C[0] = C;
    s.nb_end[0] = N / 64; s.N[0] = N; s.ldw[0] = ldw; s.cshift[0] = cshift;
    s.cs[0] = cs; s.act[0] = act; s.nsegs = 1;
    dim3 g(N / 64, M / 64);
    gemm_g<<<g, 256, 0, stream>>>(A0, A1, A2, A3, k1, k2, k3, K, M, s, ep1, ep2);
  };

  // ---- embedding + super init ----
  gemm1(x_vert, x_vert, x_vert, x_vert, 82, 82, 82, 82, cNV,
        W_emb, 128, 30, 0, b_emb, vert, 128, 1);
  supe_init_k<<<cB, 128, 0, stream>>>(vert, supe);

  // ---- GWM iterations ----
  for (int d = 0; d < 3; d++) {
    const float* Wa_main_d = Wa_main + (long)d * 131072;
    const float* Wa_super_d = Wa_super + (long)d * 131072;
    const float* Wv_d = Wv + (long)d * 131072;
    const float* Wb_d = Wb + (long)d * 1024;
    const float* Wm2s_d = Wm2s + (long)d * 131072;
    const float* Ws2m_d = Ws2m + (long)d * 16384;
    const float* Wsup_d = Wsup + (long)d * 16384;
    const float* Wself_d = Wself + (long)d * 16384;
    const float* Wzm1_d = Wzm1 + (long)d * 16384;
    const float* Wzm2_d = Wzm2 + (long)d * 16384;
    const float* Wzs1_d = Wzs1 + (long)d * 16384;
    const float* Wzs2_d = Wzs2 + (long)d * 16384;

    zero(nei, (long)cNV * cH);
    scatter_vert_k<<<(cEV * cH) / 256, 256, 0, stream>>>(vert, vsrc, vdst, nei);

    // fused: ms | am | msg | gh_m   (all A = vert, K = 128, N_total = 2560)
    {
      GSegs s{};
      s.W[0] = Wself_d;   s.bias[0] = nullptr; s.addA[0] = nei;     s.C[0] = ms;
      s.N[0] = 128;  s.ldw[0] = 128; s.cshift[0] = 30; s.cs[0] = 0;     s.act[0] = 1;
      s.nb_end[0] = 2;
      s.W[1] = Wa_main_d; s.bias[1] = nullptr; s.addA[1] = nullptr; s.C[1] = am;
      s.N[1] = 1024; s.ldw[1] = 128; s.cshift[1] = 7;  s.cs[1] = 16384; s.act[1] = 2;
      s.nb_end[1] = 18;
      s.W[2] = Wv_d;      s.bias[2] = nullptr; s.addA[2] = nullptr; s.C[2] = msg;
      s.N[2] = 1024; s.ldw[2] = 128; s.cshift[2] = 7;  s.cs[2] = 16384; s.act[2] = 0;
      s.nb_end[2] = 34;
      s.W[3] = Whh_m;     s.bias[3] = bhh_m;   s.addA[3] = nullptr; s.C[3] = gh_m;
      s.N[3] = 384;  s.ldw[3] = 384; s.cshift[3] = 30; s.cs[3] = 0;     s.act[3] = 0;
      s.nb_end[3] = 40;
      s.nsegs = 4;
      dim3 g(40, cNV / 64);
      gemm_g<<<g, 256, 0, stream>>>(vert, vert, vert, vert, 128, 128, 128, 128, cNV,
                                    s, nullptr, nullptr);
    }
    supe_pre_k<<<cB, 256, 0, stream>>>(supe, Wa_super_d, Ws2m_d, Wzm2_d, Wsup_d,
                                       Whh_s, bhh_s, asup, s2m, s2mz, sself, gh_s);
    attn_k<<<cB, 256, 0, stream>>>(am, asup, Wb_d, attn);
    m2s_k<<<cB, 256, 0, stream>>>(attn, msg, Wm2s_d, mts);
    // zmp GEMM with fused xgru epilogue (act=4): xgru = (1-zm)*ms + zm*s2m[b]
    gemm1(ms, ms, ms, ms, 128, 128, 128, 128, cNV,
          Wzm1_d, 128, 30, 0, nullptr, xgru, 128, 4, nullptr, s2mz, s2m);
    gemm1(xgru, xgru, xgru, xgru, 128, 128, 128, 128, cNV,
          Wih_m, 384, 30, 0, bih_m, gim, 384, 0);
    ew_gru_k<<<(cNV * cH) / 256, 256, 0, stream>>>(gim, gh_m, vert);
    super_upd_k<<<cB, 128, 0, stream>>>(sself, mts, gh_s, Wzs1_d, Wzs2_d,
                                        Wih_s, bih_s, supe);
  }

  // ---- AtomConv on protein sites ----
  // iter 0: din=32
  zero(nei_s, (long)cNSITE * 32);
  scatter_site_k<<<((long)cES * 32) / 256, 256, 0, stream>>>(x_site, ssrc, sdst, nei_s, 5);
  gemm1(x_site, nei_s, x_site, x_site, 32, 64, 64, 64, cNSITE,
        W0, 128, 30, 0, b0, h1, 128, 1);
  // iter 1
  zero(nei_s, (long)cNSITE * 128);
  scatter_site_k<<<((long)cES * 128) / 256, 256, 0, stream>>>(h1, ssrc, sdst, nei_s, 7);
  gemm1(h1, nei_s, h1, h1, 128, 256, 256, 256, cNSITE,
        Wconv, 128, 30, 0, bconv, h2, 128, 1);
  // iter 2
  zero(nei_s, (long)cNSITE * 128);
  scatter_site_k<<<((long)cES * 128) / 256, 256, 0, stream>>>(h2, ssrc, sdst, nei_s, 7);
  gemm1(h2, nei_s, h2, h2, 128, 256, 256, 256, cNSITE,
        Wconv + 32768, 128, 30, 0, bconv + 128, h3, 128, 1);
  // site = leaky(concat(x_site, h1, h2, h3) @ Wout + bout)
  gemm1(x_site, h1, h2, h3, 32, 160, 288, 416, cNSITE,
        Wout, 128, 30, 0, bout, site, 128, 1);

  // ---- Interaction ----
  gemm1(site, site, site, site, 128, 128, 128, 128, cNSITE,
        Wis, 64, 6, 8192, bis, pa, 448, 1);
  gemm1(vert, vert, vert, vert, 128, 128, 128, 128, cNV,
        Wic, 64, 6, 8192, bic, pg, 448, 1);
  pair_k<<<dim3(cB, 7), 256, 0, stream>>>(pa, pg, out);
}

// Round 9
// 892.226 us; speedup vs baseline: 1.6705x; 1.3230x over previous
//
#include <hip/hip_runtime.h>
#include <hip/hip_bf16.h>

typedef unsigned short u16;
typedef unsigned int u32;

// Problem constants (match reference setup_inputs)
static constexpr int cNV = 4096, cEV = 16384, cB = 128, cNC = 32, cNS = 128;
static constexpr int cNSITE = 16384, cES = 131072;
static constexpr int cH = 128, cK8 = 8, cHI = 64;

__device__ __forceinline__ float leakyf(float x){ return x > 0.f ? x : 0.1f * x; }
__device__ __forceinline__ float sigm(float x){ return 1.f / (1.f + __expf(-x)); }

typedef __attribute__((ext_vector_type(4))) short short4v;
typedef __attribute__((ext_vector_type(4))) float f32x4;

__device__ __forceinline__ u16 f2bu(float x){
  __hip_bfloat16 h = __float2bfloat16(x);
  return *(u16*)&h;
}
__device__ __forceinline__ float bf2f(u16 u){
  __hip_bfloat16 h; *(u16*)&h = u;
  return __bfloat162float(h);
}

// ---------------- helpers ----------------
__global__ void zero_k(float* __restrict__ p, long n){
  long i = (long)blockIdx.x * 256 + threadIdx.x;
  if (i < n) p[i] = 0.f;
}

// transpose+convert weight: dst[n*Kr + k] = bf16(src[k*ldw + (n>>cshift)*cs + (n&mask)])
__global__ void cvtw_k(const float* __restrict__ src, u16* __restrict__ dst,
                       int K, int krsh, int N, int ldw, int cshift, int cs){
  long i = (long)blockIdx.x * 256 + threadIdx.x;
  int Kr = 1 << krsh;
  if (i >= (long)N * Kr) return;
  int n = (int)(i >> krsh), k = (int)(i & (Kr - 1));
  float v = 0.f;
  if (k < K) v = src[(long)k * ldw + (long)(n >> cshift) * cs + (n & ((1 << cshift) - 1))];
  dst[i] = f2bu(v);
}

// ---------------- grouped MFMA GEMM (bf16 storage) ----------------
// A: up to 4 row-segments, each bf16 (dt=0) or f32 (dt=1), row-major [M][w].
// W: pre-transposed bf16 [n][Kr]. Tile 64x64, 4 waves, 2x2 16x16x16bf16_1k.
// act: 0 none, 1 leaky, 2 tanh, 3 sigm, 4 xgru-fuse.
// odt: 0 f32 C, 1 bf16 C, 2 dual (f32 C + bf16 C2).
struct GSegs {
  const u16* Wt[4];
  const float* bias[4];
  const float* addA[4];   // optional f32 add, stride K (slow path)
  void* C[4];
  u16* C2[4];
  int nb_end[4];
  int N[4];
  int Kr[4];
  int act[4];
  int odt[4];
  int nsegs;
};

__global__ __launch_bounds__(256) void gemm_g(
    const void* __restrict__ A0, const void* __restrict__ A1,
    const void* __restrict__ A2, const void* __restrict__ A3,
    int dt0, int dt1, int dt2, int dt3,
    int k1, int k2, int k3, int K, int M,
    GSegs segs, const float* __restrict__ ep1, const float* __restrict__ ep2)
{
  __shared__ __align__(16) u16 As[64 * 136];
  __shared__ __align__(16) u16 Bs[64 * 136];
  const int t = threadIdx.x;
  const int l = t & 63, w = t >> 6;
  const int wr = w >> 1, wc = w & 1;
  const int lr = l & 15, lh = l >> 4;

  // bijective XCD swizzle (all grids are multiples of 8 blocks)
  const int nwg = gridDim.x * gridDim.y;
  const int bid = blockIdx.y * gridDim.x + blockIdx.x;
  const int cpx = nwg >> 3;
  const int swz = (bid & 7) * cpx + (bid >> 3);
  const int bx = swz % gridDim.x, by = swz / gridDim.x;

  // output-segment select
  const u16* Wt = nullptr; const float* bias = nullptr; const float* addA = nullptr;
  void* C = nullptr; u16* C2 = nullptr;
  int Nn = 0, Kr = 0, act = 0, odt = 0, nb0 = 0;
  {
    int nbs = 0;
    #pragma unroll
    for (int s = 0; s < 4; s++) {
      if (s < segs.nsegs) {
        int e = segs.nb_end[s];
        if (bx >= nbs && bx < e) {
          Wt = segs.Wt[s]; bias = segs.bias[s]; addA = segs.addA[s];
          C = segs.C[s]; C2 = segs.C2[s];
          Nn = segs.N[s]; Kr = segs.Kr[s]; act = segs.act[s]; odt = segs.odt[s];
          nb0 = nbs;
        }
        nbs = e;
      }
    }
  }
  const int n0 = (bx - nb0) * 64;
  const int m0 = by * 64;
  const int w1 = k2 - k1, w2 = k3 - k2, w3 = K - k3;

  f32x4 acc[2][2];
  #pragma unroll
  for (int i = 0; i < 2; i++)
    #pragma unroll
    for (int j = 0; j < 2; j++)
      acc[i][j] = (f32x4){0.f, 0.f, 0.f, 0.f};

  const int arow = t >> 2, kq = (t & 3) * 32;
  const int bcol = t & 63, bq = (t >> 6) * 32;
  const int mg = m0 + arow;

  for (int kt = 0; kt < K; kt += 128) {
    // ---- stage A (64 rows x 128 k) ----
    #pragma unroll
    for (int sub = 0; sub < 4; sub++) {
      const int kg0 = kt + kq + sub * 8;
      const void* bp; int st, wseg, dt;
      if (kg0 < k1)      { bp = A0; st = 0;  wseg = k1; dt = dt0; }
      else if (kg0 < k2) { bp = A1; st = k1; wseg = w1; dt = dt1; }
      else if (kg0 < k3) { bp = A2; st = k2; wseg = w2; dt = dt2; }
      else               { bp = A3; st = k3; wseg = w3; dt = dt3; }
      uint4 v;
      if (dt == 0 && addA == nullptr && kg0 + 8 <= st + wseg) {
        v = *(const uint4*)((const u16*)bp + (long)mg * wseg + (kg0 - st));
      } else {
        float f[8];
        #pragma unroll
        for (int j = 0; j < 8; j++) {
          int kg = kg0 + j;
          float x = 0.f;
          if (kg < K) {
            long o = (long)mg * wseg + (kg - st);
            x = dt ? ((const float*)bp)[o] : bf2f(((const u16*)bp)[o]);
            if (addA != nullptr) x += addA[(long)mg * K + kg];
          }
          f[j] = x;
        }
        v.x = (u32)f2bu(f[0]) | ((u32)f2bu(f[1]) << 16);
        v.y = (u32)f2bu(f[2]) | ((u32)f2bu(f[3]) << 16);
        v.z = (u32)f2bu(f[4]) | ((u32)f2bu(f[5]) << 16);
        v.w = (u32)f2bu(f[6]) | ((u32)f2bu(f[7]) << 16);
      }
      *(uint4*)&As[arow * 136 + kq + sub * 8] = v;
    }
    // ---- stage B (64 cols x 128 k) from [n][Kr] bf16 ----
    #pragma unroll
    for (int sub = 0; sub < 4; sub++) {
      uint4 v = *(const uint4*)(Wt + (long)(n0 + bcol) * Kr + kt + bq + sub * 8);
      *(uint4*)&Bs[bcol * 136 + bq + sub * 8] = v;
    }
    __syncthreads();
    // ---- compute: 8 k-substeps, 2x2 fragments ----
    #pragma unroll
    for (int ks = 0; ks < 8; ks++) {
      short4v a0 = *(short4v*)&As[(wr * 32 + 0 * 16 + lr) * 136 + ks * 16 + lh * 4];
      short4v a1 = *(short4v*)&As[(wr * 32 + 1 * 16 + lr) * 136 + ks * 16 + lh * 4];
      short4v b0 = *(short4v*)&Bs[(wc * 32 + 0 * 16 + lr) * 136 + ks * 16 + lh * 4];
      short4v b1 = *(short4v*)&Bs[(wc * 32 + 1 * 16 + lr) * 136 + ks * 16 + lh * 4];
      acc[0][0] = __builtin_amdgcn_mfma_f32_16x16x16bf16_1k(a0, b0, acc[0][0], 0, 0, 0);
      acc[0][1] = __builtin_amdgcn_mfma_f32_16x16x16bf16_1k(a0, b1, acc[0][1], 0, 0, 0);
      acc[1][0] = __builtin_amdgcn_mfma_f32_16x16x16bf16_1k(a1, b0, acc[1][0], 0, 0, 0);
      acc[1][1] = __builtin_amdgcn_mfma_f32_16x16x16bf16_1k(a1, b1, acc[1][1], 0, 0, 0);
    }
    __syncthreads();
  }
  // ---- epilogue ----
  #pragma unroll
  for (int ri = 0; ri < 2; ri++) {
    #pragma unroll
    for (int ci = 0; ci < 2; ci++) {
      int col = n0 + wc * 32 + ci * 16 + lr;
      float bv = (bias != nullptr) ? bias[col] : 0.f;
      #pragma unroll
      for (int e = 0; e < 4; e++) {
        int row = m0 + wr * 32 + ri * 16 + lh * 4 + e;
        float v = acc[ri][ci][e] + bv;
        if (act == 1) v = leakyf(v);
        else if (act == 2) v = tanhf(v);
        else if (act == 3) v = sigm(v);
        else if (act == 4) {
          int b = row >> 5;
          float zm = sigm(v + ep1[b * 128 + col]);
          float msv = bf2f(((const u16*)A0)[(long)row * k1 + col]);
          v = (1.f - zm) * msv + zm * ep2[b * 128 + col];
        }
        long o = (long)row * Nn + col;
        if (odt == 0) ((float*)C)[o] = v;
        else if (odt == 1) ((u16*)C)[o] = f2bu(v);
        else { ((float*)C)[o] = v; C2[o] = f2bu(v); }
      }
    }
  }
}

// ---------------- compound-graph kernels ----------------
__global__ void supe_init_k(const float* __restrict__ vert, float* __restrict__ supe){
  int b = blockIdx.x, c = threadIdx.x;
  float s = 0.f;
  for (int i = 0; i < cNC; i++) s += vert[(b * cNC + i) * cH + c];
  supe[b * cH + c] = s;
}

__global__ void scatter_vert_k(const float* __restrict__ vert, const int* __restrict__ src,
                               const int* __restrict__ dst, float* __restrict__ nei){
  int idx = blockIdx.x * 256 + threadIdx.x;
  if (idx >= cEV * cH) return;
  int e = idx >> 7, c = idx & 127;
  atomicAdd(&nei[dst[e] * cH + c], vert[src[e] * cH + c]);
}

__global__ __launch_bounds__(256) void supe_pre_k(
    const float* __restrict__ supe,
    const float* __restrict__ Wa_super_d, const float* __restrict__ Ws2m_d,
    const float* __restrict__ Wzm2_d, const float* __restrict__ Wsup_d,
    const float* __restrict__ Whh_s, const float* __restrict__ bhh_s,
    float* __restrict__ asup, float* __restrict__ s2m, float* __restrict__ s2mz,
    float* __restrict__ sself, float* __restrict__ gh_s)
{
  __shared__ float srow[cH];
  __shared__ float s2ml[cH];
  int b = blockIdx.x, t = threadIdx.x;
  if (t < cH) srow[t] = supe[b * cH + t];
  __syncthreads();
  for (int j = 0; j < 4; j++) {
    int c = t + j * 256;
    int head = c >> 7, e = c & 127;
    const float* Wp = Wa_super_d + head * 16384 + e;
    float s = 0.f;
    for (int d2 = 0; d2 < cH; d2++) s += srow[d2] * Wp[d2 * 128];
    asup[b * 1024 + c] = tanhf(s);
  }
  if (t < cH) {
    float s = 0.f;
    for (int d2 = 0; d2 < cH; d2++) s += srow[d2] * Ws2m_d[d2 * 128 + t];
    float v = tanhf(s);
    s2ml[t] = v; s2m[b * cH + t] = v;
  } else {
    int c = t - cH;
    float s = 0.f;
    for (int d2 = 0; d2 < cH; d2++) s += srow[d2] * Wsup_d[d2 * 128 + c];
    sself[b * cH + c] = tanhf(s);
  }
  {
    int c = t;
    float s = 0.f;
    for (int d2 = 0; d2 < cH; d2++) s += srow[d2] * Whh_s[d2 * 384 + c];
    gh_s[b * 384 + c] = s + bhh_s[c];
    if (t < cH) {
      int c2 = 256 + t;
      float s2 = 0.f;
      for (int d2 = 0; d2 < cH; d2++) s2 += srow[d2] * Whh_s[d2 * 384 + c2];
      gh_s[b * 384 + c2] = s2 + bhh_s[c2];
    }
  }
  __syncthreads();
  if (t < cH) {
    float s = 0.f;
    for (int d2 = 0; d2 < cH; d2++) s += s2ml[d2] * Wzm2_d[d2 * 128 + t];
    s2mz[b * cH + t] = s;
  }
}

__global__ __launch_bounds__(256) void attn_k(
    const float* __restrict__ am, const float* __restrict__ asup,
    const float* __restrict__ Wb_d, float* __restrict__ attn)
{
  __shared__ float pw[1024];
  __shared__ float sc[cNC][cK8];
  int b = blockIdx.x, t = threadIdx.x;
  for (int j = 0; j < 4; j++) {
    int c = t + j * 256;
    pw[c] = asup[b * 1024 + c] * Wb_d[c];
  }
  __syncthreads();
  int nl = t >> 3, k = t & 7;
  int n = b * cNC + nl;
  const float* ar = am + (long)n * 1024 + k * 128;
  const float* pr = pw + k * 128;
  float s = 0.f;
  for (int e = 0; e < 128; e++) s += ar[e] * pr[e];
  sc[nl][k] = s;
  __syncthreads();
  float mx = -1e30f;
  for (int i = 0; i < cNC; i++) mx = fmaxf(mx, sc[i][k]);
  float den = 0.f;
  for (int i = 0; i < cNC; i++) den += __expf(sc[i][k] - mx);
  attn[n * cK8 + k] = __expf(s - mx) / den;
}

__global__ __launch_bounds__(256) void m2s_k(
    const float* __restrict__ attn, const float* __restrict__ msg,
    const float* __restrict__ Wm2s_d, float* __restrict__ mts)
{
  __shared__ float m2s[1024];
  __shared__ float at[cNC][cK8];
  int b = blockIdx.x, t = threadIdx.x;
  at[t >> 3][t & 7] = attn[(b * cNC + (t >> 3)) * cK8 + (t & 7)];
  __syncthreads();
  for (int j = 0; j < 4; j++) {
    int c = t + j * 256;
    int k = c >> 7;
    float s = 0.f;
    for (int i = 0; i < cNC; i++) s += at[i][k] * msg[(long)(b * cNC + i) * 1024 + c];
    m2s[c] = s;
  }
  __syncthreads();
  if (t < cH) {
    float s = 0.f;
    for (int j = 0; j < 1024; j++) s += m2s[j] * Wm2s_d[j * 128 + t];
    mts[b * cH + t] = tanhf(s);
  }
}

// GRU combine: gi (bf16, [NV][384]), gh (bf16, [NV][384]), h fp32 rmw + bf16 copy
__global__ void ew_gru_k(const u16* __restrict__ gi, const u16* __restrict__ gh,
                         float* __restrict__ h, u16* __restrict__ hb){
  int idx = blockIdx.x * 256 + threadIdx.x;
  if (idx >= cNV * cH) return;
  int n = idx >> 7, c = idx & 127;
  const u16* gir = gi + (long)n * 384;
  const u16* ghr = gh + (long)n * 384;
  float r = sigm(bf2f(gir[c]) + bf2f(ghr[c]));
  float z = sigm(bf2f(gir[128 + c]) + bf2f(ghr[128 + c]));
  float nn = tanhf(bf2f(gir[256 + c]) + r * bf2f(ghr[256 + c]));
  float v = (1.f - z) * nn + z * h[idx];
  h[idx] = v;
  hb[idx] = f2bu(v);
}

__global__ __launch_bounds__(128) void super_upd_k(
    const float* __restrict__ sself, const float* __restrict__ mts,
    const float* __restrict__ gh_s,
    const float* __restrict__ Wzs1_d, const float* __restrict__ Wzs2_d,
    const float* __restrict__ Wih_s, const float* __restrict__ bih_s,
    float* __restrict__ supe)
{
  __shared__ float ss[cH], mt[cH], xs[cH], sr[cH];
  int b = blockIdx.x, t = threadIdx.x;
  ss[t] = sself[b * cH + t];
  mt[t] = mts[b * cH + t];
  sr[t] = supe[b * cH + t];
  __syncthreads();
  float s1 = 0.f, s2 = 0.f;
  for (int d2 = 0; d2 < cH; d2++) {
    s1 += ss[d2] * Wzs1_d[d2 * 128 + t];
    s2 += mt[d2] * Wzs2_d[d2 * 128 + t];
  }
  float zs = sigm(s1 + s2);
  xs[t] = (1.f - zs) * ss[t] + zs * mt[t];
  __syncthreads();
  float g0 = 0.f, g1 = 0.f, g2 = 0.f;
  for (int d2 = 0; d2 < cH; d2++) {
    float x = xs[d2];
    g0 += x * Wih_s[d2 * 384 + t];
    g1 += x * Wih_s[d2 * 384 + 128 + t];
    g2 += x * Wih_s[d2 * 384 + 256 + t];
  }
  g0 += bih_s[t]; g1 += bih_s[128 + t]; g2 += bih_s[256 + t];
  float r = sigm(g0 + gh_s[b * 384 + t]);
  float z = sigm(g1 + gh_s[b * 384 + 128 + t]);
  float nn = tanhf(g2 + r * gh_s[b * 384 + 256 + t]);
  supe[b * cH + t] = (1.f - z) * nn + z * sr[t];
}

// ---------------- site-graph scatters ----------------
__global__ void scatter_site_k(const float* __restrict__ h, const int* __restrict__ src,
                               const int* __restrict__ dst, float* __restrict__ nei,
                               int dshift){
  long idx = (long)blockIdx.x * 256 + threadIdx.x;
  int din = 1 << dshift;
  if (idx >= (long)cES * din) return;
  int e = (int)(idx >> dshift);
  int c = (int)(idx & (din - 1));
  atomicAdd(&nei[(long)dst[e] * din + c], h[(long)src[e] * din + c]);
}

__global__ void scatter_site_b_k(const u16* __restrict__ h, const int* __restrict__ src,
                                 const int* __restrict__ dst, float* __restrict__ nei){
  long idx = (long)blockIdx.x * 256 + threadIdx.x;
  if (idx >= (long)cES * 128) return;
  int e = (int)(idx >> 7);
  int c = (int)(idx & 127);
  atomicAdd(&nei[(long)dst[e] * 128 + c], bf2f(h[(long)src[e] * 128 + c]));
}

// ---------------- interaction ----------------
__global__ __launch_bounds__(256) void pair_k(
    const u16* __restrict__ pa, const u16* __restrict__ pg, float* __restrict__ out)
{
  __shared__ float pal[cNS][cHI];
  __shared__ float pgl[cNC][cHI + 1];
  int g = blockIdx.x, i = blockIdx.y;
  int t = threadIdx.x;
  for (int l = t; l < cNS * cHI; l += 256) {
    int s = l >> 6, hh = l & 63;
    pal[s][hh] = bf2f(pa[(long)(g * cNS + s) * 448 + i * 64 + hh]);
  }
  for (int l = t; l < cNC * cHI; l += 256) {
    int c = l >> 6, hh = l & 63;
    pgl[c][hh] = bf2f(pg[(long)(g * cNC + c) * 448 + i * 64 + hh]);
  }
  __syncthreads();
  for (int o = t; o < cNS * cNC; o += 256) {
    int s = o >> 5, c = o & 31;
    float sum = 0.f;
    #pragma unroll 8
    for (int hh = 0; hh < cHI; hh++) sum += pal[s][hh] * pgl[c][hh];
    long p = (long)g * (cNS * cNC) + o;
    out[p * 7 + i] = sum;
  }
}

// ---------------- launch ----------------
extern "C" void kernel_launch(void* const* d_in, const int* in_sizes, int n_in,
                              void* d_out, int out_size, void* d_ws, size_t ws_size,
                              hipStream_t stream) {
  // f32 workspace regions (element offsets) — layout unchanged from r8
  constexpr long OFF_VERT = 0;            // 524288  vert f32
  constexpr long OFF_SUPE = 524288;       // 16384
  constexpr long OFF_SITE = 1064960;      // 2097152 -> site_b (bf16)
  constexpr long OFF_ATTN = 3162112;      // 32768
  constexpr long OFF_ASUP = 3194880;      // 131072
  constexpr long OFF_S2M = 3325952;
  constexpr long OFF_S2MZ = 3342336;
  constexpr long OFF_SSELF = 3358720;
  constexpr long OFF_GHS = 3375104;
  constexpr long OFF_MTS = 3424256;
  constexpr long OFF_NEI = 3440640;       // 524288  nei f32
  constexpr long OFF_TMPA = 3964928;      // unused
  constexpr long OFF_MS = 4489216;        // -> ms_b (bf16)
  constexpr long OFF_ZMP = 5013504;       // -> vert_b (bf16, persistent)
  constexpr long OFF_XGRU = 5537792;      // -> xgru_b (bf16)
  constexpr long OFF_GHM = 6062080;       // -> ghm_b + gim_b (bf16)
  constexpr long OFF_GIM = 7634944;       // -> pg_b (bf16, interaction)
  constexpr long OFF_AM = 9207808;        // am f32 (GWM) / nei_s f32 (site)
  constexpr long OFF_MSG = 13402112;      // msg f32 (GWM) / pa_b (interaction)
  constexpr long OFF_H1 = 17596416;       // -> h1b
  constexpr long OFF_H2 = 19693568;       // -> h2b
  constexpr long OFF_H3 = 21790720;       // -> h3b (1M) + wbuf (bf16 weights)
  constexpr long WS_FLOATS = 23887872;    // ~95.6 MB
  if (ws_size < (size_t)WS_FLOATS * 4) return;

  // bf16 weight buffer sub-offsets (u16 elements)
  constexpr long WT_EMB = 0;         // N=128  Kr=128
  constexpr long WT_SELF = 16384;    // N=384  Kr=128 (3d x 128)
  constexpr long WT_AMAIN = 65536;   // N=3072 Kr=128
  constexpr long WT_V = 458752;      // N=3072 Kr=128
  constexpr long WT_HHM = 851968;    // N=384  Kr=128
  constexpr long WT_ZM1 = 901120;    // N=384  Kr=128
  constexpr long WT_IHM = 950272;    // N=384  Kr=128
  constexpr long WT_W0 = 999424;     // N=128  Kr=128
  constexpr long WT_CONV = 1015808;  // N=256  Kr=256
  constexpr long WT_OUT = 1081344;   // N=128  Kr=512
  constexpr long WT_IS = 1146880;    // N=448  Kr=128
  constexpr long WT_IC = 1204224;    // N=448  Kr=128  (end 1261568 u16 = 630784 f32)

  const float* x_vert  = (const float*)d_in[0];
  const int*   vsrc    = (const int*)d_in[1];
  const int*   vdst    = (const int*)d_in[2];
  const float* W_emb   = (const float*)d_in[4];
  const float* b_emb   = (const float*)d_in[5];
  const float* Wa_main = (const float*)d_in[6];
  const float* Wa_super= (const float*)d_in[7];
  const float* Wv      = (const float*)d_in[8];
  const float* Wb      = (const float*)d_in[9];
  const float* Wm2s    = (const float*)d_in[10];
  const float* Ws2m    = (const float*)d_in[11];
  const float* Wsup    = (const float*)d_in[12];
  const float* Wself   = (const float*)d_in[13];
  const float* Wzm1    = (const float*)d_in[14];
  const float* Wzm2    = (const float*)d_in[15];
  const float* Wzs1    = (const float*)d_in[16];
  const float* Wzs2    = (const float*)d_in[17];
  const float* Wih_m   = (const float*)d_in[18];
  const float* Whh_m   = (const float*)d_in[19];
  const float* bih_m   = (const float*)d_in[20];
  const float* bhh_m   = (const float*)d_in[21];
  const float* Wih_s   = (const float*)d_in[22];
  const float* Whh_s   = (const float*)d_in[23];
  const float* bih_s   = (const float*)d_in[24];
  const float* bhh_s   = (const float*)d_in[25];
  const float* x_site  = (const float*)d_in[26];
  const int*   ssrc    = (const int*)d_in[27];
  const int*   sdst    = (const int*)d_in[28];
  const float* W0      = (const float*)d_in[29];
  const float* b0      = (const float*)d_in[30];
  const float* Wconv   = (const float*)d_in[31];
  const float* bconv   = (const float*)d_in[32];
  const float* Wout    = (const float*)d_in[33];
  const float* bout    = (const float*)d_in[34];
  const float* Wis     = (const float*)d_in[35];
  const float* bis     = (const float*)d_in[36];
  const float* Wic     = (const float*)d_in[37];
  const float* bic     = (const float*)d_in[38];
  float* out = (float*)d_out;

  float* ws = (float*)d_ws;
  float* vert  = ws + OFF_VERT;
  float* supe  = ws + OFF_SUPE;
  float* attn  = ws + OFF_ATTN;
  float* asup  = ws + OFF_ASUP;
  float* s2m   = ws + OFF_S2M;
  float* s2mz  = ws + OFF_S2MZ;
  float* sself = ws + OFF_SSELF;
  float* gh_s  = ws + OFF_GHS;
  float* mts   = ws + OFF_MTS;
  float* nei   = ws + OFF_NEI;
  float* am    = ws + OFF_AM;
  float* msg   = ws + OFF_MSG;
  float* nei_s = ws + OFF_AM;     // site phase (am dead)

  u16* vert_b = (u16*)(ws + OFF_ZMP);
  u16* ms_b   = (u16*)(ws + OFF_MS);
  u16* xgru_b = (u16*)(ws + OFF_XGRU);
  u16* ghm_b  = (u16*)(ws + OFF_GHM);
  u16* gim_b  = (u16*)(ws + OFF_GHM + 786432);
  u16* h1b    = (u16*)(ws + OFF_H1);
  u16* h2b    = (u16*)(ws + OFF_H2);
  u16* h3b    = (u16*)(ws + OFF_H3);
  u16* site_b = (u16*)(ws + OFF_SITE);
  u16* pa_b   = (u16*)(ws + OFF_MSG);   // interaction (msg dead)
  u16* pg_b   = (u16*)(ws + OFF_GIM);   // interaction
  u16* wbuf   = (u16*)(ws + OFF_H3 + 1048576);

  auto zero = [&](float* p, long n){
    zero_k<<<dim3((unsigned)((n + 255) / 256)), 256, 0, stream>>>(p, n);
  };
  auto cvtw = [&](const float* src, long wt_off, int K, int krsh, int N,
                  int ldw, int cshift, int cs){
    long tot = (long)N << krsh;
    cvtw_k<<<dim3((unsigned)((tot + 255) / 256)), 256, 0, stream>>>(
        src, wbuf + wt_off, K, krsh, N, ldw, cshift, cs);
  };
  // single-output-segment GEMM helper
  auto gemm1 = [&](const void* A0, int dt0, const void* A1, int dt1,
                   const void* A2, int dt2, const void* A3, int dt3,
                   int k1, int k2, int k3, int K, int M,
                   long wt_off, int Kr, const float* bias,
                   void* C, u16* C2, int N, int act, int odt,
                   const float* addA = nullptr,
                   const float* ep1 = nullptr, const float* ep2 = nullptr){
    GSegs s{};
    s.Wt[0] = wbuf + wt_off; s.bias[0] = bias; s.addA[0] = addA;
    s.C[0] = C; s.C2[0] = C2;
    s.nb_end[0] = N / 64; s.N[0] = N; s.Kr[0] = Kr; s.act[0] = act; s.odt[0] = odt;
    s.nsegs = 1;
    dim3 g(N / 64, M / 64);
    gemm_g<<<g, 256, 0, stream>>>(A0, A1, A2, A3, dt0, dt1, dt2, dt3,
                                  k1, k2, k3, K, M, s, ep1, ep2);
  };

  // ---- one-time weight convert+transpose (bf16, [n][Kr]) ----
  cvtw(W_emb, WT_EMB, 82, 7, 128, 128, 30, 0);
  cvtw(Wself, WT_SELF, 128, 7, 384, 128, 7, 16384);
  cvtw(Wa_main, WT_AMAIN, 128, 7, 3072, 128, 7, 16384);
  cvtw(Wv, WT_V, 128, 7, 3072, 128, 7, 16384);
  cvtw(Whh_m, WT_HHM, 128, 7, 384, 384, 30, 0);
  cvtw(Wzm1, WT_ZM1, 128, 7, 384, 128, 7, 16384);
  cvtw(Wih_m, WT_IHM, 128, 7, 384, 384, 30, 0);
  cvtw(W0, WT_W0, 64, 7, 128, 128, 30, 0);
  cvtw(Wconv, WT_CONV, 256, 8, 256, 128, 7, 32768);
  cvtw(Wout, WT_OUT, 416, 9, 128, 128, 30, 0);
  cvtw(Wis, WT_IS, 128, 7, 448, 64, 6, 8192);
  cvtw(Wic, WT_IC, 128, 7, 448, 64, 6, 8192);

  // ---- embedding (dual store: vert f32 + vert_b bf16) + super init ----
  gemm1(x_vert, 1, x_vert, 1, x_vert, 1, x_vert, 1, 82, 82, 82, 82, cNV,
        WT_EMB, 128, b_emb, vert, vert_b, 128, 1, 2);
  supe_init_k<<<cB, 128, 0, stream>>>(vert, supe);

  // ---- GWM iterations ----
  for (int d = 0; d < 3; d++) {
    const float* Wa_super_d = Wa_super + (long)d * 131072;
    const float* Wb_d = Wb + (long)d * 1024;
    const float* Wm2s_d = Wm2s + (long)d * 131072;
    const float* Ws2m_d = Ws2m + (long)d * 16384;
    const float* Wsup_d = Wsup + (long)d * 16384;
    const float* Wzm2_d = Wzm2 + (long)d * 16384;
    const float* Wzs1_d = Wzs1 + (long)d * 16384;
    const float* Wzs2_d = Wzs2 + (long)d * 16384;

    zero(nei, (long)cNV * cH);
    scatter_vert_k<<<(cEV * cH) / 256, 256, 0, stream>>>(vert, vsrc, vdst, nei);

    // fused: ms_b | am | msg | ghm_b   (A = vert_b, K=128, N_total=2560)
    {
      GSegs s{};
      s.Wt[0] = wbuf + WT_SELF + (long)d * 16384;  s.bias[0] = nullptr;
      s.addA[0] = nei;     s.C[0] = ms_b;  s.C2[0] = nullptr;
      s.N[0] = 128;  s.Kr[0] = 128; s.act[0] = 1; s.odt[0] = 1; s.nb_end[0] = 2;
      s.Wt[1] = wbuf + WT_AMAIN + (long)d * 131072; s.bias[1] = nullptr;
      s.addA[1] = nullptr; s.C[1] = am;    s.C2[1] = nullptr;
      s.N[1] = 1024; s.Kr[1] = 128; s.act[1] = 2; s.odt[1] = 0; s.nb_end[1] = 18;
      s.Wt[2] = wbuf + WT_V + (long)d * 131072;     s.bias[2] = nullptr;
      s.addA[2] = nullptr; s.C[2] = msg;   s.C2[2] = nullptr;
      s.N[2] = 1024; s.Kr[2] = 128; s.act[2] = 0; s.odt[2] = 0; s.nb_end[2] = 34;
      s.Wt[3] = wbuf + WT_HHM;                      s.bias[3] = bhh_m;
      s.addA[3] = nullptr; s.C[3] = ghm_b; s.C2[3] = nullptr;
      s.N[3] = 384;  s.Kr[3] = 128; s.act[3] = 0; s.odt[3] = 1; s.nb_end[3] = 40;
      s.nsegs = 4;
      dim3 g(40, cNV / 64);
      gemm_g<<<g, 256, 0, stream>>>(vert_b, vert_b, vert_b, vert_b, 0, 0, 0, 0,
                                    128, 128, 128, 128, cNV, s, nullptr, nullptr);
    }
    supe_pre_k<<<cB, 256, 0, stream>>>(supe, Wa_super_d, Ws2m_d, Wzm2_d, Wsup_d,
                                       Whh_s, bhh_s, asup, s2m, s2mz, sself, gh_s);
    attn_k<<<cB, 256, 0, stream>>>(am, asup, Wb_d, attn);
    m2s_k<<<cB, 256, 0, stream>>>(attn, msg, Wm2s_d, mts);
    // zmp GEMM + fused xgru epilogue (act=4)
    gemm1(ms_b, 0, ms_b, 0, ms_b, 0, ms_b, 0, 128, 128, 128, 128, cNV,
          WT_ZM1 + (long)d * 16384, 128, nullptr, xgru_b, nullptr, 128, 4, 1,
          nullptr, s2mz, s2m);
    gemm1(xgru_b, 0, xgru_b, 0, xgru_b, 0, xgru_b, 0, 128, 128, 128, 128, cNV,
          WT_IHM, 128, bih_m, gim_b, nullptr, 384, 0, 1);
    ew_gru_k<<<(cNV * cH) / 256, 256, 0, stream>>>(gim_b, ghm_b, vert, vert_b);
    super_upd_k<<<cB, 128, 0, stream>>>(sself, mts, gh_s, Wzs1_d, Wzs2_d,
                                        Wih_s, bih_s, supe);
  }

  // ---- AtomConv on protein sites ----
  zero(nei_s, (long)cNSITE * 32);
  scatter_site_k<<<((long)cES * 32) / 256, 256, 0, stream>>>(x_site, ssrc, sdst, nei_s, 5);
  gemm1(x_site, 1, nei_s, 1, nei_s, 1, nei_s, 1, 32, 64, 64, 64, cNSITE,
        WT_W0, 128, b0, h1b, nullptr, 128, 1, 1);
  zero(nei_s, (long)cNSITE * 128);
  scatter_site_b_k<<<((long)cES * 128) / 256, 256, 0, stream>>>(h1b, ssrc, sdst, nei_s);
  gemm1(h1b, 0, nei_s, 1, nei_s, 1, nei_s, 1, 128, 256, 256, 256, cNSITE,
        WT_CONV, 256, bconv, h2b, nullptr, 128, 1, 1);
  zero(nei_s, (long)cNSITE * 128);
  scatter_site_b_k<<<((long)cES * 128) / 256, 256, 0, stream>>>(h2b, ssrc, sdst, nei_s);
  gemm1(h2b, 0, nei_s, 1, nei_s, 1, nei_s, 1, 128, 256, 256, 256, cNSITE,
        WT_CONV + 32768, 256, bconv + 128, h3b, nullptr, 128, 1, 1);
  // site = leaky(concat(x_site f32, h1b, h2b, h3b) @ Wout + bout)
  gemm1(x_site, 1, h1b, 0, h2b, 0, h3b, 0, 32, 160, 288, 416, cNSITE,
        WT_OUT, 512, bout, site_b, nullptr, 128, 1, 1);

  // ---- Interaction ----
  gemm1(site_b, 0, site_b, 0, site_b, 0, site_b, 0, 128, 128, 128, 128, cNSITE,
        WT_IS, 128, bis, pa_b, nullptr, 448, 1, 1);
  gemm1(vert_b, 0, vert_b, 0, vert_b, 0, vert_b, 0, 128, 128, 128, 128, cNV,
        WT_IC, 128, bic, pg_b, nullptr, 448, 1, 1);
  pair_k<<<dim3(cB, 7), 256, 0, stream>>>(pa_b, pg_b, out);
}

// Round 10
// 833.020 us; speedup vs baseline: 1.7893x; 1.0711x over previous
//
#include <hip/hip_runtime.h>
#include <hip/hip_bf16.h>

typedef unsigned short u16;
typedef unsigned int u32;

// Problem constants (match reference setup_inputs)
static constexpr int cNV = 4096, cEV = 16384, cB = 128, cNC = 32, cNS = 128;
static constexpr int cNSITE = 16384, cES = 131072;
static constexpr int cH = 128, cK8 = 8, cHI = 64;

__device__ __forceinline__ float leakyf(float x){ return x > 0.f ? x : 0.1f * x; }
__device__ __forceinline__ float sigm(float x){ return 1.f / (1.f + __expf(-x)); }

typedef __attribute__((ext_vector_type(4))) short short4v;
typedef __attribute__((ext_vector_type(4))) float f32x4;

__device__ __forceinline__ u16 f2bu(float x){
  __hip_bfloat16 h = __float2bfloat16(x);
  return *(u16*)&h;
}
__device__ __forceinline__ float bf2f(u16 u){
  __hip_bfloat16 h; *(u16*)&h = u;
  return __bfloat162float(h);
}

// ---------------- CSR build ----------------
__global__ void zero_i_k(int* __restrict__ p, int n){
  int i = blockIdx.x * 256 + threadIdx.x;
  if (i < n) p[i] = 0;
}
__global__ void copy_i_k(const int* __restrict__ s, int* __restrict__ d, int n){
  int i = blockIdx.x * 256 + threadIdx.x;
  if (i < n) d[i] = s[i];
}
__global__ void count_k(const int* __restrict__ dst, int* __restrict__ cnt, int ne){
  int i = blockIdx.x * 256 + threadIdx.x;
  if (i < ne) atomicAdd(&cnt[dst[i]], 1);
}
// single-block exclusive scan: off[0..n] from cnt[0..n-1]; n divisible by 256
__global__ void scan_k(const int* __restrict__ cnt, int* __restrict__ off, int n){
  __shared__ int part[256];
  int t = threadIdx.x;
  int chunk = n >> 8;
  int base = t * chunk;
  int s = 0;
  for (int j = 0; j < chunk; j++) s += cnt[base + j];
  part[t] = s;
  __syncthreads();
  for (int d = 1; d < 256; d <<= 1) {
    int v = (t >= d) ? part[t - d] : 0;
    __syncthreads();
    part[t] += v;
    __syncthreads();
  }
  int run = (t == 0) ? 0 : part[t - 1];
  for (int j = 0; j < chunk; j++) { off[base + j] = run; run += cnt[base + j]; }
  if (t == 255) off[n] = run;
}
__global__ void fill_k(const int* __restrict__ src, const int* __restrict__ dst,
                       int* __restrict__ cur, int* __restrict__ perm, int ne){
  int i = blockIdx.x * 256 + threadIdx.x;
  if (i < ne) {
    int p = atomicAdd(&cur[dst[i]], 1);
    perm[p] = src[i];
  }
}

// ---------------- gathers (replace atomic scatters) ----------------
__global__ void gather128_f_k(const float* __restrict__ h, const int* __restrict__ off,
                              const int* __restrict__ perm, float* __restrict__ nei){
  int row = blockIdx.x, t = threadIdx.x;
  int b = off[row], e = off[row + 1];
  float s = 0.f;
  for (int i = b; i < e; i++) s += h[(long)perm[i] * 128 + t];
  nei[(long)row * 128 + t] = s;
}
__global__ void gather128_b_k(const u16* __restrict__ h, const int* __restrict__ off,
                              const int* __restrict__ perm, u16* __restrict__ nei){
  int row = blockIdx.x, t = threadIdx.x;
  int b = off[row], e = off[row + 1];
  float s = 0.f;
  for (int i = b; i < e; i++) s += bf2f(h[(long)perm[i] * 128 + t]);
  nei[(long)row * 128 + t] = f2bu(s);
}
__global__ void gather32_k(const float* __restrict__ h, const int* __restrict__ off,
                           const int* __restrict__ perm, u16* __restrict__ nei){
  int t = threadIdx.x;
  int row = blockIdx.x * 8 + (t >> 5), c = t & 31;
  int b = off[row], e = off[row + 1];
  float s = 0.f;
  for (int i = b; i < e; i++) s += h[(long)perm[i] * 32 + c];
  nei[(long)row * 32 + c] = f2bu(s);
}

// transpose+convert weight: dst[n*Kr + k] = bf16(src[k*ldw + (n>>cshift)*cs + (n&mask)])
__global__ void cvtw_k(const float* __restrict__ src, u16* __restrict__ dst,
                       int K, int krsh, int N, int ldw, int cshift, int cs){
  long i = (long)blockIdx.x * 256 + threadIdx.x;
  int Kr = 1 << krsh;
  if (i >= (long)N * Kr) return;
  int n = (int)(i >> krsh), k = (int)(i & (Kr - 1));
  float v = 0.f;
  if (k < K) v = src[(long)k * ldw + (long)(n >> cshift) * cs + (n & ((1 << cshift) - 1))];
  dst[i] = f2bu(v);
}

// ---------------- grouped MFMA GEMM (bf16 storage) ----------------
struct GSegs {
  const u16* Wt[4];
  const float* bias[4];
  const float* addA[4];   // optional f32 add, stride K (slow path)
  void* C[4];
  u16* C2[4];
  int nb_end[4];
  int N[4];
  int Kr[4];
  int act[4];
  int odt[4];
  int nsegs;
};

__global__ __launch_bounds__(256) void gemm_g(
    const void* __restrict__ A0, const void* __restrict__ A1,
    const void* __restrict__ A2, const void* __restrict__ A3,
    int dt0, int dt1, int dt2, int dt3,
    int k1, int k2, int k3, int K, int M,
    GSegs segs, const float* __restrict__ ep1, const float* __restrict__ ep2)
{
  __shared__ __align__(16) u16 As[64 * 136];
  __shared__ __align__(16) u16 Bs[64 * 136];
  const int t = threadIdx.x;
  const int l = t & 63, w = t >> 6;
  const int wr = w >> 1, wc = w & 1;
  const int lr = l & 15, lh = l >> 4;

  const int nwg = gridDim.x * gridDim.y;
  const int bid = blockIdx.y * gridDim.x + blockIdx.x;
  const int cpx = nwg >> 3;
  const int swz = (bid & 7) * cpx + (bid >> 3);
  const int bx = swz % gridDim.x, by = swz / gridDim.x;

  const u16* Wt = nullptr; const float* bias = nullptr; const float* addA = nullptr;
  void* C = nullptr; u16* C2 = nullptr;
  int Nn = 0, Kr = 0, act = 0, odt = 0, nb0 = 0;
  {
    int nbs = 0;
    #pragma unroll
    for (int s = 0; s < 4; s++) {
      if (s < segs.nsegs) {
        int e = segs.nb_end[s];
        if (bx >= nbs && bx < e) {
          Wt = segs.Wt[s]; bias = segs.bias[s]; addA = segs.addA[s];
          C = segs.C[s]; C2 = segs.C2[s];
          Nn = segs.N[s]; Kr = segs.Kr[s]; act = segs.act[s]; odt = segs.odt[s];
          nb0 = nbs;
        }
        nbs = e;
      }
    }
  }
  const int n0 = (bx - nb0) * 64;
  const int m0 = by * 64;
  const int w1 = k2 - k1, w2 = k3 - k2, w3 = K - k3;

  f32x4 acc[2][2];
  #pragma unroll
  for (int i = 0; i < 2; i++)
    #pragma unroll
    for (int j = 0; j < 2; j++)
      acc[i][j] = (f32x4){0.f, 0.f, 0.f, 0.f};

  const int arow = t >> 2, kq = (t & 3) * 32;
  const int bcol = t & 63, bq = (t >> 6) * 32;
  const int mg = m0 + arow;

  for (int kt = 0; kt < K; kt += 128) {
    #pragma unroll
    for (int sub = 0; sub < 4; sub++) {
      const int kg0 = kt + kq + sub * 8;
      const void* bp; int st, wseg, dt;
      if (kg0 < k1)      { bp = A0; st = 0;  wseg = k1; dt = dt0; }
      else if (kg0 < k2) { bp = A1; st = k1; wseg = w1; dt = dt1; }
      else if (kg0 < k3) { bp = A2; st = k2; wseg = w2; dt = dt2; }
      else               { bp = A3; st = k3; wseg = w3; dt = dt3; }
      uint4 v;
      if (dt == 0 && addA == nullptr && kg0 + 8 <= st + wseg) {
        v = *(const uint4*)((const u16*)bp + (long)mg * wseg + (kg0 - st));
      } else {
        float f[8];
        #pragma unroll
        for (int j = 0; j < 8; j++) {
          int kg = kg0 + j;
          float x = 0.f;
          if (kg < K) {
            long o = (long)mg * wseg + (kg - st);
            x = dt ? ((const float*)bp)[o] : bf2f(((const u16*)bp)[o]);
            if (addA != nullptr) x += addA[(long)mg * K + kg];
          }
          f[j] = x;
        }
        v.x = (u32)f2bu(f[0]) | ((u32)f2bu(f[1]) << 16);
        v.y = (u32)f2bu(f[2]) | ((u32)f2bu(f[3]) << 16);
        v.z = (u32)f2bu(f[4]) | ((u32)f2bu(f[5]) << 16);
        v.w = (u32)f2bu(f[6]) | ((u32)f2bu(f[7]) << 16);
      }
      *(uint4*)&As[arow * 136 + kq + sub * 8] = v;
    }
    #pragma unroll
    for (int sub = 0; sub < 4; sub++) {
      uint4 v = *(const uint4*)(Wt + (long)(n0 + bcol) * Kr + kt + bq + sub * 8);
      *(uint4*)&Bs[bcol * 136 + bq + sub * 8] = v;
    }
    __syncthreads();
    #pragma unroll
    for (int ks = 0; ks < 8; ks++) {
      short4v a0 = *(short4v*)&As[(wr * 32 + 0 * 16 + lr) * 136 + ks * 16 + lh * 4];
      short4v a1 = *(short4v*)&As[(wr * 32 + 1 * 16 + lr) * 136 + ks * 16 + lh * 4];
      short4v b0 = *(short4v*)&Bs[(wc * 32 + 0 * 16 + lr) * 136 + ks * 16 + lh * 4];
      short4v b1 = *(short4v*)&Bs[(wc * 32 + 1 * 16 + lr) * 136 + ks * 16 + lh * 4];
      acc[0][0] = __builtin_amdgcn_mfma_f32_16x16x16bf16_1k(a0, b0, acc[0][0], 0, 0, 0);
      acc[0][1] = __builtin_amdgcn_mfma_f32_16x16x16bf16_1k(a0, b1, acc[0][1], 0, 0, 0);
      acc[1][0] = __builtin_amdgcn_mfma_f32_16x16x16bf16_1k(a1, b0, acc[1][0], 0, 0, 0);
      acc[1][1] = __builtin_amdgcn_mfma_f32_16x16x16bf16_1k(a1, b1, acc[1][1], 0, 0, 0);
    }
    __syncthreads();
  }
  #pragma unroll
  for (int ri = 0; ri < 2; ri++) {
    #pragma unroll
    for (int ci = 0; ci < 2; ci++) {
      int col = n0 + wc * 32 + ci * 16 + lr;
      float bv = (bias != nullptr) ? bias[col] : 0.f;
      #pragma unroll
      for (int e = 0; e < 4; e++) {
        int row = m0 + wr * 32 + ri * 16 + lh * 4 + e;
        float v = acc[ri][ci][e] + bv;
        if (act == 1) v = leakyf(v);
        else if (act == 2) v = tanhf(v);
        else if (act == 3) v = sigm(v);
        else if (act == 4) {
          int b = row >> 5;
          float zm = sigm(v + ep1[b * 128 + col]);
          float msv = bf2f(((const u16*)A0)[(long)row * k1 + col]);
          v = (1.f - zm) * msv + zm * ep2[b * 128 + col];
        }
        long o = (long)row * Nn + col;
        if (odt == 0) ((float*)C)[o] = v;
        else if (odt == 1) ((u16*)C)[o] = f2bu(v);
        else { ((float*)C)[o] = v; C2[o] = f2bu(v); }
      }
    }
  }
}

// ---------------- compound-graph kernels ----------------
__global__ void supe_init_k(const float* __restrict__ vert, float* __restrict__ supe){
  int b = blockIdx.x, c = threadIdx.x;
  float s = 0.f;
  for (int i = 0; i < cNC; i++) s += vert[(b * cNC + i) * cH + c];
  supe[b * cH + c] = s;
}

__global__ __launch_bounds__(256) void supe_pre_k(
    const float* __restrict__ supe,
    const float* __restrict__ Wa_super_d, const float* __restrict__ Ws2m_d,
    const float* __restrict__ Wzm2_d, const float* __restrict__ Wsup_d,
    const float* __restrict__ Whh_s, const float* __restrict__ bhh_s,
    float* __restrict__ asup, float* __restrict__ s2m, float* __restrict__ s2mz,
    float* __restrict__ sself, float* __restrict__ gh_s)
{
  __shared__ float srow[cH];
  __shared__ float s2ml[cH];
  int b = blockIdx.x, t = threadIdx.x;
  if (t < cH) srow[t] = supe[b * cH + t];
  __syncthreads();
  for (int j = 0; j < 4; j++) {
    int c = t + j * 256;
    int head = c >> 7, e = c & 127;
    const float* Wp = Wa_super_d + head * 16384 + e;
    float s = 0.f;
    for (int d2 = 0; d2 < cH; d2++) s += srow[d2] * Wp[d2 * 128];
    asup[b * 1024 + c] = tanhf(s);
  }
  if (t < cH) {
    float s = 0.f;
    for (int d2 = 0; d2 < cH; d2++) s += srow[d2] * Ws2m_d[d2 * 128 + t];
    float v = tanhf(s);
    s2ml[t] = v; s2m[b * cH + t] = v;
  } else {
    int c = t - cH;
    float s = 0.f;
    for (int d2 = 0; d2 < cH; d2++) s += srow[d2] * Wsup_d[d2 * 128 + c];
    sself[b * cH + c] = tanhf(s);
  }
  {
    int c = t;
    float s = 0.f;
    for (int d2 = 0; d2 < cH; d2++) s += srow[d2] * Whh_s[d2 * 384 + c];
    gh_s[b * 384 + c] = s + bhh_s[c];
    if (t < cH) {
      int c2 = 256 + t;
      float s2 = 0.f;
      for (int d2 = 0; d2 < cH; d2++) s2 += srow[d2] * Whh_s[d2 * 384 + c2];
      gh_s[b * 384 + c2] = s2 + bhh_s[c2];
    }
  }
  __syncthreads();
  if (t < cH) {
    float s = 0.f;
    for (int d2 = 0; d2 < cH; d2++) s += s2ml[d2] * Wzm2_d[d2 * 128 + t];
    s2mz[b * cH + t] = s;
  }
}

__global__ __launch_bounds__(256) void attn_k(
    const float* __restrict__ am, const float* __restrict__ asup,
    const float* __restrict__ Wb_d, float* __restrict__ attn)
{
  __shared__ float pw[1024];
  __shared__ float sc[cNC][cK8];
  int b = blockIdx.x, t = threadIdx.x;
  for (int j = 0; j < 4; j++) {
    int c = t + j * 256;
    pw[c] = asup[b * 1024 + c] * Wb_d[c];
  }
  __syncthreads();
  int nl = t >> 3, k = t & 7;
  int n = b * cNC + nl;
  const float* ar = am + (long)n * 1024 + k * 128;
  const float* pr = pw + k * 128;
  float s = 0.f;
  for (int e = 0; e < 128; e++) s += ar[e] * pr[e];
  sc[nl][k] = s;
  __syncthreads();
  float mx = -1e30f;
  for (int i = 0; i < cNC; i++) mx = fmaxf(mx, sc[i][k]);
  float den = 0.f;
  for (int i = 0; i < cNC; i++) den += __expf(sc[i][k] - mx);
  attn[n * cK8 + k] = __expf(s - mx) / den;
}

__global__ __launch_bounds__(256) void m2s_k(
    const float* __restrict__ attn, const float* __restrict__ msg,
    const float* __restrict__ Wm2s_d, float* __restrict__ mts)
{
  __shared__ float m2s[1024];
  __shared__ float at[cNC][cK8];
  int b = blockIdx.x, t = threadIdx.x;
  at[t >> 3][t & 7] = attn[(b * cNC + (t >> 3)) * cK8 + (t & 7)];
  __syncthreads();
  for (int j = 0; j < 4; j++) {
    int c = t + j * 256;
    int k = c >> 7;
    float s = 0.f;
    for (int i = 0; i < cNC; i++) s += at[i][k] * msg[(long)(b * cNC + i) * 1024 + c];
    m2s[c] = s;
  }
  __syncthreads();
  if (t < cH) {
    float s = 0.f;
    for (int j = 0; j < 1024; j++) s += m2s[j] * Wm2s_d[j * 128 + t];
    mts[b * cH + t] = tanhf(s);
  }
}

__global__ void ew_gru_k(const u16* __restrict__ gi, const u16* __restrict__ gh,
                         float* __restrict__ h, u16* __restrict__ hb){
  int idx = blockIdx.x * 256 + threadIdx.x;
  if (idx >= cNV * cH) return;
  int n = idx >> 7, c = idx & 127;
  const u16* gir = gi + (long)n * 384;
  const u16* ghr = gh + (long)n * 384;
  float r = sigm(bf2f(gir[c]) + bf2f(ghr[c]));
  float z = sigm(bf2f(gir[128 + c]) + bf2f(ghr[128 + c]));
  float nn = tanhf(bf2f(gir[256 + c]) + r * bf2f(ghr[256 + c]));
  float v = (1.f - z) * nn + z * h[idx];
  h[idx] = v;
  hb[idx] = f2bu(v);
}

__global__ __launch_bounds__(128) void super_upd_k(
    const float* __restrict__ sself, const float* __restrict__ mts,
    const float* __restrict__ gh_s,
    const float* __restrict__ Wzs1_d, const float* __restrict__ Wzs2_d,
    const float* __restrict__ Wih_s, const float* __restrict__ bih_s,
    float* __restrict__ supe)
{
  __shared__ float ss[cH], mt[cH], xs[cH], sr[cH];
  int b = blockIdx.x, t = threadIdx.x;
  ss[t] = sself[b * cH + t];
  mt[t] = mts[b * cH + t];
  sr[t] = supe[b * cH + t];
  __syncthreads();
  float s1 = 0.f, s2 = 0.f;
  for (int d2 = 0; d2 < cH; d2++) {
    s1 += ss[d2] * Wzs1_d[d2 * 128 + t];
    s2 += mt[d2] * Wzs2_d[d2 * 128 + t];
  }
  float zs = sigm(s1 + s2);
  xs[t] = (1.f - zs) * ss[t] + zs * mt[t];
  __syncthreads();
  float g0 = 0.f, g1 = 0.f, g2 = 0.f;
  for (int d2 = 0; d2 < cH; d2++) {
    float x = xs[d2];
    g0 += x * Wih_s[d2 * 384 + t];
    g1 += x * Wih_s[d2 * 384 + 128 + t];
    g2 += x * Wih_s[d2 * 384 + 256 + t];
  }
  g0 += bih_s[t]; g1 += bih_s[128 + t]; g2 += bih_s[256 + t];
  float r = sigm(g0 + gh_s[b * 384 + t]);
  float z = sigm(g1 + gh_s[b * 384 + 128 + t]);
  float nn = tanhf(g2 + r * gh_s[b * 384 + 256 + t]);
  supe[b * cH + t] = (1.f - z) * nn + z * sr[t];
}

// ---------------- interaction ----------------
__global__ __launch_bounds__(256) void pair_k(
    const u16* __restrict__ pa, const u16* __restrict__ pg, float* __restrict__ out)
{
  __shared__ float pal[cNS][cHI];
  __shared__ float pgl[cNC][cHI + 1];
  int g = blockIdx.x, i = blockIdx.y;
  int t = threadIdx.x;
  for (int l = t; l < cNS * cHI; l += 256) {
    int s = l >> 6, hh = l & 63;
    pal[s][hh] = bf2f(pa[(long)(g * cNS + s) * 448 + i * 64 + hh]);
  }
  for (int l = t; l < cNC * cHI; l += 256) {
    int c = l >> 6, hh = l & 63;
    pgl[c][hh] = bf2f(pg[(long)(g * cNC + c) * 448 + i * 64 + hh]);
  }
  __syncthreads();
  for (int o = t; o < cNS * cNC; o += 256) {
    int s = o >> 5, c = o & 31;
    float sum = 0.f;
    #pragma unroll 8
    for (int hh = 0; hh < cHI; hh++) sum += pal[s][hh] * pgl[c][hh];
    long p = (long)g * (cNS * cNC) + o;
    out[p * 7 + i] = sum;
  }
}

// ---------------- launch ----------------
extern "C" void kernel_launch(void* const* d_in, const int* in_sizes, int n_in,
                              void* d_out, int out_size, void* d_ws, size_t ws_size,
                              hipStream_t stream) {
  constexpr long OFF_VERT = 0;            // 524288  vert f32
  constexpr long OFF_SUPE = 524288;
  constexpr long OFF_SITE = 1064960;      // -> site_b (bf16)
  constexpr long OFF_ATTN = 3162112;
  constexpr long OFF_ASUP = 3194880;
  constexpr long OFF_S2M = 3325952;
  constexpr long OFF_S2MZ = 3342336;
  constexpr long OFF_SSELF = 3358720;
  constexpr long OFF_GHS = 3375104;
  constexpr long OFF_MTS = 3424256;
  constexpr long OFF_NEI = 3440640;       // nei f32 (vert graph)
  constexpr long OFF_TMPA = 3964928;      // -> CSR int workspace
  constexpr long OFF_MS = 4489216;        // -> ms_b
  constexpr long OFF_ZMP = 5013504;       // -> vert_b (persistent)
  constexpr long OFF_XGRU = 5537792;      // -> xgru_b
  constexpr long OFF_GHM = 6062080;       // -> ghm_b + gim_b
  constexpr long OFF_GIM = 7634944;       // -> pg_b (interaction)
  constexpr long OFF_AM = 9207808;        // am f32 (GWM) / nei_sb (site phase)
  constexpr long OFF_MSG = 13402112;      // msg f32 (GWM) / pa_b (interaction)
  constexpr long OFF_H1 = 17596416;       // -> h1b
  constexpr long OFF_H2 = 19693568;       // -> h2b
  constexpr long OFF_H3 = 21790720;       // -> h3b (1M f32) + wbuf
  constexpr long WS_FLOATS = 23887872;
  if (ws_size < (size_t)WS_FLOATS * 4) return;

  // bf16 weight buffer sub-offsets (u16 elements)
  constexpr long WT_EMB = 0;
  constexpr long WT_SELF = 16384;
  constexpr long WT_AMAIN = 65536;
  constexpr long WT_V = 458752;
  constexpr long WT_HHM = 851968;
  constexpr long WT_ZM1 = 901120;
  constexpr long WT_IHM = 950272;
  constexpr long WT_W0 = 999424;
  constexpr long WT_CONV = 1015808;
  constexpr long WT_OUT = 1081344;
  constexpr long WT_IS = 1146880;
  constexpr long WT_IC = 1204224;

  const float* x_vert  = (const float*)d_in[0];
  const int*   vsrc    = (const int*)d_in[1];
  const int*   vdst    = (const int*)d_in[2];
  const float* W_emb   = (const float*)d_in[4];
  const float* b_emb   = (const float*)d_in[5];
  const float* Wa_main = (const float*)d_in[6];
  const float* Wa_super= (const float*)d_in[7];
  const float* Wv      = (const float*)d_in[8];
  const float* Wb      = (const float*)d_in[9];
  const float* Wm2s    = (const float*)d_in[10];
  const float* Ws2m    = (const float*)d_in[11];
  const float* Wsup    = (const float*)d_in[12];
  const float* Wself   = (const float*)d_in[13];
  const float* Wzm1    = (const float*)d_in[14];
  const float* Wzm2    = (const float*)d_in[15];
  const float* Wzs1    = (const float*)d_in[16];
  const float* Wzs2    = (const float*)d_in[17];
  const float* Wih_m   = (const float*)d_in[18];
  const float* Whh_m   = (const float*)d_in[19];
  const float* bih_m   = (const float*)d_in[20];
  const float* bhh_m   = (const float*)d_in[21];
  const float* Wih_s   = (const float*)d_in[22];
  const float* Whh_s   = (const float*)d_in[23];
  const float* bih_s   = (const float*)d_in[24];
  const float* bhh_s   = (const float*)d_in[25];
  const float* x_site  = (const float*)d_in[26];
  const int*   ssrc    = (const int*)d_in[27];
  const int*   sdst    = (const int*)d_in[28];
  const float* W0      = (const float*)d_in[29];
  const float* b0      = (const float*)d_in[30];
  const float* Wconv   = (const float*)d_in[31];
  const float* bconv   = (const float*)d_in[32];
  const float* Wout    = (const float*)d_in[33];
  const float* bout    = (const float*)d_in[34];
  const float* Wis     = (const float*)d_in[35];
  const float* bis     = (const float*)d_in[36];
  const float* Wic     = (const float*)d_in[37];
  const float* bic     = (const float*)d_in[38];
  float* out = (float*)d_out;

  float* ws = (float*)d_ws;
  float* vert  = ws + OFF_VERT;
  float* supe  = ws + OFF_SUPE;
  float* attn  = ws + OFF_ATTN;
  float* asup  = ws + OFF_ASUP;
  float* s2m   = ws + OFF_S2M;
  float* s2mz  = ws + OFF_S2MZ;
  float* sself = ws + OFF_SSELF;
  float* gh_s  = ws + OFF_GHS;
  float* mts   = ws + OFF_MTS;
  float* nei   = ws + OFF_NEI;
  float* am    = ws + OFF_AM;
  float* msg   = ws + OFF_MSG;

  u16* vert_b = (u16*)(ws + OFF_ZMP);
  u16* ms_b   = (u16*)(ws + OFF_MS);
  u16* xgru_b = (u16*)(ws + OFF_XGRU);
  u16* ghm_b  = (u16*)(ws + OFF_GHM);
  u16* gim_b  = (u16*)(ws + OFF_GHM + 786432);
  u16* h1b    = (u16*)(ws + OFF_H1);
  u16* h2b    = (u16*)(ws + OFF_H2);
  u16* h3b    = (u16*)(ws + OFF_H3);
  u16* site_b = (u16*)(ws + OFF_SITE);
  u16* nei_sb = (u16*)(ws + OFF_AM);    // site phase (am dead)
  u16* pa_b   = (u16*)(ws + OFF_MSG);   // interaction (msg dead)
  u16* pg_b   = (u16*)(ws + OFF_GIM);   // interaction
  u16* wbuf   = (u16*)(ws + OFF_H3 + 1048576);

  // CSR int workspace (inside OFF_TMPA, 524288 ints available)
  int* iws   = (int*)(ws + OFF_TMPA);
  int* voff  = iws;            // 4097
  int* vcur  = iws + 8192;     // 4096
  int* vperm = iws + 16384;    // 16384
  int* soff  = iws + 32768;    // 16385
  int* scur  = iws + 57344;    // 16384
  int* sperm = iws + 81920;    // 131072 (end 212992 < 524288)

  auto cvtw = [&](const float* src, long wt_off, int K, int krsh, int N,
                  int ldw, int cshift, int cs){
    long tot = (long)N << krsh;
    cvtw_k<<<dim3((unsigned)((tot + 255) / 256)), 256, 0, stream>>>(
        src, wbuf + wt_off, K, krsh, N, ldw, cshift, cs);
  };
  auto gemm1 = [&](const void* A0, int dt0, const void* A1, int dt1,
                   const void* A2, int dt2, const void* A3, int dt3,
                   int k1, int k2, int k3, int K, int M,
                   long wt_off, int Kr, const float* bias,
                   void* C, u16* C2, int N, int act, int odt,
                   const float* addA = nullptr,
                   const float* ep1 = nullptr, const float* ep2 = nullptr){
    GSegs s{};
    s.Wt[0] = wbuf + wt_off; s.bias[0] = bias; s.addA[0] = addA;
    s.C[0] = C; s.C2[0] = C2;
    s.nb_end[0] = N / 64; s.N[0] = N; s.Kr[0] = Kr; s.act[0] = act; s.odt[0] = odt;
    s.nsegs = 1;
    dim3 g(N / 64, M / 64);
    gemm_g<<<g, 256, 0, stream>>>(A0, A1, A2, A3, dt0, dt1, dt2, dt3,
                                  k1, k2, k3, K, M, s, ep1, ep2);
  };

  // ---- CSR build (both graphs) ----
  zero_i_k<<<16, 256, 0, stream>>>(vcur, cNV);
  count_k<<<cEV / 256, 256, 0, stream>>>(vdst, vcur, cEV);
  scan_k<<<1, 256, 0, stream>>>(vcur, voff, cNV);
  copy_i_k<<<16, 256, 0, stream>>>(voff, vcur, cNV);
  fill_k<<<cEV / 256, 256, 0, stream>>>(vsrc, vdst, vcur, vperm, cEV);
  zero_i_k<<<64, 256, 0, stream>>>(scur, cNSITE);
  count_k<<<cES / 256, 256, 0, stream>>>(sdst, scur, cES);
  scan_k<<<1, 256, 0, stream>>>(scur, soff, cNSITE);
  copy_i_k<<<64, 256, 0, stream>>>(soff, scur, cNSITE);
  fill_k<<<cES / 256, 256, 0, stream>>>(ssrc, sdst, scur, sperm, cES);

  // ---- one-time weight convert+transpose ----
  cvtw(W_emb, WT_EMB, 82, 7, 128, 128, 30, 0);
  cvtw(Wself, WT_SELF, 128, 7, 384, 128, 7, 16384);
  cvtw(Wa_main, WT_AMAIN, 128, 7, 3072, 128, 7, 16384);
  cvtw(Wv, WT_V, 128, 7, 3072, 128, 7, 16384);
  cvtw(Whh_m, WT_HHM, 128, 7, 384, 384, 30, 0);
  cvtw(Wzm1, WT_ZM1, 128, 7, 384, 128, 7, 16384);
  cvtw(Wih_m, WT_IHM, 128, 7, 384, 384, 30, 0);
  cvtw(W0, WT_W0, 64, 7, 128, 128, 30, 0);
  cvtw(Wconv, WT_CONV, 256, 8, 256, 128, 7, 32768);
  cvtw(Wout, WT_OUT, 416, 9, 128, 128, 30, 0);
  cvtw(Wis, WT_IS, 128, 7, 448, 64, 6, 8192);
  cvtw(Wic, WT_IC, 128, 7, 448, 64, 6, 8192);

  // ---- embedding (dual store) + super init ----
  gemm1(x_vert, 1, x_vert, 1, x_vert, 1, x_vert, 1, 82, 82, 82, 82, cNV,
        WT_EMB, 128, b_emb, vert, vert_b, 128, 1, 2);
  supe_init_k<<<cB, 128, 0, stream>>>(vert, supe);

  // ---- GWM iterations ----
  for (int d = 0; d < 3; d++) {
    const float* Wa_super_d = Wa_super + (long)d * 131072;
    const float* Wb_d = Wb + (long)d * 1024;
    const float* Wm2s_d = Wm2s + (long)d * 131072;
    const float* Ws2m_d = Ws2m + (long)d * 16384;
    const float* Wsup_d = Wsup + (long)d * 16384;
    const float* Wzm2_d = Wzm2 + (long)d * 16384;
    const float* Wzs1_d = Wzs1 + (long)d * 16384;
    const float* Wzs2_d = Wzs2 + (long)d * 16384;

    gather128_f_k<<<cNV, 128, 0, stream>>>(vert, voff, vperm, nei);

    // fused: ms_b | am | msg | ghm_b   (A = vert_b, K=128, N_total=2560)
    {
      GSegs s{};
      s.Wt[0] = wbuf + WT_SELF + (long)d * 16384;  s.bias[0] = nullptr;
      s.addA[0] = nei;     s.C[0] = ms_b;  s.C2[0] = nullptr;
      s.N[0] = 128;  s.Kr[0] = 128; s.act[0] = 1; s.odt[0] = 1; s.nb_end[0] = 2;
      s.Wt[1] = wbuf + WT_AMAIN + (long)d * 131072; s.bias[1] = nullptr;
      s.addA[1] = nullptr; s.C[1] = am;    s.C2[1] = nullptr;
      s.N[1] = 1024; s.Kr[1] = 128; s.act[1] = 2; s.odt[1] = 0; s.nb_end[1] = 18;
      s.Wt[2] = wbuf + WT_V + (long)d * 131072;     s.bias[2] = nullptr;
      s.addA[2] = nullptr; s.C[2] = msg;   s.C2[2] = nullptr;
      s.N[2] = 1024; s.Kr[2] = 128; s.act[2] = 0; s.odt[2] = 0; s.nb_end[2] = 34;
      s.Wt[3] = wbuf + WT_HHM;                      s.bias[3] = bhh_m;
      s.addA[3] = nullptr; s.C[3] = ghm_b; s.C2[3] = nullptr;
      s.N[3] = 384;  s.Kr[3] = 128; s.act[3] = 0; s.odt[3] = 1; s.nb_end[3] = 40;
      s.nsegs = 4;
      dim3 g(40, cNV / 64);
      gemm_g<<<g, 256, 0, stream>>>(vert_b, vert_b, vert_b, vert_b, 0, 0, 0, 0,
                                    128, 128, 128, 128, cNV, s, nullptr, nullptr);
    }
    supe_pre_k<<<cB, 256, 0, stream>>>(supe, Wa_super_d, Ws2m_d, Wzm2_d, Wsup_d,
                                       Whh_s, bhh_s, asup, s2m, s2mz, sself, gh_s);
    attn_k<<<cB, 256, 0, stream>>>(am, asup, Wb_d, attn);
    m2s_k<<<cB, 256, 0, stream>>>(attn, msg, Wm2s_d, mts);
    gemm1(ms_b, 0, ms_b, 0, ms_b, 0, ms_b, 0, 128, 128, 128, 128, cNV,
          WT_ZM1 + (long)d * 16384, 128, nullptr, xgru_b, nullptr, 128, 4, 1,
          nullptr, s2mz, s2m);
    gemm1(xgru_b, 0, xgru_b, 0, xgru_b, 0, xgru_b, 0, 128, 128, 128, 128, cNV,
          WT_IHM, 128, bih_m, gim_b, nullptr, 384, 0, 1);
    ew_gru_k<<<(cNV * cH) / 256, 256, 0, stream>>>(gim_b, ghm_b, vert, vert_b);
    super_upd_k<<<cB, 128, 0, stream>>>(sself, mts, gh_s, Wzs1_d, Wzs2_d,
                                        Wih_s, bih_s, supe);
  }

  // ---- AtomConv on protein sites (CSR gathers, bf16 nei) ----
  gather32_k<<<cNSITE / 8, 256, 0, stream>>>(x_site, soff, sperm, nei_sb);
  gemm1(x_site, 1, nei_sb, 0, nei_sb, 0, nei_sb, 0, 32, 64, 64, 64, cNSITE,
        WT_W0, 128, b0, h1b, nullptr, 128, 1, 1);
  gather128_b_k<<<cNSITE, 128, 0, stream>>>(h1b, soff, sperm, nei_sb);
  gemm1(h1b, 0, nei_sb, 0, nei_sb, 0, nei_sb, 0, 128, 256, 256, 256, cNSITE,
        WT_CONV, 256, bconv, h2b, nullptr, 128, 1, 1);
  gather128_b_k<<<cNSITE, 128, 0, stream>>>(h2b, soff, sperm, nei_sb);
  gemm1(h2b, 0, nei_sb, 0, nei_sb, 0, nei_sb, 0, 128, 256, 256, 256, cNSITE,
        WT_CONV + 32768, 256, bconv + 128, h3b, nullptr, 128, 1, 1);
  gemm1(x_site, 1, h1b, 0, h2b, 0, h3b, 0, 32, 160, 288, 416, cNSITE,
        WT_OUT, 512, bout, site_b, nullptr, 128, 1, 1);

  // ---- Interaction ----
  gemm1(site_b, 0, site_b, 0, site_b, 0, site_b, 0, 128, 128, 128, 128, cNSITE,
        WT_IS, 128, bis, pa_b, nullptr, 448, 1, 1);
  gemm1(vert_b, 0, vert_b, 0, vert_b, 0, vert_b, 0, 128, 128, 128, 128, cNV,
        WT_IC, 128, bic, pg_b, nullptr, 448, 1, 1);
  pair_k<<<dim3(cB, 7), 256, 0, stream>>>(pa_b, pg_b, out);
}

// Round 11
// 806.103 us; speedup vs baseline: 1.8490x; 1.0334x over previous
//
#include <hip/hip_runtime.h>
#include <hip/hip_bf16.h>

typedef unsigned short u16;
typedef unsigned int u32;

// Problem constants (match reference setup_inputs)
static constexpr int cNV = 4096, cEV = 16384, cB = 128, cNC = 32, cNS = 128;
static constexpr int cNSITE = 16384, cES = 131072;
static constexpr int cH = 128, cK8 = 8, cHI = 64;

__device__ __forceinline__ float leakyf(float x){ return x > 0.f ? x : 0.1f * x; }
__device__ __forceinline__ float sigm(float x){ return 1.f / (1.f + __expf(-x)); }

typedef __attribute__((ext_vector_type(4))) short short4v;
typedef __attribute__((ext_vector_type(4))) float f32x4;

__device__ __forceinline__ u16 f2bu(float x){
  __hip_bfloat16 h = __float2bfloat16(x);
  return *(u16*)&h;
}
__device__ __forceinline__ float bf2f(u16 u){
  __hip_bfloat16 h; *(u16*)&h = u;
  return __bfloat162float(h);
}

// ---------------- CSR build ----------------
__global__ void zero_i_k(int* __restrict__ p, int n){
  int i = blockIdx.x * 256 + threadIdx.x;
  if (i < n) p[i] = 0;
}
__global__ void copy_i_k(const int* __restrict__ s, int* __restrict__ d, int n){
  int i = blockIdx.x * 256 + threadIdx.x;
  if (i < n) d[i] = s[i];
}
__global__ void count_k(const int* __restrict__ dst, int* __restrict__ cnt, int ne){
  int i = blockIdx.x * 256 + threadIdx.x;
  if (i < ne) atomicAdd(&cnt[dst[i]], 1);
}
// single-block exclusive scan: off[0..n] from cnt[0..n-1]; n divisible by 256
__global__ void scan_k(const int* __restrict__ cnt, int* __restrict__ off, int n){
  __shared__ int part[256];
  int t = threadIdx.x;
  int chunk = n >> 8;
  int base = t * chunk;
  int s = 0;
  for (int j = 0; j < chunk; j++) s += cnt[base + j];
  part[t] = s;
  __syncthreads();
  for (int d = 1; d < 256; d <<= 1) {
    int v = (t >= d) ? part[t - d] : 0;
    __syncthreads();
    part[t] += v;
    __syncthreads();
  }
  int run = (t == 0) ? 0 : part[t - 1];
  for (int j = 0; j < chunk; j++) { off[base + j] = run; run += cnt[base + j]; }
  if (t == 255) off[n] = run;
}
__global__ void fill_k(const int* __restrict__ src, const int* __restrict__ dst,
                       int* __restrict__ cur, int* __restrict__ perm, int ne){
  int i = blockIdx.x * 256 + threadIdx.x;
  if (i < ne) {
    int p = atomicAdd(&cur[dst[i]], 1);
    perm[p] = src[i];
  }
}

// ---------------- gathers ----------------
__global__ void gather128_f_k(const float* __restrict__ h, const int* __restrict__ off,
                              const int* __restrict__ perm, float* __restrict__ nei){
  int row = blockIdx.x, t = threadIdx.x;
  int b = off[row], e = off[row + 1];
  float s = 0.f;
  for (int i = b; i < e; i++) s += h[(long)perm[i] * 128 + t];
  nei[(long)row * 128 + t] = s;
}
__global__ void gather128_b_k(const u16* __restrict__ h, const int* __restrict__ off,
                              const int* __restrict__ perm, u16* __restrict__ nei){
  int row = blockIdx.x, t = threadIdx.x;
  int b = off[row], e = off[row + 1];
  float s = 0.f;
  for (int i = b; i < e; i++) s += bf2f(h[(long)perm[i] * 128 + t]);
  nei[(long)row * 128 + t] = f2bu(s);
}
__global__ void gather32_k(const float* __restrict__ h, const int* __restrict__ off,
                           const int* __restrict__ perm, u16* __restrict__ nei){
  int t = threadIdx.x;
  int row = blockIdx.x * 8 + (t >> 5), c = t & 31;
  int b = off[row], e = off[row + 1];
  float s = 0.f;
  for (int i = b; i < e; i++) s += h[(long)perm[i] * 32 + c];
  nei[(long)row * 32 + c] = f2bu(s);
}

// transpose+convert weight: dst[n*Kr + k] = bf16(src[k*ldw + (n>>cshift)*cs + (n&mask)])
__global__ void cvtw_k(const float* __restrict__ src, u16* __restrict__ dst,
                       int K, int krsh, int N, int ldw, int cshift, int cs){
  long i = (long)blockIdx.x * 256 + threadIdx.x;
  int Kr = 1 << krsh;
  if (i >= (long)N * Kr) return;
  int n = (int)(i >> krsh), k = (int)(i & (Kr - 1));
  float v = 0.f;
  if (k < K) v = src[(long)k * ldw + (long)(n >> cshift) * cs + (n & ((1 << cshift) - 1))];
  dst[i] = f2bu(v);
}

// ---------------- grouped MFMA GEMM (bf16 storage) ----------------
struct GSegs {
  const u16* Wt[4];
  const float* bias[4];
  const float* addA[4];   // optional f32 add, stride K (slow path)
  void* C[4];
  u16* C2[4];
  int nb_end[4];
  int N[4];
  int Kr[4];
  int act[4];
  int odt[4];
  int nsegs;
};

__global__ __launch_bounds__(256) void gemm_g(
    const void* __restrict__ A0, const void* __restrict__ A1,
    const void* __restrict__ A2, const void* __restrict__ A3,
    int dt0, int dt1, int dt2, int dt3,
    int k1, int k2, int k3, int K, int M,
    GSegs segs, const float* __restrict__ ep1, const float* __restrict__ ep2)
{
  __shared__ __align__(16) u16 As[64 * 136];
  __shared__ __align__(16) u16 Bs[64 * 136];
  const int t = threadIdx.x;
  const int l = t & 63, w = t >> 6;
  const int wr = w >> 1, wc = w & 1;
  const int lr = l & 15, lh = l >> 4;

  const int nwg = gridDim.x * gridDim.y;
  const int bid = blockIdx.y * gridDim.x + blockIdx.x;
  const int cpx = nwg >> 3;
  const int swz = (bid & 7) * cpx + (bid >> 3);
  const int bx = swz % gridDim.x, by = swz / gridDim.x;

  const u16* Wt = nullptr; const float* bias = nullptr; const float* addA = nullptr;
  void* C = nullptr; u16* C2 = nullptr;
  int Nn = 0, Kr = 0, act = 0, odt = 0, nb0 = 0;
  {
    int nbs = 0;
    #pragma unroll
    for (int s = 0; s < 4; s++) {
      if (s < segs.nsegs) {
        int e = segs.nb_end[s];
        if (bx >= nbs && bx < e) {
          Wt = segs.Wt[s]; bias = segs.bias[s]; addA = segs.addA[s];
          C = segs.C[s]; C2 = segs.C2[s];
          Nn = segs.N[s]; Kr = segs.Kr[s]; act = segs.act[s]; odt = segs.odt[s];
          nb0 = nbs;
        }
        nbs = e;
      }
    }
  }
  const int n0 = (bx - nb0) * 64;
  const int m0 = by * 64;
  const int w1 = k2 - k1, w2 = k3 - k2, w3 = K - k3;

  f32x4 acc[2][2];
  #pragma unroll
  for (int i = 0; i < 2; i++)
    #pragma unroll
    for (int j = 0; j < 2; j++)
      acc[i][j] = (f32x4){0.f, 0.f, 0.f, 0.f};

  const int arow = t >> 2, kq = (t & 3) * 32;
  const int bcol = t & 63, bq = (t >> 6) * 32;
  const int mg = m0 + arow;

  for (int kt = 0; kt < K; kt += 128) {
    #pragma unroll
    for (int sub = 0; sub < 4; sub++) {
      const int kg0 = kt + kq + sub * 8;
      const void* bp; int st, wseg, dt;
      if (kg0 < k1)      { bp = A0; st = 0;  wseg = k1; dt = dt0; }
      else if (kg0 < k2) { bp = A1; st = k1; wseg = w1; dt = dt1; }
      else if (kg0 < k3) { bp = A2; st = k2; wseg = w2; dt = dt2; }
      else               { bp = A3; st = k3; wseg = w3; dt = dt3; }
      uint4 v;
      if (dt == 0 && addA == nullptr && kg0 + 8 <= st + wseg) {
        v = *(const uint4*)((const u16*)bp + (long)mg * wseg + (kg0 - st));
      } else {
        float f[8];
        #pragma unroll
        for (int j = 0; j < 8; j++) {
          int kg = kg0 + j;
          float x = 0.f;
          if (kg < K) {
            long o = (long)mg * wseg + (kg - st);
            x = dt ? ((const float*)bp)[o] : bf2f(((const u16*)bp)[o]);
            if (addA != nullptr) x += addA[(long)mg * K + kg];
          }
          f[j] = x;
        }
        v.x = (u32)f2bu(f[0]) | ((u32)f2bu(f[1]) << 16);
        v.y = (u32)f2bu(f[2]) | ((u32)f2bu(f[3]) << 16);
        v.z = (u32)f2bu(f[4]) | ((u32)f2bu(f[5]) << 16);
        v.w = (u32)f2bu(f[6]) | ((u32)f2bu(f[7]) << 16);
      }
      *(uint4*)&As[arow * 136 + kq + sub * 8] = v;
    }
    #pragma unroll
    for (int sub = 0; sub < 4; sub++) {
      uint4 v = *(const uint4*)(Wt + (long)(n0 + bcol) * Kr + kt + bq + sub * 8);
      *(uint4*)&Bs[bcol * 136 + bq + sub * 8] = v;
    }
    __syncthreads();
    #pragma unroll
    for (int ks = 0; ks < 8; ks++) {
      short4v a0 = *(short4v*)&As[(wr * 32 + 0 * 16 + lr) * 136 + ks * 16 + lh * 4];
      short4v a1 = *(short4v*)&As[(wr * 32 + 1 * 16 + lr) * 136 + ks * 16 + lh * 4];
      short4v b0 = *(short4v*)&Bs[(wc * 32 + 0 * 16 + lr) * 136 + ks * 16 + lh * 4];
      short4v b1 = *(short4v*)&Bs[(wc * 32 + 1 * 16 + lr) * 136 + ks * 16 + lh * 4];
      acc[0][0] = __builtin_amdgcn_mfma_f32_16x16x16bf16_1k(a0, b0, acc[0][0], 0, 0, 0);
      acc[0][1] = __builtin_amdgcn_mfma_f32_16x16x16bf16_1k(a0, b1, acc[0][1], 0, 0, 0);
      acc[1][0] = __builtin_amdgcn_mfma_f32_16x16x16bf16_1k(a1, b0, acc[1][0], 0, 0, 0);
      acc[1][1] = __builtin_amdgcn_mfma_f32_16x16x16bf16_1k(a1, b1, acc[1][1], 0, 0, 0);
    }
    __syncthreads();
  }
  #pragma unroll
  for (int ri = 0; ri < 2; ri++) {
    #pragma unroll
    for (int ci = 0; ci < 2; ci++) {
      int col = n0 + wc * 32 + ci * 16 + lr;
      float bv = (bias != nullptr) ? bias[col] : 0.f;
      #pragma unroll
      for (int e = 0; e < 4; e++) {
        int row = m0 + wr * 32 + ri * 16 + lh * 4 + e;
        float v = acc[ri][ci][e] + bv;
        if (act == 1) v = leakyf(v);
        else if (act == 2) v = tanhf(v);
        else if (act == 3) v = sigm(v);
        else if (act == 4) {
          int b = row >> 5;
          float zm = sigm(v + ep1[b * 128 + col]);
          float msv = bf2f(((const u16*)A0)[(long)row * k1 + col]);
          v = (1.f - zm) * msv + zm * ep2[b * 128 + col];
        }
        long o = (long)row * Nn + col;
        if (odt == 0) ((float*)C)[o] = v;
        else if (odt == 1) ((u16*)C)[o] = f2bu(v);
        else { ((float*)C)[o] = v; C2[o] = f2bu(v); }
      }
    }
  }
}

// ---------------- compound-graph kernels ----------------
__global__ void supe_init_k(const float* __restrict__ vert, float* __restrict__ supe){
  int b = blockIdx.x, c = threadIdx.x;
  float s = 0.f;
  for (int i = 0; i < cNC; i++) s += vert[(b * cNC + i) * cH + c];
  supe[b * cH + c] = s;
}

__global__ __launch_bounds__(256) void supe_pre_k(
    const float* __restrict__ supe,
    const float* __restrict__ Wa_super_d, const float* __restrict__ Ws2m_d,
    const float* __restrict__ Wzm2_d, const float* __restrict__ Wsup_d,
    const float* __restrict__ Whh_s, const float* __restrict__ bhh_s,
    float* __restrict__ asup, float* __restrict__ s2m, float* __restrict__ s2mz,
    float* __restrict__ sself, float* __restrict__ gh_s)
{
  __shared__ float srow[cH];
  __shared__ float s2ml[cH];
  int b = blockIdx.x, t = threadIdx.x;
  if (t < cH) srow[t] = supe[b * cH + t];
  __syncthreads();
  for (int j = 0; j < 4; j++) {
    int c = t + j * 256;
    int head = c >> 7, e = c & 127;
    const float* Wp = Wa_super_d + head * 16384 + e;
    float s = 0.f;
    for (int d2 = 0; d2 < cH; d2++) s += srow[d2] * Wp[d2 * 128];
    asup[b * 1024 + c] = tanhf(s);
  }
  if (t < cH) {
    float s = 0.f;
    for (int d2 = 0; d2 < cH; d2++) s += srow[d2] * Ws2m_d[d2 * 128 + t];
    float v = tanhf(s);
    s2ml[t] = v; s2m[b * cH + t] = v;
  } else {
    int c = t - cH;
    float s = 0.f;
    for (int d2 = 0; d2 < cH; d2++) s += srow[d2] * Wsup_d[d2 * 128 + c];
    sself[b * cH + c] = tanhf(s);
  }
  {
    int c = t;
    float s = 0.f;
    for (int d2 = 0; d2 < cH; d2++) s += srow[d2] * Whh_s[d2 * 384 + c];
    gh_s[b * 384 + c] = s + bhh_s[c];
    if (t < cH) {
      int c2 = 256 + t;
      float s2 = 0.f;
      for (int d2 = 0; d2 < cH; d2++) s2 += srow[d2] * Whh_s[d2 * 384 + c2];
      gh_s[b * 384 + c2] = s2 + bhh_s[c2];
    }
  }
  __syncthreads();
  if (t < cH) {
    float s = 0.f;
    for (int d2 = 0; d2 < cH; d2++) s += s2ml[d2] * Wzm2_d[d2 * 128 + t];
    s2mz[b * cH + t] = s;
  }
}

// attention scores + segment softmax (am in bf16)
__global__ __launch_bounds__(256) void attn_k(
    const u16* __restrict__ am, const float* __restrict__ asup,
    const float* __restrict__ Wb_d, float* __restrict__ attn)
{
  __shared__ float pw[1024];
  __shared__ float sc[cNC][cK8];
  int b = blockIdx.x, t = threadIdx.x;
  for (int j = 0; j < 4; j++) {
    int c = t + j * 256;
    pw[c] = asup[b * 1024 + c] * Wb_d[c];
  }
  __syncthreads();
  int nl = t >> 3, k = t & 7;
  int n = b * cNC + nl;
  const u16* ar = am + (long)n * 1024 + k * 128;
  const float* pr = pw + k * 128;
  float s = 0.f;
  for (int e = 0; e < 128; e++) s += bf2f(ar[e]) * pr[e];
  sc[nl][k] = s;
  __syncthreads();
  float mx = -1e30f;
  for (int i = 0; i < cNC; i++) mx = fmaxf(mx, sc[i][k]);
  float den = 0.f;
  for (int i = 0; i < cNC; i++) den += __expf(sc[i][k] - mx);
  attn[n * cK8 + k] = __expf(s - mx) / den;
}

// m2s + main_to_super (msg in bf16)
__global__ __launch_bounds__(256) void m2s_k(
    const float* __restrict__ attn, const u16* __restrict__ msg,
    const float* __restrict__ Wm2s_d, float* __restrict__ mts)
{
  __shared__ float m2s[1024];
  __shared__ float at[cNC][cK8];
  int b = blockIdx.x, t = threadIdx.x;
  at[t >> 3][t & 7] = attn[(b * cNC + (t >> 3)) * cK8 + (t & 7)];
  __syncthreads();
  for (int j = 0; j < 4; j++) {
    int c = t + j * 256;
    int k = c >> 7;
    float s = 0.f;
    for (int i = 0; i < cNC; i++) s += at[i][k] * bf2f(msg[(long)(b * cNC + i) * 1024 + c]);
    m2s[c] = s;
  }
  __syncthreads();
  if (t < cH) {
    float s = 0.f;
    for (int j = 0; j < 1024; j++) s += m2s[j] * Wm2s_d[j * 128 + t];
    mts[b * cH + t] = tanhf(s);
  }
}

__global__ void ew_gru_k(const u16* __restrict__ gi, const u16* __restrict__ gh,
                         float* __restrict__ h, u16* __restrict__ hb){
  int idx = blockIdx.x * 256 + threadIdx.x;
  if (idx >= cNV * cH) return;
  int n = idx >> 7, c = idx & 127;
  const u16* gir = gi + (long)n * 384;
  const u16* ghr = gh + (long)n * 384;
  float r = sigm(bf2f(gir[c]) + bf2f(ghr[c]));
  float z = sigm(bf2f(gir[128 + c]) + bf2f(ghr[128 + c]));
  float nn = tanhf(bf2f(gir[256 + c]) + r * bf2f(ghr[256 + c]));
  float v = (1.f - z) * nn + z * h[idx];
  h[idx] = v;
  hb[idx] = f2bu(v);
}

__global__ __launch_bounds__(128) void super_upd_k(
    const float* __restrict__ sself, const float* __restrict__ mts,
    const float* __restrict__ gh_s,
    const float* __restrict__ Wzs1_d, const float* __restrict__ Wzs2_d,
    const float* __restrict__ Wih_s, const float* __restrict__ bih_s,
    float* __restrict__ supe)
{
  __shared__ float ss[cH], mt[cH], xs[cH], sr[cH];
  int b = blockIdx.x, t = threadIdx.x;
  ss[t] = sself[b * cH + t];
  mt[t] = mts[b * cH + t];
  sr[t] = supe[b * cH + t];
  __syncthreads();
  float s1 = 0.f, s2 = 0.f;
  for (int d2 = 0; d2 < cH; d2++) {
    s1 += ss[d2] * Wzs1_d[d2 * 128 + t];
    s2 += mt[d2] * Wzs2_d[d2 * 128 + t];
  }
  float zs = sigm(s1 + s2);
  xs[t] = (1.f - zs) * ss[t] + zs * mt[t];
  __syncthreads();
  float g0 = 0.f, g1 = 0.f, g2 = 0.f;
  for (int d2 = 0; d2 < cH; d2++) {
    float x = xs[d2];
    g0 += x * Wih_s[d2 * 384 + t];
    g1 += x * Wih_s[d2 * 384 + 128 + t];
    g2 += x * Wih_s[d2 * 384 + 256 + t];
  }
  g0 += bih_s[t]; g1 += bih_s[128 + t]; g2 += bih_s[256 + t];
  float r = sigm(g0 + gh_s[b * 384 + t]);
  float z = sigm(g1 + gh_s[b * 384 + 128 + t]);
  float nn = tanhf(g2 + r * gh_s[b * 384 + 256 + t]);
  supe[b * cH + t] = (1.f - z) * nn + z * sr[t];
}

// ---------------- interaction ----------------
__global__ __launch_bounds__(256) void pair_k(
    const u16* __restrict__ pa, const u16* __restrict__ pg, float* __restrict__ out)
{
  __shared__ float pal[cNS][cHI];
  __shared__ float pgl[cNC][cHI + 1];
  int g = blockIdx.x, i = blockIdx.y;
  int t = threadIdx.x;
  for (int l = t; l < cNS * cHI; l += 256) {
    int s = l >> 6, hh = l & 63;
    pal[s][hh] = bf2f(pa[(long)(g * cNS + s) * 448 + i * 64 + hh]);
  }
  for (int l = t; l < cNC * cHI; l += 256) {
    int c = l >> 6, hh = l & 63;
    pgl[c][hh] = bf2f(pg[(long)(g * cNC + c) * 448 + i * 64 + hh]);
  }
  __syncthreads();
  for (int o = t; o < cNS * cNC; o += 256) {
    int s = o >> 5, c = o & 31;
    float sum = 0.f;
    #pragma unroll 8
    for (int hh = 0; hh < cHI; hh++) sum += pal[s][hh] * pgl[c][hh];
    long p = (long)g * (cNS * cNC) + o;
    out[p * 7 + i] = sum;
  }
}

// ---------------- launch ----------------
extern "C" void kernel_launch(void* const* d_in, const int* in_sizes, int n_in,
                              void* d_out, int out_size, void* d_ws, size_t ws_size,
                              hipStream_t stream) {
  constexpr long OFF_VERT = 0;            // 524288  vert f32
  constexpr long OFF_SUPE = 524288;
  constexpr long OFF_SITE = 1064960;      // -> site_b (bf16)
  constexpr long OFF_ATTN = 3162112;
  constexpr long OFF_ASUP = 3194880;
  constexpr long OFF_S2M = 3325952;
  constexpr long OFF_S2MZ = 3342336;
  constexpr long OFF_SSELF = 3358720;
  constexpr long OFF_GHS = 3375104;
  constexpr long OFF_MTS = 3424256;
  constexpr long OFF_NEI = 3440640;       // nei f32 (vert graph)
  constexpr long OFF_TMPA = 3964928;      // -> CSR int workspace
  constexpr long OFF_MS = 4489216;        // -> ms_b
  constexpr long OFF_ZMP = 5013504;       // -> vert_b (persistent)
  constexpr long OFF_XGRU = 5537792;      // -> xgru_b
  constexpr long OFF_GHM = 6062080;       // -> ghm_b + gim_b
  constexpr long OFF_GIM = 7634944;       // -> pg_b (interaction)
  constexpr long OFF_AM = 9207808;        // am_b (GWM) / nei_sb (site phase)
  constexpr long OFF_MSG = 13402112;      // msg_b (GWM) / pa_b (interaction)
  constexpr long OFF_H1 = 17596416;       // -> h1b
  constexpr long OFF_H2 = 19693568;       // -> h2b
  constexpr long OFF_H3 = 21790720;       // -> h3b (1M f32) + wbuf
  constexpr long WS_FLOATS = 23887872;
  if (ws_size < (size_t)WS_FLOATS * 4) return;

  // bf16 weight buffer sub-offsets (u16 elements)
  constexpr long WT_EMB = 0;
  constexpr long WT_SELF = 16384;
  constexpr long WT_AMAIN = 65536;
  constexpr long WT_V = 458752;
  constexpr long WT_HHM = 851968;
  constexpr long WT_ZM1 = 901120;
  constexpr long WT_IHM = 950272;
  constexpr long WT_W0 = 999424;
  constexpr long WT_CONV = 1015808;
  constexpr long WT_OUT = 1081344;
  constexpr long WT_IS = 1146880;
  constexpr long WT_IC = 1204224;

  const float* x_vert  = (const float*)d_in[0];
  const int*   vsrc    = (const int*)d_in[1];
  const int*   vdst    = (const int*)d_in[2];
  const float* W_emb   = (const float*)d_in[4];
  const float* b_emb   = (const float*)d_in[5];
  const float* Wa_main = (const float*)d_in[6];
  const float* Wa_super= (const float*)d_in[7];
  const float* Wv      = (const float*)d_in[8];
  const float* Wb      = (const float*)d_in[9];
  const float* Wm2s    = (const float*)d_in[10];
  const float* Ws2m    = (const float*)d_in[11];
  const float* Wsup    = (const float*)d_in[12];
  const float* Wself   = (const float*)d_in[13];
  const float* Wzm1    = (const float*)d_in[14];
  const float* Wzm2    = (const float*)d_in[15];
  const float* Wzs1    = (const float*)d_in[16];
  const float* Wzs2    = (const float*)d_in[17];
  const float* Wih_m   = (const float*)d_in[18];
  const float* Whh_m   = (const float*)d_in[19];
  const float* bih_m   = (const float*)d_in[20];
  const float* bhh_m   = (const float*)d_in[21];
  const float* Wih_s   = (const float*)d_in[22];
  const float* Whh_s   = (const float*)d_in[23];
  const float* bih_s   = (const float*)d_in[24];
  const float* bhh_s   = (const float*)d_in[25];
  const float* x_site  = (const float*)d_in[26];
  const int*   ssrc    = (const int*)d_in[27];
  const int*   sdst    = (const int*)d_in[28];
  const float* W0      = (const float*)d_in[29];
  const float* b0      = (const float*)d_in[30];
  const float* Wconv   = (const float*)d_in[31];
  const float* bconv   = (const float*)d_in[32];
  const float* Wout    = (const float*)d_in[33];
  const float* bout    = (const float*)d_in[34];
  const float* Wis     = (const float*)d_in[35];
  const float* bis     = (const float*)d_in[36];
  const float* Wic     = (const float*)d_in[37];
  const float* bic     = (const float*)d_in[38];
  float* out = (float*)d_out;

  float* ws = (float*)d_ws;
  float* vert  = ws + OFF_VERT;
  float* supe  = ws + OFF_SUPE;
  float* attn  = ws + OFF_ATTN;
  float* asup  = ws + OFF_ASUP;
  float* s2m   = ws + OFF_S2M;
  float* s2mz  = ws + OFF_S2MZ;
  float* sself = ws + OFF_SSELF;
  float* gh_s  = ws + OFF_GHS;
  float* mts   = ws + OFF_MTS;
  float* nei   = ws + OFF_NEI;

  u16* vert_b = (u16*)(ws + OFF_ZMP);
  u16* ms_b   = (u16*)(ws + OFF_MS);
  u16* xgru_b = (u16*)(ws + OFF_XGRU);
  u16* ghm_b  = (u16*)(ws + OFF_GHM);
  u16* gim_b  = (u16*)(ws + OFF_GHM + 786432);
  u16* h1b    = (u16*)(ws + OFF_H1);
  u16* h2b    = (u16*)(ws + OFF_H2);
  u16* h3b    = (u16*)(ws + OFF_H3);
  u16* site_b = (u16*)(ws + OFF_SITE);
  u16* am_b   = (u16*)(ws + OFF_AM);
  u16* msg_b  = (u16*)(ws + OFF_MSG);
  u16* nei_sb = (u16*)(ws + OFF_AM);    // site phase (am dead)
  u16* pa_b   = (u16*)(ws + OFF_MSG);   // interaction (msg dead)
  u16* pg_b   = (u16*)(ws + OFF_GIM);   // interaction
  u16* wbuf   = (u16*)(ws + OFF_H3 + 1048576);

  // CSR int workspace (inside OFF_TMPA, 524288 ints available)
  int* iws   = (int*)(ws + OFF_TMPA);
  int* voff  = iws;
  int* vcur  = iws + 8192;
  int* vperm = iws + 16384;
  int* soff  = iws + 32768;
  int* scur  = iws + 57344;
  int* sperm = iws + 81920;

  auto cvtw = [&](const float* src, long wt_off, int K, int krsh, int N,
                  int ldw, int cshift, int cs){
    long tot = (long)N << krsh;
    cvtw_k<<<dim3((unsigned)((tot + 255) / 256)), 256, 0, stream>>>(
        src, wbuf + wt_off, K, krsh, N, ldw, cshift, cs);
  };
  auto gemm1 = [&](const void* A0, int dt0, const void* A1, int dt1,
                   const void* A2, int dt2, const void* A3, int dt3,
                   int k1, int k2, int k3, int K, int M,
                   long wt_off, int Kr, const float* bias,
                   void* C, u16* C2, int N, int act, int odt,
                   const float* addA = nullptr,
                   const float* ep1 = nullptr, const float* ep2 = nullptr){
    GSegs s{};
    s.Wt[0] = wbuf + wt_off; s.bias[0] = bias; s.addA[0] = addA;
    s.C[0] = C; s.C2[0] = C2;
    s.nb_end[0] = N / 64; s.N[0] = N; s.Kr[0] = Kr; s.act[0] = act; s.odt[0] = odt;
    s.nsegs = 1;
    dim3 g(N / 64, M / 64);
    gemm_g<<<g, 256, 0, stream>>>(A0, A1, A2, A3, dt0, dt1, dt2, dt3,
                                  k1, k2, k3, K, M, s, ep1, ep2);
  };

  // ---- CSR build (both graphs) ----
  zero_i_k<<<16, 256, 0, stream>>>(vcur, cNV);
  count_k<<<cEV / 256, 256, 0, stream>>>(vdst, vcur, cEV);
  scan_k<<<1, 256, 0, stream>>>(vcur, voff, cNV);
  copy_i_k<<<16, 256, 0, stream>>>(voff, vcur, cNV);
  fill_k<<<cEV / 256, 256, 0, stream>>>(vsrc, vdst, vcur, vperm, cEV);
  zero_i_k<<<64, 256, 0, stream>>>(scur, cNSITE);
  count_k<<<cES / 256, 256, 0, stream>>>(sdst, scur, cES);
  scan_k<<<1, 256, 0, stream>>>(scur, soff, cNSITE);
  copy_i_k<<<64, 256, 0, stream>>>(soff, scur, cNSITE);
  fill_k<<<cES / 256, 256, 0, stream>>>(ssrc, sdst, scur, sperm, cES);

  // ---- one-time weight convert+transpose ----
  cvtw(W_emb, WT_EMB, 82, 7, 128, 128, 30, 0);
  cvtw(Wself, WT_SELF, 128, 7, 384, 128, 7, 16384);
  cvtw(Wa_main, WT_AMAIN, 128, 7, 3072, 128, 7, 16384);
  cvtw(Wv, WT_V, 128, 7, 3072, 128, 7, 16384);
  cvtw(Whh_m, WT_HHM, 128, 7, 384, 384, 30, 0);
  cvtw(Wzm1, WT_ZM1, 128, 7, 384, 128, 7, 16384);
  cvtw(Wih_m, WT_IHM, 128, 7, 384, 384, 30, 0);
  cvtw(W0, WT_W0, 64, 7, 128, 128, 30, 0);
  cvtw(Wconv, WT_CONV, 256, 8, 256, 128, 7, 32768);
  cvtw(Wout, WT_OUT, 416, 9, 128, 128, 30, 0);
  cvtw(Wis, WT_IS, 128, 7, 448, 64, 6, 8192);
  cvtw(Wic, WT_IC, 128, 7, 448, 64, 6, 8192);

  // ---- embedding (dual store) + super init ----
  gemm1(x_vert, 1, x_vert, 1, x_vert, 1, x_vert, 1, 82, 82, 82, 82, cNV,
        WT_EMB, 128, b_emb, vert, vert_b, 128, 1, 2);
  supe_init_k<<<cB, 128, 0, stream>>>(vert, supe);

  // ---- GWM iterations ----
  for (int d = 0; d < 3; d++) {
    const float* Wa_super_d = Wa_super + (long)d * 131072;
    const float* Wb_d = Wb + (long)d * 1024;
    const float* Wm2s_d = Wm2s + (long)d * 131072;
    const float* Ws2m_d = Ws2m + (long)d * 16384;
    const float* Wsup_d = Wsup + (long)d * 16384;
    const float* Wzm2_d = Wzm2 + (long)d * 16384;
    const float* Wzs1_d = Wzs1 + (long)d * 16384;
    const float* Wzs2_d = Wzs2 + (long)d * 16384;

    gather128_f_k<<<cNV, 128, 0, stream>>>(vert, voff, vperm, nei);

    // fused: ms_b | am_b | msg_b | ghm_b   (A = vert_b, K=128, N_total=2560)
    {
      GSegs s{};
      s.Wt[0] = wbuf + WT_SELF + (long)d * 16384;  s.bias[0] = nullptr;
      s.addA[0] = nei;     s.C[0] = ms_b;  s.C2[0] = nullptr;
      s.N[0] = 128;  s.Kr[0] = 128; s.act[0] = 1; s.odt[0] = 1; s.nb_end[0] = 2;
      s.Wt[1] = wbuf + WT_AMAIN + (long)d * 131072; s.bias[1] = nullptr;
      s.addA[1] = nullptr; s.C[1] = am_b;  s.C2[1] = nullptr;
      s.N[1] = 1024; s.Kr[1] = 128; s.act[1] = 2; s.odt[1] = 1; s.nb_end[1] = 18;
      s.Wt[2] = wbuf + WT_V + (long)d * 131072;     s.bias[2] = nullptr;
      s.addA[2] = nullptr; s.C[2] = msg_b; s.C2[2] = nullptr;
      s.N[2] = 1024; s.Kr[2] = 128; s.act[2] = 0; s.odt[2] = 1; s.nb_end[2] = 34;
      s.Wt[3] = wbuf + WT_HHM;                      s.bias[3] = bhh_m;
      s.addA[3] = nullptr; s.C[3] = ghm_b; s.C2[3] = nullptr;
      s.N[3] = 384;  s.Kr[3] = 128; s.act[3] = 0; s.odt[3] = 1; s.nb_end[3] = 40;
      s.nsegs = 4;
      dim3 g(40, cNV / 64);
      gemm_g<<<g, 256, 0, stream>>>(vert_b, vert_b, vert_b, vert_b, 0, 0, 0, 0,
                                    128, 128, 128, 128, cNV, s, nullptr, nullptr);
    }
    supe_pre_k<<<cB, 256, 0, stream>>>(supe, Wa_super_d, Ws2m_d, Wzm2_d, Wsup_d,
                                       Whh_s, bhh_s, asup, s2m, s2mz, sself, gh_s);
    attn_k<<<cB, 256, 0, stream>>>(am_b, asup, Wb_d, attn);
    m2s_k<<<cB, 256, 0, stream>>>(attn, msg_b, Wm2s_d, mts);
    gemm1(ms_b, 0, ms_b, 0, ms_b, 0, ms_b, 0, 128, 128, 128, 128, cNV,
          WT_ZM1 + (long)d * 16384, 128, nullptr, xgru_b, nullptr, 128, 4, 1,
          nullptr, s2mz, s2m);
    gemm1(xgru_b, 0, xgru_b, 0, xgru_b, 0, xgru_b, 0, 128, 128, 128, 128, cNV,
          WT_IHM, 128, bih_m, gim_b, nullptr, 384, 0, 1);
    ew_gru_k<<<(cNV * cH) / 256, 256, 0, stream>>>(gim_b, ghm_b, vert, vert_b);
    super_upd_k<<<cB, 128, 0, stream>>>(sself, mts, gh_s, Wzs1_d, Wzs2_d,
                                        Wih_s, bih_s, supe);
  }

  // ---- AtomConv on protein sites (CSR gathers, bf16 nei) ----
  gather32_k<<<cNSITE / 8, 256, 0, stream>>>(x_site, soff, sperm, nei_sb);
  gemm1(x_site, 1, nei_sb, 0, nei_sb, 0, nei_sb, 0, 32, 64, 64, 64, cNSITE,
        WT_W0, 128, b0, h1b, nullptr, 128, 1, 1);
  gather128_b_k<<<cNSITE, 128, 0, stream>>>(h1b, soff, sperm, nei_sb);
  gemm1(h1b, 0, nei_sb, 0, nei_sb, 0, nei_sb, 0, 128, 256, 256, 256, cNSITE,
        WT_CONV, 256, bconv, h2b, nullptr, 128, 1, 1);
  gather128_b_k<<<cNSITE, 128, 0, stream>>>(h2b, soff, sperm, nei_sb);
  gemm1(h2b, 0, nei_sb, 0, nei_sb, 0, nei_sb, 0, 128, 256, 256, 256, cNSITE,
        WT_CONV + 32768, 256, bconv + 128, h3b, nullptr, 128, 1, 1);
  gemm1(x_site, 1, h1b, 0, h2b, 0, h3b, 0, 32, 160, 288, 416, cNSITE,
        WT_OUT, 512, bout, site_b, nullptr, 128, 1, 1);

  // ---- Interaction ----
  gemm1(site_b, 0, site_b, 0, site_b, 0, site_b, 0, 128, 128, 128, 128, cNSITE,
        WT_IS, 128, bis, pa_b, nullptr, 448, 1, 1);
  gemm1(vert_b, 0, vert_b, 0, vert_b, 0, vert_b, 0, 128, 128, 128, 128, cNV,
        WT_IC, 128, bic, pg_b, nullptr, 448, 1, 1);
  pair_k<<<dim3(cB, 7), 256, 0, stream>>>(pa_b, pg_b, out);
}